// Round 11
// baseline (2729.550 us; speedup 1.0000x reference)
//
#include <hip/hip_runtime.h>
#include <math.h>

#define NVOX 60000

typedef __attribute__((ext_vector_type(8))) short short8v;            // 8 bf16 raw
typedef __attribute__((ext_vector_type(8))) unsigned short ushort8v;  // 8 bf16 raw
typedef __attribute__((ext_vector_type(4))) float f32x4;

static __device__ __forceinline__ unsigned short f2bf(float f) {
    unsigned u = __float_as_uint(f);
    unsigned r = (u + 0x7fffu + ((u >> 16) & 1u)) >> 16;
    return (unsigned short)r;
}
static __device__ __forceinline__ float bf2f(unsigned short h) {
    return __uint_as_float(((unsigned)h) << 16);
}
// async global->LDS 16B per lane: dest = lds_base + lane*16 (wave-uniform base)
static __device__ __forceinline__ void gll16(const unsigned short* g, unsigned short* l) {
    __builtin_amdgcn_global_load_lds(
        (const __attribute__((address_space(1))) unsigned*)g,
        (__attribute__((address_space(3))) unsigned*)l,
        16, 0, 0);
}

// ---------------------------------------------------------------- pos embed (bf16 out)
__global__ __launch_bounds__(256) void pos_kernel(const float* __restrict__ ciw,
                                                  unsigned short* __restrict__ pos) {
    int idx = blockIdx.x * 256 + threadIdx.x;
    if (idx >= NVOX * 128) return;
    int n = idx >> 7, d = idx & 127;
    int c = d >> 6, t = (d & 63) >> 1;
    float xy = ciw[n * 2 + c] - 6.0f;
    float inv = exp2f((float)t * (13.287712379549449f / 32.0f)); // 10000^(t/32)
    float e = xy / inv;
    pos[idx] = f2bf((d & 1) ? cosf(e) : sinf(e));
}

// ------------------------------------------------------- fp32 -> bf16 convert
__global__ __launch_bounds__(256) void cvt_bf16(const float* __restrict__ in,
                                                unsigned short* __restrict__ out, int n) {
    int idx = blockIdx.x * 256 + threadIdx.x;
    if (idx < n) out[idx] = f2bf(in[idx]);
}

// ----------------- feat init: f32 copy + bf16 shadow + bf16(feat+pos0) shadow
__global__ __launch_bounds__(256) void feat_init(const float* __restrict__ vf,
                                                 const unsigned short* __restrict__ pos0,
                                                 float* __restrict__ feat,
                                                 unsigned short* __restrict__ featb,
                                                 unsigned short* __restrict__ featq) {
    int idx = blockIdx.x * 256 + threadIdx.x;
    if (idx >= NVOX * 128) return;
    float v = vf[idx];
    feat[idx] = v;
    featb[idx] = f2bf(v);
    featq[idx] = f2bf(v + bf2f(pos0[idx]));
}

// ----------------------------------------- MFMA GEMM: C = A*W^T + b (+variants)
// QKV: A = (blockIdx.y<2 ? Aq : Av) — all blocks pure async staging.
// LNF (N==128, gridDim.y==1): feat = LN(feat + A@W^T + b)*g+b2; writes feat/featb
// and, if posq!=nullptr, featq = bf16(LNout + posq)  (next layer's q/k input).
template<int KTOT, bool QKV, bool GELU, bool CBF16, bool LNF>
__global__ __launch_bounds__(256) void gemm_mfma(
    const unsigned short* __restrict__ Aq, const unsigned short* __restrict__ Av,
    const unsigned short* __restrict__ W, const float* __restrict__ bias,
    void* __restrict__ Cp, int M, int ldc,
    float* __restrict__ feat, unsigned short* __restrict__ featb,
    unsigned short* __restrict__ featq, const unsigned short* __restrict__ posq,
    const float* __restrict__ lng, const float* __restrict__ lnb)
{
    __shared__ unsigned short smem[128 * 128];   // As(16KB) + Ws(16KB), reused as Cs(32KB)
    __shared__ float2 lnsum[128][2];
    unsigned short* As = smem;
    unsigned short* Ws = smem + 128 * 64;
    const int tid = threadIdx.x;
    const int lane = tid & 63, wave = tid >> 6;
    const int wr = wave >> 1, wc = wave & 1;
    const int llo = lane & 15, lhi = lane >> 4;
    const int m0 = blockIdx.x * 128;
    const int n0 = blockIdx.y * 128;
    const unsigned short* A = QKV ? (((int)blockIdx.y < 2) ? Aq : Av) : Aq;
    const int gr = lane >> 3;           // row within 8-row group
    const int gc = (lane & 7) ^ gr;     // pre-swizzled source chunk
    f32x4 acc[4][4] = {};

    for (int k0 = 0; k0 < KTOT; k0 += 64) {
        #pragma unroll
        for (int p = 0; p < 4; ++p) {
            int r0 = wave * 32 + p * 8;
            gll16(W + (size_t)(n0 + r0 + gr) * KTOT + k0 + gc * 8, &Ws[r0 * 64]);
        }
        #pragma unroll
        for (int p = 0; p < 4; ++p) {
            int r0 = wave * 32 + p * 8;
            gll16(A + (size_t)(m0 + r0 + gr) * KTOT + k0 + gc * 8, &As[r0 * 64]);
        }
        __syncthreads();
        #pragma unroll
        for (int kk = 0; kk < 2; ++kk) {
            int kb = kk * 64 + lhi * 16;
            short8v af[4], bf[4];
            #pragma unroll
            for (int i = 0; i < 4; ++i) {
                int r = wr * 64 + i * 16 + llo;
                af[i] = *reinterpret_cast<const short8v*>((const char*)As + r * 128 + (kb ^ ((r & 7) << 4)));
                int cc = wc * 64 + i * 16 + llo;
                bf[i] = *reinterpret_cast<const short8v*>((const char*)Ws + cc * 128 + (kb ^ ((cc & 7) << 4)));
            }
            #pragma unroll
            for (int i = 0; i < 4; ++i)
                #pragma unroll
                for (int j = 0; j < 4; ++j)
                    acc[i][j] = __builtin_amdgcn_mfma_f32_16x16x32_bf16(af[i], bf[j], acc[i][j], 0, 0, 0);
        }
        __syncthreads();
    }

    if (LNF) {
        // residual + LN: pass 1 computes x = feat + acc + bias -> stored back in acc
        float s1[4][4] = {}, s2[4][4] = {};
        #pragma unroll
        for (int i = 0; i < 4; ++i)
            #pragma unroll
            for (int rg = 0; rg < 4; ++rg) {
                int m = m0 + wr * 64 + i * 16 + lhi * 4 + rg;
                if (m < M) {
                    #pragma unroll
                    for (int j = 0; j < 4; ++j) {
                        int n = wc * 64 + j * 16 + llo;
                        float x = feat[(size_t)m * 128 + n] + acc[i][j][rg] + bias[n];
                        acc[i][j][rg] = x;
                        s1[i][rg] += x; s2[i][rg] += x * x;
                    }
                }
            }
        #pragma unroll
        for (int i = 0; i < 4; ++i)
            #pragma unroll
            for (int rg = 0; rg < 4; ++rg) {
                #pragma unroll
                for (int off = 1; off < 16; off <<= 1) {
                    s1[i][rg] += __shfl_xor(s1[i][rg], off);
                    s2[i][rg] += __shfl_xor(s2[i][rg], off);
                }
                if (llo == 0)
                    lnsum[wr * 64 + i * 16 + lhi * 4 + rg][wc] = make_float2(s1[i][rg], s2[i][rg]);
            }
        __syncthreads();
        #pragma unroll
        for (int i = 0; i < 4; ++i)
            #pragma unroll
            for (int rg = 0; rg < 4; ++rg) {
                int r = wr * 64 + i * 16 + lhi * 4 + rg;
                int m = m0 + r;
                if (m >= M) continue;
                float2 a0 = lnsum[r][0], a1 = lnsum[r][1];
                float mu = (a0.x + a1.x) * 0.0078125f;
                float var = fmaxf((a0.y + a1.y) * 0.0078125f - mu * mu, 0.f);
                float inv = rsqrtf(var + 1e-5f);
                #pragma unroll
                for (int j = 0; j < 4; ++j) {
                    int n = wc * 64 + j * 16 + llo;
                    float v = (acc[i][j][rg] - mu) * inv * lng[n] + lnb[n];
                    feat[(size_t)m * 128 + n] = v;
                    featb[(size_t)m * 128 + n] = f2bf(v);
                    if (posq != nullptr)
                        featq[(size_t)m * 128 + n] = f2bf(v + bf2f(posq[(size_t)m * 128 + n]));
                }
            }
    } else if (CBF16) {
        #pragma unroll
        for (int j = 0; j < 4; ++j) {
            int nl = wc * 64 + j * 16 + llo;
            float bn = bias[n0 + nl];
            #pragma unroll
            for (int i = 0; i < 4; ++i)
                #pragma unroll
                for (int rg = 0; rg < 4; ++rg) {
                    float v = acc[i][j][rg] + bn;
                    if (GELU) v = 0.5f * v * (1.0f + erff(v * 0.7071067811865475f));
                    smem[(wr * 64 + i * 16 + lhi * 4 + rg) * 128 + nl] = f2bf(v);
                }
        }
        __syncthreads();
        unsigned short* C = (unsigned short*)Cp;
        #pragma unroll
        for (int c = 0; c < 8; ++c) {
            int idx = tid + c * 256;
            int r = idx >> 4, ch = idx & 15;
            if (m0 + r < M)
                *reinterpret_cast<ushort8v*>(C + (size_t)(m0 + r) * ldc + n0 + ch * 8) =
                    *reinterpret_cast<const ushort8v*>(&smem[r * 128 + ch * 8]);
        }
    } else {
        float* C = (float*)Cp;
        #pragma unroll
        for (int j = 0; j < 4; ++j) {
            int n = n0 + wc * 64 + j * 16 + llo;
            float bn = bias[n];
            #pragma unroll
            for (int i = 0; i < 4; ++i)
                #pragma unroll
                for (int rg = 0; rg < 4; ++rg) {
                    int m = m0 + wr * 64 + i * 16 + lhi * 4 + rg;
                    if (m < M) {
                        float v = acc[i][j][rg] + bn;
                        if (GELU) v = 0.5f * v * (1.0f + erff(v * 0.7071067811865475f));
                        C[(size_t)m * ldc + n] = v;
                    }
                }
        }
    }
}

// ------------------------------------------------------- windowed attention (bf16 qkv)
template<int CAPT, int HG>
__global__ __launch_bounds__(256) void attn_kernel(
    const unsigned short* __restrict__ qkv, const int* __restrict__ vlist, int nvox,
    unsigned short* __restrict__ oout)
{
    __shared__ float Ks[CAPT][HG * 16];
    __shared__ float Vs[CAPT][HG * 16];
    __shared__ int vl[CAPT];
    const int w = blockIdx.x;
    const int hb = blockIdx.y * HG;
    const int tid = threadIdx.x;
    const int T = min(CAPT, nvox - w * CAPT);
    if (tid < T) vl[tid] = vlist[w * CAPT + tid];
    constexpr int R8 = HG * 2;
    for (int idx = tid; idx < T * R8; idx += 256) {
        int t = idx / R8, c8 = (idx % R8) * 8;
        int vox = vlist[w * CAPT + t];
        const unsigned short* base = qkv + (size_t)vox * 384 + hb * 16 + c8;
        ushort8v kv = *reinterpret_cast<const ushort8v*>(base + 128);
        ushort8v vv = *reinterpret_cast<const ushort8v*>(base + 256);
        #pragma unroll
        for (int q = 0; q < 8; ++q) { Ks[t][c8 + q] = bf2f(kv[q]); Vs[t][c8 + q] = bf2f(vv[q]); }
    }
    __syncthreads();
    const int ITEMS = T * HG;
    for (int item = tid; item < ITEMS; item += 256) {
        int h = item & (HG - 1);
        int q = item / HG;
        int vq = vl[q];
        const unsigned short* qb = qkv + (size_t)vq * 384 + (hb + h) * 16;
        ushort8v qa = *reinterpret_cast<const ushort8v*>(qb);
        ushort8v qc = *reinterpret_cast<const ushort8v*>(qb + 8);
        float4 q0 = make_float4(bf2f(qa[0]), bf2f(qa[1]), bf2f(qa[2]), bf2f(qa[3]));
        float4 q1 = make_float4(bf2f(qa[4]), bf2f(qa[5]), bf2f(qa[6]), bf2f(qa[7]));
        float4 q2 = make_float4(bf2f(qc[0]), bf2f(qc[1]), bf2f(qc[2]), bf2f(qc[3]));
        float4 q3 = make_float4(bf2f(qc[4]), bf2f(qc[5]), bf2f(qc[6]), bf2f(qc[7]));
        float mx = -INFINITY, l = 0.f;
        float4 o0 = make_float4(0,0,0,0), o1 = o0, o2 = o0, o3 = o0;
        for (int t = 0; t < T; ++t) {
            const float4* kr = reinterpret_cast<const float4*>(&Ks[t][h * 16]);
            float4 k0 = kr[0], k1 = kr[1], k2 = kr[2], k3 = kr[3];
            float s = q0.x*k0.x + q0.y*k0.y + q0.z*k0.z + q0.w*k0.w
                    + q1.x*k1.x + q1.y*k1.y + q1.z*k1.z + q1.w*k1.w
                    + q2.x*k2.x + q2.y*k2.y + q2.z*k2.z + q2.w*k2.w
                    + q3.x*k3.x + q3.y*k3.y + q3.z*k3.z + q3.w*k3.w;
            s *= 0.25f;
            float mo = mx;
            mx = fmaxf(mx, s);
            float cc = __expf(mo - mx);
            float p  = __expf(s - mx);
            l = l * cc + p;
            const float4* vr = reinterpret_cast<const float4*>(&Vs[t][h * 16]);
            float4 v0 = vr[0], v1 = vr[1], v2 = vr[2], v3 = vr[3];
            o0.x = o0.x*cc + p*v0.x; o0.y = o0.y*cc + p*v0.y; o0.z = o0.z*cc + p*v0.z; o0.w = o0.w*cc + p*v0.w;
            o1.x = o1.x*cc + p*v1.x; o1.y = o1.y*cc + p*v1.y; o1.z = o1.z*cc + p*v1.z; o1.w = o1.w*cc + p*v1.w;
            o2.x = o2.x*cc + p*v2.x; o2.y = o2.y*cc + p*v2.y; o2.z = o2.z*cc + p*v2.z; o2.w = o2.w*cc + p*v2.w;
            o3.x = o3.x*cc + p*v3.x; o3.y = o3.y*cc + p*v3.y; o3.z = o3.z*cc + p*v3.z; o3.w = o3.w*cc + p*v3.w;
        }
        float rl = 1.0f / l;
        ushort8v r0, r1;
        r0[0]=f2bf(o0.x*rl); r0[1]=f2bf(o0.y*rl); r0[2]=f2bf(o0.z*rl); r0[3]=f2bf(o0.w*rl);
        r0[4]=f2bf(o1.x*rl); r0[5]=f2bf(o1.y*rl); r0[6]=f2bf(o1.z*rl); r0[7]=f2bf(o1.w*rl);
        r1[0]=f2bf(o2.x*rl); r1[1]=f2bf(o2.y*rl); r1[2]=f2bf(o2.z*rl); r1[3]=f2bf(o2.w*rl);
        r1[4]=f2bf(o3.x*rl); r1[5]=f2bf(o3.y*rl); r1[6]=f2bf(o3.z*rl); r1[7]=f2bf(o3.w*rl);
        unsigned short* op = oout + (size_t)vq * 128 + (hb + h) * 16;
        *reinterpret_cast<ushort8v*>(op) = r0;
        *reinterpret_cast<ushort8v*>(op + 8) = r1;
    }
}

// ------------------- BEV scatter into padded canvas (bf16, stride 420)
__global__ __launch_bounds__(256) void scatter_kernel(const float* __restrict__ feat,
    const int* __restrict__ coors, unsigned short* __restrict__ canvas)
{
    int idx = blockIdx.x * 256 + threadIdx.x;
    if (idx >= NVOX * 16) return;
    int n = idx >> 4, c8 = (idx & 15) << 3;
    int b = coors[n * 4], y = coors[n * 4 + 2], x = coors[n * 4 + 3];
    const float* src = feat + (size_t)n * 128 + c8;
    float4 u0 = *reinterpret_cast<const float4*>(src);
    float4 u1 = *reinterpret_cast<const float4*>(src + 4);
    ushort8v v;
    v[0]=f2bf(u0.x); v[1]=f2bf(u0.y); v[2]=f2bf(u0.z); v[3]=f2bf(u0.w);
    v[4]=f2bf(u1.x); v[5]=f2bf(u1.y); v[6]=f2bf(u1.z); v[7]=f2bf(u1.w);
    size_t p = (((size_t)b * 404 + y + 2) * 420 + x + 2) * 128 + c8;
    *reinterpret_cast<ushort8v*>(canvas + p) = v;
}

// --------- zero the halo of a stride-420 padded canvas
__global__ __launch_bounds__(256) void halo_zero(unsigned short* __restrict__ c) {
    int idx = blockIdx.x * 256 + threadIdx.x;
    if (idx >= 2 * 9680 * 16) return;
    int b = idx / (9680 * 16);
    int rem = idx % (9680 * 16);
    int p = rem >> 4, ch = (rem & 15) * 8;
    int y, x;
    if (p < 1680) { int ry = p / 420; y = (ry < 2) ? ry : ry + 400; x = p % 420; }
    else { int q = p - 1680; y = 2 + q / 20; int cx = q % 20; x = (cx < 2) ? cx : cx + 400; }
    ushort8v z = {};
    *reinterpret_cast<ushort8v*>(c + (((size_t)b * 404 + y) * 420 + x) * 128 + ch) = z;
}

// ------------------- conv weight re-layout -> bf16 [i][ky*3+kx][cout][cin]
__global__ __launch_bounds__(256) void wtrans_kernel(const float* __restrict__ cw,
                                                     unsigned short* __restrict__ wbuf)
{
    int idx = blockIdx.x * 256 + threadIdx.x;
    if (idx >= 2 * 9 * 128 * 128) return;
    int ci = idx & 127;
    int co = (idx >> 7) & 127;
    int kk = (idx >> 14) % 9;
    int i  = idx / (9 * 16384);
    wbuf[idx] = f2bf(cw[(((size_t)i * 128 + co) * 128 + ci) * 9 + kk]);
}

// ---------------- 3x3 dilated(2) conv + BN + ReLU, LDS-A once + LDS-W double-buffered
template<bool NCHW_OUT>
__global__ __launch_bounds__(512, 1) void conv_mfma(
    const unsigned short* __restrict__ in, const unsigned short* __restrict__ wbuf,
    const float* __restrict__ g, const float* __restrict__ bsh,
    const float* __restrict__ bm, const float* __restrict__ bv,
    void* __restrict__ out)
{
    __shared__ unsigned short Ab[8 * 36 * 128];
    __shared__ unsigned short Wb[2 * 128 * 128];
    const int tid = threadIdx.x;
    const int lane = tid & 63, wave = tid >> 6;
    const int cog = wave & 1, yg = wave >> 1;
    const int llo = lane & 15, lhi = lane >> 4;
    const int x0 = blockIdx.x * 32, y0 = blockIdx.y * 4, b = blockIdx.z;
    const int c16s = lane & 15;

    #pragma unroll
    for (int it = 0; it < 9; ++it) {
        int gidx = it * 32 + wave * 4 + lhi;
        int row = gidx / 36, xi = gidx % 36;
        gll16(in + (((size_t)b * 404 + y0 + row) * 420 + x0 + xi) * 128 + ((c16s ^ (xi & 15)) * 8),
              Ab + (size_t)(it * 512 + wave * 64) * 8);
    }
    {
        const unsigned short* wt = wbuf;
        #pragma unroll
        for (int it = 0; it < 4; ++it) {
            int co = it * 32 + wave * 4 + lhi;
            gll16(wt + co * 128 + ((c16s ^ (co & 15)) * 8),
                  Wb + (size_t)(it * 512 + wave * 64) * 8);
        }
    }
    __syncthreads();

    f32x4 acc[2][4] = {};
    #pragma unroll
    for (int t = 0; t < 9; ++t) {
        if (t < 8) {
            const unsigned short* wt = wbuf + (size_t)(t + 1) * 16384;
            unsigned short* dst = Wb + ((t + 1) & 1) * 16384;
            #pragma unroll
            for (int it = 0; it < 4; ++it) {
                int co = it * 32 + wave * 4 + lhi;
                gll16(wt + co * 128 + ((c16s ^ (co & 15)) * 8),
                      dst + (size_t)(it * 512 + wave * 64) * 8);
            }
        }
        const unsigned short* Wp = Wb + (t & 1) * 16384;
        const int ky = t / 3, kx = t % 3;
        const int r = yg + 2 * ky;
        #pragma unroll
        for (int kk = 0; kk < 4; ++kk) {
            short8v a[2], w[4];
            #pragma unroll
            for (int i = 0; i < 2; ++i) {
                int xi = i * 16 + llo + 2 * kx;
                a[i] = *reinterpret_cast<const short8v*>(
                    (const char*)Ab + (r * 36 + xi) * 256 + ((kk * 64 + lhi * 16) ^ ((xi & 15) << 4)));
            }
            #pragma unroll
            for (int j = 0; j < 4; ++j) {
                int co = cog * 64 + j * 16 + llo;
                w[j] = *reinterpret_cast<const short8v*>(
                    (const char*)Wp + co * 256 + ((kk * 64 + lhi * 16) ^ ((co & 15) << 4)));
            }
            #pragma unroll
            for (int i = 0; i < 2; ++i)
                #pragma unroll
                for (int j = 0; j < 4; ++j)
                    acc[i][j] = __builtin_amdgcn_mfma_f32_16x16x32_bf16(a[i], w[j], acc[i][j], 0, 0, 0);
        }
        __syncthreads();
    }

    const int y = y0 + yg;
    if (NCHW_OUT) {
        #pragma unroll
        for (int j = 0; j < 4; ++j) {
            int co = cog * 64 + j * 16 + llo;
            float scale = rsqrtf(bv[co] + 1e-3f) * g[co];
            float shift = bsh[co] - bm[co] * scale;
            #pragma unroll
            for (int i = 0; i < 2; ++i) {
                int px = x0 + i * 16 + lhi * 4;
                if (px < 400) {
                    float4 v;
                    v.x = fmaxf(acc[i][j][0] * scale + shift, 0.f);
                    v.y = fmaxf(acc[i][j][1] * scale + shift, 0.f);
                    v.z = fmaxf(acc[i][j][2] * scale + shift, 0.f);
                    v.w = fmaxf(acc[i][j][3] * scale + shift, 0.f);
                    *reinterpret_cast<float4*>(
                        (float*)out + (((size_t)b * 128 + co) * 400 + y) * 400 + px) = v;
                }
            }
        }
    } else {
        unsigned short* Cw = Wb + wave * 2048;
        #pragma unroll
        for (int j = 0; j < 4; ++j) {
            int co = cog * 64 + j * 16 + llo;
            float scale = rsqrtf(bv[co] + 1e-3f) * g[co];
            float shift = bsh[co] - bm[co] * scale;
            #pragma unroll
            for (int i = 0; i < 2; ++i)
                #pragma unroll
                for (int rg = 0; rg < 4; ++rg)
                    Cw[(i * 16 + lhi * 4 + rg) * 64 + j * 16 + llo] =
                        f2bf(fmaxf(acc[i][j][rg] * scale + shift, 0.f));
        }
        #pragma unroll
        for (int s = 0; s < 4; ++s) {
            int pxl = s * 8 + (lane >> 3);
            int oct = lane & 7;
            int px = x0 + pxl;
            if (px < 400)
                *reinterpret_cast<ushort8v*>(
                    (unsigned short*)out + (((size_t)b * 404 + y + 2) * 420 + px + 2) * 128
                                         + cog * 64 + oct * 8) =
                    *reinterpret_cast<const ushort8v*>(&Cw[pxl * 64 + oct * 8]);
        }
    }
}

// ---------------------------------------------------------------- launcher
extern "C" void kernel_launch(void* const* d_in, const int* in_sizes, int n_in,
                              void* d_out, int out_size, void* d_ws, size_t ws_size,
                              hipStream_t stream) {
    const float* voxel_feat = (const float*)d_in[0];
    const int*   coors      = (const int*)d_in[1];
    const float* ciw0       = (const float*)d_in[2];
    const float* ciw1       = (const float*)d_in[3];
    const int* vx[2][2] = {{(const int*)d_in[4], (const int*)d_in[6]},
                           {(const int*)d_in[8], (const int*)d_in[10]}};
    const float* ipw = (const float*)d_in[12];
    const float* ipb = (const float*)d_in[13];
    const float* ow  = (const float*)d_in[14];
    const float* obp = (const float*)d_in[15];
    const float* l1w = (const float*)d_in[16];
    const float* l1b = (const float*)d_in[17];
    const float* l2w = (const float*)d_in[18];
    const float* l2b = (const float*)d_in[19];
    const float* g1  = (const float*)d_in[20];
    const float* b1  = (const float*)d_in[21];
    const float* g2  = (const float*)d_in[22];
    const float* b2  = (const float*)d_in[23];
    const float* cw  = (const float*)d_in[24];
    const float* bng = (const float*)d_in[25];
    const float* bnb = (const float*)d_in[26];
    const float* bnm = (const float*)d_in[27];
    const float* bnv = (const float*)d_in[28];

    float* F = (float*)d_ws;
    unsigned short* W0   = (unsigned short*)F;
    unsigned short* ipwb = W0;                           // 589824
    unsigned short* owb  = W0 + 589824;                  // 196608
    unsigned short* l1wb = W0 + 786432;                  // 393216
    unsigned short* l2wb = W0 + 1179648;                 // 393216
    unsigned short* cwb  = W0 + 1572864;                 // 294912
    float* feat = F + 940000;                            // 7.68M f32
    unsigned short* featb = (unsigned short*)(F + 8620000);   // bf16 feat
    unsigned short* pos0  = (unsigned short*)(F + 12460000);
    unsigned short* pos1  = (unsigned short*)(F + 16300000);
    unsigned short* obufb = (unsigned short*)(F + 20140000);
    unsigned short* featq = (unsigned short*)(F + 23980000);  // bf16 (feat+pos_cur)
    // conv phase: padded canvases [2][404][420][128] bf16 = 43,438,080 ushorts each
    unsigned short* canvas1 = (unsigned short*)(F + 8620000);
    unsigned short* canvas2 = (unsigned short*)(F + 30339040);
    unsigned short* qkvb = (unsigned short*)d_out;

    pos_kernel<<<30000, 256, 0, stream>>>(ciw0, pos0);
    pos_kernel<<<30000, 256, 0, stream>>>(ciw1, pos1);
    feat_init<<<30000, 256, 0, stream>>>(voxel_feat, pos0, feat, featb, featq);
    cvt_bf16<<<(589824 + 255) / 256, 256, 0, stream>>>(ipw, ipwb, 589824);
    cvt_bf16<<<(196608 + 255) / 256, 256, 0, stream>>>(ow,  owb,  196608);
    cvt_bf16<<<(393216 + 255) / 256, 256, 0, stream>>>(l1w, l1wb, 393216);
    cvt_bf16<<<(393216 + 255) / 256, 256, 0, stream>>>(l2w, l2wb, 393216);
    wtrans_kernel<<<(2 * 9 * 16384 + 255) / 256, 256, 0, stream>>>(cw, cwb);

    for (int li = 0; li < 12; ++li) {
        const unsigned short* posNext = ((li + 1) & 1) ? pos1 : pos0;
        int s = li & 1;
        // QKV: q/k blocks read featq (= feat+pos), v block reads featb — all async
        gemm_mfma<128, true, false, true, false><<<dim3(469, 3), 256, 0, stream>>>(
            featq, featb, ipwb + (size_t)li * 49152, ipb + li * 384, qkvb, NVOX, 384,
            nullptr, nullptr, nullptr, nullptr, nullptr, nullptr);
        attn_kernel<25, 8><<<dim3(960, 1), 256, 0, stream>>>(qkvb, vx[s][0], 24000, obufb);
        attn_kernel<100, 2><<<dim3(360, 4), 256, 0, stream>>>(qkvb, vx[s][1], 36000, obufb);
        // out-proj + residual + LN1 fused (no featq write)
        gemm_mfma<128, false, false, false, true><<<dim3(469, 1), 256, 0, stream>>>(
            obufb, nullptr, owb + (size_t)li * 16384, obp + li * 128, nullptr, NVOX, 128,
            feat, featb, nullptr, nullptr, g1 + li * 128, b1 + li * 128);
        // FFN1 + GELU, bf16 out
        gemm_mfma<128, false, true, true, false><<<dim3(469, 2), 256, 0, stream>>>(
            featb, nullptr, l1wb + (size_t)li * 32768, l1b + li * 256, qkvb, NVOX, 256,
            nullptr, nullptr, nullptr, nullptr, nullptr, nullptr);
        // FFN2 + residual + LN2 fused, also emits featq for next layer
        gemm_mfma<256, false, false, false, true><<<dim3(469, 1), 256, 0, stream>>>(
            qkvb, nullptr, l2wb + (size_t)li * 32768, l2b + li * 128, nullptr, NVOX, 128,
            feat, featb, featq, posNext, g2 + li * 128, b2 + li * 128);
    }

    hipMemsetAsync(canvas1, 0, (size_t)43438080 * 2, stream);
    halo_zero<<<(2 * 9680 * 16 + 255) / 256, 256, 0, stream>>>(canvas2);
    scatter_kernel<<<(NVOX * 16 + 255) / 256, 256, 0, stream>>>(feat, coors, canvas1);
    conv_mfma<false><<<dim3(13, 100, 2), 512, 0, stream>>>(
        canvas1, cwb, bng, bnb, bnm, bnv, canvas2);
    conv_mfma<true><<<dim3(13, 100, 2), 512, 0, stream>>>(
        canvas2, cwb + 9 * 16384, bng + 128, bnb + 128, bnm + 128, bnv + 128, (float*)d_out);
}

// Round 12
// 2523.744 us; speedup vs baseline: 1.0815x; 1.0815x over previous
//
#include <hip/hip_runtime.h>
#include <math.h>

#define NVOX 60000

typedef __attribute__((ext_vector_type(8))) short short8v;            // 8 bf16 raw
typedef __attribute__((ext_vector_type(8))) unsigned short ushort8v;  // 8 bf16 raw
typedef __attribute__((ext_vector_type(4))) float f32x4;

static __device__ __forceinline__ unsigned short f2bf(float f) {
    unsigned u = __float_as_uint(f);
    unsigned r = (u + 0x7fffu + ((u >> 16) & 1u)) >> 16;
    return (unsigned short)r;
}
static __device__ __forceinline__ float bf2f(unsigned short h) {
    return __uint_as_float(((unsigned)h) << 16);
}
// async global->LDS 16B per lane: dest = lds_base + lane*16 (wave-uniform base)
static __device__ __forceinline__ void gll16(const unsigned short* g, unsigned short* l) {
    __builtin_amdgcn_global_load_lds(
        (const __attribute__((address_space(1))) unsigned*)g,
        (__attribute__((address_space(3))) unsigned*)l,
        16, 0, 0);
}

// ---------------------------------------------------------------- pos embed (bf16 out)
__global__ __launch_bounds__(256) void pos_kernel(const float* __restrict__ ciw,
                                                  unsigned short* __restrict__ pos) {
    int idx = blockIdx.x * 256 + threadIdx.x;
    if (idx >= NVOX * 128) return;
    int n = idx >> 7, d = idx & 127;
    int c = d >> 6, t = (d & 63) >> 1;
    float xy = ciw[n * 2 + c] - 6.0f;
    float inv = exp2f((float)t * (13.287712379549449f / 32.0f)); // 10000^(t/32)
    float e = xy / inv;
    pos[idx] = f2bf((d & 1) ? cosf(e) : sinf(e));
}

// ------------------------------------------------------- fp32 -> bf16 convert
__global__ __launch_bounds__(256) void cvt_bf16(const float* __restrict__ in,
                                                unsigned short* __restrict__ out, int n) {
    int idx = blockIdx.x * 256 + threadIdx.x;
    if (idx < n) out[idx] = f2bf(in[idx]);
}

// -------------------------------------------- feat init: f32 copy + bf16 shadow
__global__ __launch_bounds__(256) void feat_init(const float* __restrict__ vf,
                                                 float* __restrict__ feat,
                                                 unsigned short* __restrict__ featb) {
    int idx = blockIdx.x * 256 + threadIdx.x;
    if (idx >= NVOX * 128) return;
    float v = vf[idx];
    feat[idx] = v;
    featb[idx] = f2bf(v);
}

// ----------------------------------------- MFMA GEMM: C = A*W^T + b (+variants)
// A bf16 [M,KTOT]; W bf16 [N,KTOT]; optional A+=Aadd (bf16, K=128) for
// col-blocks < add_nblk; CBF16 out staged via LDS for coalesced ushort8 stores;
// LNF: fused residual+LN epilogue (N==128, gridDim.y==1).
template<int KTOT, bool ADD, bool GELU, bool CBF16, bool LNF>
__global__ __launch_bounds__(256) void gemm_mfma(
    const unsigned short* __restrict__ A, const unsigned short* __restrict__ Aadd, int add_nblk,
    const unsigned short* __restrict__ W, const float* __restrict__ bias,
    void* __restrict__ Cp, int M, int ldc,
    float* __restrict__ feat, unsigned short* __restrict__ featb,
    const float* __restrict__ lng, const float* __restrict__ lnb)
{
    __shared__ unsigned short smem[128 * 128];   // As(16KB) + Ws(16KB), reused as Cs(32KB)
    __shared__ float2 lnsum[128][2];
    unsigned short* As = smem;
    unsigned short* Ws = smem + 128 * 64;
    const int tid = threadIdx.x;
    const int lane = tid & 63, wave = tid >> 6;
    const int wr = wave >> 1, wc = wave & 1;
    const int llo = lane & 15, lhi = lane >> 4;
    const int m0 = blockIdx.x * 128;
    const int n0 = blockIdx.y * 128;
    const bool addp = ADD && ((int)blockIdx.y < add_nblk);
    const int gr = lane >> 3;           // row within 8-row group
    const int gc = (lane & 7) ^ gr;     // pre-swizzled source chunk
    f32x4 acc[4][4] = {};

    for (int k0 = 0; k0 < KTOT; k0 += 64) {
        #pragma unroll
        for (int p = 0; p < 4; ++p) {
            int r0 = wave * 32 + p * 8;
            gll16(W + (size_t)(n0 + r0 + gr) * KTOT + k0 + gc * 8, &Ws[r0 * 64]);
        }
        if (!addp) {
            #pragma unroll
            for (int p = 0; p < 4; ++p) {
                int r0 = wave * 32 + p * 8;
                gll16(A + (size_t)(m0 + r0 + gr) * KTOT + k0 + gc * 8, &As[r0 * 64]);
            }
        } else {
            #pragma unroll
            for (int p = 0; p < 4; ++p) {
                int c = tid + p * 256;
                int r = c >> 3, c16 = c & 7;
                int m = m0 + r;
                short8v av = {};
                if (m < M) {
                    ushort8v fa = *reinterpret_cast<const ushort8v*>(A + (size_t)m * KTOT + k0 + c16 * 8);
                    ushort8v pa = *reinterpret_cast<const ushort8v*>(Aadd + (size_t)m * 128 + k0 + c16 * 8);
                    #pragma unroll
                    for (int q = 0; q < 8; ++q) av[q] = (short)f2bf(bf2f(fa[q]) + bf2f(pa[q]));
                }
                *reinterpret_cast<short8v*>((char*)As + r * 128 + ((c16 * 16) ^ ((r & 7) << 4))) = av;
            }
        }
        __syncthreads();
        #pragma unroll
        for (int kk = 0; kk < 2; ++kk) {
            int kb = kk * 64 + lhi * 16;
            short8v af[4], bf[4];
            #pragma unroll
            for (int i = 0; i < 4; ++i) {
                int r = wr * 64 + i * 16 + llo;
                af[i] = *reinterpret_cast<const short8v*>((const char*)As + r * 128 + (kb ^ ((r & 7) << 4)));
                int cc = wc * 64 + i * 16 + llo;
                bf[i] = *reinterpret_cast<const short8v*>((const char*)Ws + cc * 128 + (kb ^ ((cc & 7) << 4)));
            }
            #pragma unroll
            for (int i = 0; i < 4; ++i)
                #pragma unroll
                for (int j = 0; j < 4; ++j)
                    acc[i][j] = __builtin_amdgcn_mfma_f32_16x16x32_bf16(af[i], bf[j], acc[i][j], 0, 0, 0);
        }
        __syncthreads();
    }

    if (LNF) {
        // residual + LN: pass 1 computes x = feat + acc + bias -> stored back in acc
        float s1[4][4] = {}, s2[4][4] = {};
        #pragma unroll
        for (int i = 0; i < 4; ++i)
            #pragma unroll
            for (int rg = 0; rg < 4; ++rg) {
                int m = m0 + wr * 64 + i * 16 + lhi * 4 + rg;
                if (m < M) {
                    #pragma unroll
                    for (int j = 0; j < 4; ++j) {
                        int n = wc * 64 + j * 16 + llo;
                        float x = feat[(size_t)m * 128 + n] + acc[i][j][rg] + bias[n];
                        acc[i][j][rg] = x;
                        s1[i][rg] += x; s2[i][rg] += x * x;
                    }
                }
            }
        #pragma unroll
        for (int i = 0; i < 4; ++i)
            #pragma unroll
            for (int rg = 0; rg < 4; ++rg) {
                #pragma unroll
                for (int off = 1; off < 16; off <<= 1) {
                    s1[i][rg] += __shfl_xor(s1[i][rg], off);
                    s2[i][rg] += __shfl_xor(s2[i][rg], off);
                }
                if (llo == 0)
                    lnsum[wr * 64 + i * 16 + lhi * 4 + rg][wc] = make_float2(s1[i][rg], s2[i][rg]);
            }
        __syncthreads();
        #pragma unroll
        for (int i = 0; i < 4; ++i)
            #pragma unroll
            for (int rg = 0; rg < 4; ++rg) {
                int r = wr * 64 + i * 16 + lhi * 4 + rg;
                int m = m0 + r;
                if (m >= M) continue;
                float2 a0 = lnsum[r][0], a1 = lnsum[r][1];
                float mu = (a0.x + a1.x) * 0.0078125f;
                float var = fmaxf((a0.y + a1.y) * 0.0078125f - mu * mu, 0.f);
                float inv = rsqrtf(var + 1e-5f);
                #pragma unroll
                for (int j = 0; j < 4; ++j) {
                    int n = wc * 64 + j * 16 + llo;
                    float v = (acc[i][j][rg] - mu) * inv * lng[n] + lnb[n];
                    feat[(size_t)m * 128 + n] = v;
                    featb[(size_t)m * 128 + n] = f2bf(v);
                }
            }
    } else if (CBF16) {
        #pragma unroll
        for (int j = 0; j < 4; ++j) {
            int nl = wc * 64 + j * 16 + llo;
            float bn = bias[n0 + nl];
            #pragma unroll
            for (int i = 0; i < 4; ++i)
                #pragma unroll
                for (int rg = 0; rg < 4; ++rg) {
                    float v = acc[i][j][rg] + bn;
                    if (GELU) v = 0.5f * v * (1.0f + erff(v * 0.7071067811865475f));
                    smem[(wr * 64 + i * 16 + lhi * 4 + rg) * 128 + nl] = f2bf(v);
                }
        }
        __syncthreads();
        unsigned short* C = (unsigned short*)Cp;
        #pragma unroll
        for (int c = 0; c < 8; ++c) {
            int idx = tid + c * 256;
            int r = idx >> 4, ch = idx & 15;
            if (m0 + r < M)
                *reinterpret_cast<ushort8v*>(C + (size_t)(m0 + r) * ldc + n0 + ch * 8) =
                    *reinterpret_cast<const ushort8v*>(&smem[r * 128 + ch * 8]);
        }
    } else {
        float* C = (float*)Cp;
        #pragma unroll
        for (int j = 0; j < 4; ++j) {
            int n = n0 + wc * 64 + j * 16 + llo;
            float bn = bias[n];
            #pragma unroll
            for (int i = 0; i < 4; ++i)
                #pragma unroll
                for (int rg = 0; rg < 4; ++rg) {
                    int m = m0 + wr * 64 + i * 16 + lhi * 4 + rg;
                    if (m < M) {
                        float v = acc[i][j][rg] + bn;
                        if (GELU) v = 0.5f * v * (1.0f + erff(v * 0.7071067811865475f));
                        C[(size_t)m * ldc + n] = v;
                    }
                }
        }
    }
}

// ------------------------------------------------------- windowed attention (bf16 qkv)
template<int CAPT, int HG>
__global__ __launch_bounds__(256) void attn_kernel(
    const unsigned short* __restrict__ qkv, const int* __restrict__ vlist, int nvox,
    unsigned short* __restrict__ oout)
{
    __shared__ float Ks[CAPT][HG * 16];
    __shared__ float Vs[CAPT][HG * 16];
    __shared__ int vl[CAPT];
    const int w = blockIdx.x;
    const int hb = blockIdx.y * HG;
    const int tid = threadIdx.x;
    const int T = min(CAPT, nvox - w * CAPT);
    if (tid < T) vl[tid] = vlist[w * CAPT + tid];
    constexpr int R8 = HG * 2;
    for (int idx = tid; idx < T * R8; idx += 256) {
        int t = idx / R8, c8 = (idx % R8) * 8;
        int vox = vlist[w * CAPT + t];
        const unsigned short* base = qkv + (size_t)vox * 384 + hb * 16 + c8;
        ushort8v kv = *reinterpret_cast<const ushort8v*>(base + 128);
        ushort8v vv = *reinterpret_cast<const ushort8v*>(base + 256);
        #pragma unroll
        for (int q = 0; q < 8; ++q) { Ks[t][c8 + q] = bf2f(kv[q]); Vs[t][c8 + q] = bf2f(vv[q]); }
    }
    __syncthreads();
    const int ITEMS = T * HG;
    for (int item = tid; item < ITEMS; item += 256) {
        int h = item & (HG - 1);
        int q = item / HG;
        int vq = vl[q];
        const unsigned short* qb = qkv + (size_t)vq * 384 + (hb + h) * 16;
        ushort8v qa = *reinterpret_cast<const ushort8v*>(qb);
        ushort8v qc = *reinterpret_cast<const ushort8v*>(qb + 8);
        float4 q0 = make_float4(bf2f(qa[0]), bf2f(qa[1]), bf2f(qa[2]), bf2f(qa[3]));
        float4 q1 = make_float4(bf2f(qa[4]), bf2f(qa[5]), bf2f(qa[6]), bf2f(qa[7]));
        float4 q2 = make_float4(bf2f(qc[0]), bf2f(qc[1]), bf2f(qc[2]), bf2f(qc[3]));
        float4 q3 = make_float4(bf2f(qc[4]), bf2f(qc[5]), bf2f(qc[6]), bf2f(qc[7]));
        float mx = -INFINITY, l = 0.f;
        float4 o0 = make_float4(0,0,0,0), o1 = o0, o2 = o0, o3 = o0;
        for (int t = 0; t < T; ++t) {
            const float4* kr = reinterpret_cast<const float4*>(&Ks[t][h * 16]);
            float4 k0 = kr[0], k1 = kr[1], k2 = kr[2], k3 = kr[3];
            float s = q0.x*k0.x + q0.y*k0.y + q0.z*k0.z + q0.w*k0.w
                    + q1.x*k1.x + q1.y*k1.y + q1.z*k1.z + q1.w*k1.w
                    + q2.x*k2.x + q2.y*k2.y + q2.z*k2.z + q2.w*k2.w
                    + q3.x*k3.x + q3.y*k3.y + q3.z*k3.z + q3.w*k3.w;
            s *= 0.25f;
            float mo = mx;
            mx = fmaxf(mx, s);
            float cc = __expf(mo - mx);
            float p  = __expf(s - mx);
            l = l * cc + p;
            const float4* vr = reinterpret_cast<const float4*>(&Vs[t][h * 16]);
            float4 v0 = vr[0], v1 = vr[1], v2 = vr[2], v3 = vr[3];
            o0.x = o0.x*cc + p*v0.x; o0.y = o0.y*cc + p*v0.y; o0.z = o0.z*cc + p*v0.z; o0.w = o0.w*cc + p*v0.w;
            o1.x = o1.x*cc + p*v1.x; o1.y = o1.y*cc + p*v1.y; o1.z = o1.z*cc + p*v1.z; o1.w = o1.w*cc + p*v1.w;
            o2.x = o2.x*cc + p*v2.x; o2.y = o2.y*cc + p*v2.y; o2.z = o2.z*cc + p*v2.z; o2.w = o2.w*cc + p*v2.w;
            o3.x = o3.x*cc + p*v3.x; o3.y = o3.y*cc + p*v3.y; o3.z = o3.z*cc + p*v3.z; o3.w = o3.w*cc + p*v3.w;
        }
        float rl = 1.0f / l;
        ushort8v r0, r1;
        r0[0]=f2bf(o0.x*rl); r0[1]=f2bf(o0.y*rl); r0[2]=f2bf(o0.z*rl); r0[3]=f2bf(o0.w*rl);
        r0[4]=f2bf(o1.x*rl); r0[5]=f2bf(o1.y*rl); r0[6]=f2bf(o1.z*rl); r0[7]=f2bf(o1.w*rl);
        r1[0]=f2bf(o2.x*rl); r1[1]=f2bf(o2.y*rl); r1[2]=f2bf(o2.z*rl); r1[3]=f2bf(o2.w*rl);
        r1[4]=f2bf(o3.x*rl); r1[5]=f2bf(o3.y*rl); r1[6]=f2bf(o3.z*rl); r1[7]=f2bf(o3.w*rl);
        unsigned short* op = oout + (size_t)vq * 128 + (hb + h) * 16;
        *reinterpret_cast<ushort8v*>(op) = r0;
        *reinterpret_cast<ushort8v*>(op + 8) = r1;
    }
}

// ------------------- BEV scatter into padded canvas (bf16, stride 420)
__global__ __launch_bounds__(256) void scatter_kernel(const float* __restrict__ feat,
    const int* __restrict__ coors, unsigned short* __restrict__ canvas)
{
    int idx = blockIdx.x * 256 + threadIdx.x;
    if (idx >= NVOX * 16) return;
    int n = idx >> 4, c8 = (idx & 15) << 3;
    int b = coors[n * 4], y = coors[n * 4 + 2], x = coors[n * 4 + 3];
    const float* src = feat + (size_t)n * 128 + c8;
    float4 u0 = *reinterpret_cast<const float4*>(src);
    float4 u1 = *reinterpret_cast<const float4*>(src + 4);
    ushort8v v;
    v[0]=f2bf(u0.x); v[1]=f2bf(u0.y); v[2]=f2bf(u0.z); v[3]=f2bf(u0.w);
    v[4]=f2bf(u1.x); v[5]=f2bf(u1.y); v[6]=f2bf(u1.z); v[7]=f2bf(u1.w);
    size_t p = (((size_t)b * 404 + y + 2) * 420 + x + 2) * 128 + c8;
    *reinterpret_cast<ushort8v*>(canvas + p) = v;
}

// --------- zero the halo of a stride-420 padded canvas
__global__ __launch_bounds__(256) void halo_zero(unsigned short* __restrict__ c) {
    int idx = blockIdx.x * 256 + threadIdx.x;
    if (idx >= 2 * 9680 * 16) return;
    int b = idx / (9680 * 16);
    int rem = idx % (9680 * 16);
    int p = rem >> 4, ch = (rem & 15) * 8;
    int y, x;
    if (p < 1680) { int ry = p / 420; y = (ry < 2) ? ry : ry + 400; x = p % 420; }
    else { int q = p - 1680; y = 2 + q / 20; int cx = q % 20; x = (cx < 2) ? cx : cx + 400; }
    ushort8v z = {};
    *reinterpret_cast<ushort8v*>(c + (((size_t)b * 404 + y) * 420 + x) * 128 + ch) = z;
}

// ------------------- conv weight re-layout -> bf16 [i][ky*3+kx][cout][cin]
__global__ __launch_bounds__(256) void wtrans_kernel(const float* __restrict__ cw,
                                                     unsigned short* __restrict__ wbuf)
{
    int idx = blockIdx.x * 256 + threadIdx.x;
    if (idx >= 2 * 9 * 128 * 128) return;
    int ci = idx & 127;
    int co = (idx >> 7) & 127;
    int kk = (idx >> 14) % 9;
    int i  = idx / (9 * 16384);
    wbuf[idx] = f2bf(cw[(((size_t)i * 128 + co) * 128 + ci) * 9 + kk]);
}

// ---------------- 3x3 dilated(2) conv + BN + ReLU, LDS-A once + LDS-W double-buffered
template<bool NCHW_OUT>
__global__ __launch_bounds__(512, 1) void conv_mfma(
    const unsigned short* __restrict__ in, const unsigned short* __restrict__ wbuf,
    const float* __restrict__ g, const float* __restrict__ bsh,
    const float* __restrict__ bm, const float* __restrict__ bv,
    void* __restrict__ out)
{
    __shared__ unsigned short Ab[8 * 36 * 128];
    __shared__ unsigned short Wb[2 * 128 * 128];
    const int tid = threadIdx.x;
    const int lane = tid & 63, wave = tid >> 6;
    const int cog = wave & 1, yg = wave >> 1;
    const int llo = lane & 15, lhi = lane >> 4;
    const int x0 = blockIdx.x * 32, y0 = blockIdx.y * 4, b = blockIdx.z;
    const int c16s = lane & 15;

    #pragma unroll
    for (int it = 0; it < 9; ++it) {
        int gidx = it * 32 + wave * 4 + lhi;
        int row = gidx / 36, xi = gidx % 36;
        gll16(in + (((size_t)b * 404 + y0 + row) * 420 + x0 + xi) * 128 + ((c16s ^ (xi & 15)) * 8),
              Ab + (size_t)(it * 512 + wave * 64) * 8);
    }
    {
        const unsigned short* wt = wbuf;
        #pragma unroll
        for (int it = 0; it < 4; ++it) {
            int co = it * 32 + wave * 4 + lhi;
            gll16(wt + co * 128 + ((c16s ^ (co & 15)) * 8),
                  Wb + (size_t)(it * 512 + wave * 64) * 8);
        }
    }
    __syncthreads();

    f32x4 acc[2][4] = {};
    #pragma unroll
    for (int t = 0; t < 9; ++t) {
        if (t < 8) {
            const unsigned short* wt = wbuf + (size_t)(t + 1) * 16384;
            unsigned short* dst = Wb + ((t + 1) & 1) * 16384;
            #pragma unroll
            for (int it = 0; it < 4; ++it) {
                int co = it * 32 + wave * 4 + lhi;
                gll16(wt + co * 128 + ((c16s ^ (co & 15)) * 8),
                      dst + (size_t)(it * 512 + wave * 64) * 8);
            }
        }
        const unsigned short* Wp = Wb + (t & 1) * 16384;
        const int ky = t / 3, kx = t % 3;
        const int r = yg + 2 * ky;
        #pragma unroll
        for (int kk = 0; kk < 4; ++kk) {
            short8v a[2], w[4];
            #pragma unroll
            for (int i = 0; i < 2; ++i) {
                int xi = i * 16 + llo + 2 * kx;
                a[i] = *reinterpret_cast<const short8v*>(
                    (const char*)Ab + (r * 36 + xi) * 256 + ((kk * 64 + lhi * 16) ^ ((xi & 15) << 4)));
            }
            #pragma unroll
            for (int j = 0; j < 4; ++j) {
                int co = cog * 64 + j * 16 + llo;
                w[j] = *reinterpret_cast<const short8v*>(
                    (const char*)Wp + co * 256 + ((kk * 64 + lhi * 16) ^ ((co & 15) << 4)));
            }
            #pragma unroll
            for (int i = 0; i < 2; ++i)
                #pragma unroll
                for (int j = 0; j < 4; ++j)
                    acc[i][j] = __builtin_amdgcn_mfma_f32_16x16x32_bf16(a[i], w[j], acc[i][j], 0, 0, 0);
        }
        __syncthreads();
    }

    const int y = y0 + yg;
    if (NCHW_OUT) {
        #pragma unroll
        for (int j = 0; j < 4; ++j) {
            int co = cog * 64 + j * 16 + llo;
            float scale = rsqrtf(bv[co] + 1e-3f) * g[co];
            float shift = bsh[co] - bm[co] * scale;
            #pragma unroll
            for (int i = 0; i < 2; ++i) {
                int px = x0 + i * 16 + lhi * 4;
                if (px < 400) {
                    float4 v;
                    v.x = fmaxf(acc[i][j][0] * scale + shift, 0.f);
                    v.y = fmaxf(acc[i][j][1] * scale + shift, 0.f);
                    v.z = fmaxf(acc[i][j][2] * scale + shift, 0.f);
                    v.w = fmaxf(acc[i][j][3] * scale + shift, 0.f);
                    *reinterpret_cast<float4*>(
                        (float*)out + (((size_t)b * 128 + co) * 400 + y) * 400 + px) = v;
                }
            }
        }
    } else {
        unsigned short* Cw = Wb + wave * 2048;
        #pragma unroll
        for (int j = 0; j < 4; ++j) {
            int co = cog * 64 + j * 16 + llo;
            float scale = rsqrtf(bv[co] + 1e-3f) * g[co];
            float shift = bsh[co] - bm[co] * scale;
            #pragma unroll
            for (int i = 0; i < 2; ++i)
                #pragma unroll
                for (int rg = 0; rg < 4; ++rg)
                    Cw[(i * 16 + lhi * 4 + rg) * 64 + j * 16 + llo] =
                        f2bf(fmaxf(acc[i][j][rg] * scale + shift, 0.f));
        }
        #pragma unroll
        for (int s = 0; s < 4; ++s) {
            int pxl = s * 8 + (lane >> 3);
            int oct = lane & 7;
            int px = x0 + pxl;
            if (px < 400)
                *reinterpret_cast<ushort8v*>(
                    (unsigned short*)out + (((size_t)b * 404 + y + 2) * 420 + px + 2) * 128
                                         + cog * 64 + oct * 8) =
                    *reinterpret_cast<const ushort8v*>(&Cw[pxl * 64 + oct * 8]);
        }
    }
}

// ---------------------------------------------------------------- launcher
extern "C" void kernel_launch(void* const* d_in, const int* in_sizes, int n_in,
                              void* d_out, int out_size, void* d_ws, size_t ws_size,
                              hipStream_t stream) {
    const float* voxel_feat = (const float*)d_in[0];
    const int*   coors      = (const int*)d_in[1];
    const float* ciw0       = (const float*)d_in[2];
    const float* ciw1       = (const float*)d_in[3];
    const int* vx[2][2] = {{(const int*)d_in[4], (const int*)d_in[6]},
                           {(const int*)d_in[8], (const int*)d_in[10]}};
    const float* ipw = (const float*)d_in[12];
    const float* ipb = (const float*)d_in[13];
    const float* ow  = (const float*)d_in[14];
    const float* obp = (const float*)d_in[15];
    const float* l1w = (const float*)d_in[16];
    const float* l1b = (const float*)d_in[17];
    const float* l2w = (const float*)d_in[18];
    const float* l2b = (const float*)d_in[19];
    const float* g1  = (const float*)d_in[20];
    const float* b1  = (const float*)d_in[21];
    const float* g2  = (const float*)d_in[22];
    const float* b2  = (const float*)d_in[23];
    const float* cw  = (const float*)d_in[24];
    const float* bng = (const float*)d_in[25];
    const float* bnb = (const float*)d_in[26];
    const float* bnm = (const float*)d_in[27];
    const float* bnv = (const float*)d_in[28];

    float* F = (float*)d_ws;
    unsigned short* W0   = (unsigned short*)F;           // bf16 weights: 1,867,776
    unsigned short* ipwb = W0;                           // 589824
    unsigned short* owb  = W0 + 589824;                  // 196608
    unsigned short* l1wb = W0 + 786432;                  // 393216
    unsigned short* l2wb = W0 + 1179648;                 // 393216
    unsigned short* cwb  = W0 + 1572864;                 // 294912
    float* feat = F + 940000;                            // 7.68M f32, ends at 8.62M
    unsigned short* featb = (unsigned short*)(F + 8620000);   // 7.68M bf16
    unsigned short* pos0  = (unsigned short*)(F + 12460000);  // 7.68M bf16
    unsigned short* pos1  = (unsigned short*)(F + 16300000);
    unsigned short* obufb = (unsigned short*)(F + 20140000);
    unsigned short* hbufb = (unsigned short*)(F + 23980000);  // 15.36M bf16
    // conv phase (featb/pos/obuf/hbuf dead; feat live for scatter):
    // padded canvases: [2][404 rows][420 cols][128] bf16 = 43,438,080 ushorts each
    unsigned short* canvas1 = (unsigned short*)(F + 8620000);
    unsigned short* canvas2 = (unsigned short*)(F + 30339040);
    unsigned short* qkvb = (unsigned short*)d_out;       // 23.04M bf16 scratch

    feat_init<<<30000, 256, 0, stream>>>(voxel_feat, feat, featb);
    pos_kernel<<<30000, 256, 0, stream>>>(ciw0, pos0);
    pos_kernel<<<30000, 256, 0, stream>>>(ciw1, pos1);
    cvt_bf16<<<(589824 + 255) / 256, 256, 0, stream>>>(ipw, ipwb, 589824);
    cvt_bf16<<<(196608 + 255) / 256, 256, 0, stream>>>(ow,  owb,  196608);
    cvt_bf16<<<(393216 + 255) / 256, 256, 0, stream>>>(l1w, l1wb, 393216);
    cvt_bf16<<<(393216 + 255) / 256, 256, 0, stream>>>(l2w, l2wb, 393216);
    wtrans_kernel<<<(2 * 9 * 16384 + 255) / 256, 256, 0, stream>>>(cw, cwb);

    for (int li = 0; li < 12; ++li) {
        int s = li & 1;
        const unsigned short* pos = s ? pos1 : pos0;
        gemm_mfma<128, true, false, true, false><<<dim3(469, 3), 256, 0, stream>>>(
            featb, pos, 2, ipwb + (size_t)li * 49152, ipb + li * 384, qkvb, NVOX, 384,
            nullptr, nullptr, nullptr, nullptr);
        attn_kernel<25, 8><<<dim3(960, 1), 256, 0, stream>>>(qkvb, vx[s][0], 24000, obufb);
        attn_kernel<100, 2><<<dim3(360, 4), 256, 0, stream>>>(qkvb, vx[s][1], 36000, obufb);
        gemm_mfma<128, false, false, false, true><<<dim3(469, 1), 256, 0, stream>>>(
            obufb, nullptr, 0, owb + (size_t)li * 16384, obp + li * 128, nullptr, NVOX, 128,
            feat, featb, g1 + li * 128, b1 + li * 128);
        gemm_mfma<128, false, true, true, false><<<dim3(469, 2), 256, 0, stream>>>(
            featb, nullptr, 0, l1wb + (size_t)li * 32768, l1b + li * 256, hbufb, NVOX, 256,
            nullptr, nullptr, nullptr, nullptr);
        gemm_mfma<256, false, false, false, true><<<dim3(469, 1), 256, 0, stream>>>(
            hbufb, nullptr, 0, l2wb + (size_t)li * 32768, l2b + li * 128, nullptr, NVOX, 128,
            feat, featb, g2 + li * 128, b2 + li * 128);
    }

    // BEV: zero canvas1 fully + canvas2 halo only, scatter, conv1, conv2
    hipMemsetAsync(canvas1, 0, (size_t)43438080 * 2, stream);
    halo_zero<<<(2 * 9680 * 16 + 255) / 256, 256, 0, stream>>>(canvas2);
    scatter_kernel<<<(NVOX * 16 + 255) / 256, 256, 0, stream>>>(feat, coors, canvas1);
    conv_mfma<false><<<dim3(13, 100, 2), 512, 0, stream>>>(
        canvas1, cwb, bng, bnb, bnm, bnv, canvas2);
    conv_mfma<true><<<dim3(13, 100, 2), 512, 0, stream>>>(
        canvas2, cwb + 9 * 16384, bng + 128, bnb + 128, bnm + 128, bnv + 128, (float*)d_out);
}

// Round 13
// 2339.858 us; speedup vs baseline: 1.1665x; 1.0786x over previous
//
#include <hip/hip_runtime.h>
#include <math.h>

#define NVOX 60000

typedef __attribute__((ext_vector_type(8))) short short8v;            // 8 bf16 raw
typedef __attribute__((ext_vector_type(8))) unsigned short ushort8v;  // 8 bf16 raw
typedef __attribute__((ext_vector_type(4))) float f32x4;

static __device__ __forceinline__ unsigned short f2bf(float f) {
    unsigned u = __float_as_uint(f);
    unsigned r = (u + 0x7fffu + ((u >> 16) & 1u)) >> 16;
    return (unsigned short)r;
}
static __device__ __forceinline__ float bf2f(unsigned short h) {
    return __uint_as_float(((unsigned)h) << 16);
}
// async global->LDS 16B per lane: dest = lds_base + lane*16 (wave-uniform base)
static __device__ __forceinline__ void gll16(const unsigned short* g, unsigned short* l) {
    __builtin_amdgcn_global_load_lds(
        (const __attribute__((address_space(1))) unsigned*)g,
        (__attribute__((address_space(3))) unsigned*)l,
        16, 0, 0);
}

// ---------------------------------------------------------------- pos embed (bf16 out)
__global__ __launch_bounds__(256) void pos_kernel(const float* __restrict__ ciw,
                                                  unsigned short* __restrict__ pos) {
    int idx = blockIdx.x * 256 + threadIdx.x;
    if (idx >= NVOX * 128) return;
    int n = idx >> 7, d = idx & 127;
    int c = d >> 6, t = (d & 63) >> 1;
    float xy = ciw[n * 2 + c] - 6.0f;
    float inv = exp2f((float)t * (13.287712379549449f / 32.0f)); // 10000^(t/32)
    float e = xy / inv;
    pos[idx] = f2bf((d & 1) ? cosf(e) : sinf(e));
}

// ------------------------------------------------------- fp32 -> bf16 convert
__global__ __launch_bounds__(256) void cvt_bf16(const float* __restrict__ in,
                                                unsigned short* __restrict__ out, int n) {
    int idx = blockIdx.x * 256 + threadIdx.x;
    if (idx < n) out[idx] = f2bf(in[idx]);
}

// ----------------------------------------- MFMA GEMM: C = A*W^T + b (+variants)
// A bf16 [M,KTOT]; W bf16 [N,KTOT]; optional A+=Aadd (bf16, K=128) for
// col-blocks < add_nblk; CBF16 out staged via LDS for coalesced ushort8 stores;
// LNF: fused residual+LN epilogue (N==128, gridDim.y==1), bf16 residual stream.
template<int KTOT, bool ADD, bool GELU, bool CBF16, bool LNF>
__global__ __launch_bounds__(256) void gemm_mfma(
    const unsigned short* __restrict__ A, const unsigned short* __restrict__ Aadd, int add_nblk,
    const unsigned short* __restrict__ W, const float* __restrict__ bias,
    void* __restrict__ Cp, int M, int ldc,
    unsigned short* __restrict__ featb,
    const float* __restrict__ lng, const float* __restrict__ lnb)
{
    __shared__ unsigned short smem[128 * 128];   // As(16KB) + Ws(16KB), reused as Cs(32KB)
    __shared__ float2 lnsum[128][2];
    unsigned short* As = smem;
    unsigned short* Ws = smem + 128 * 64;
    const int tid = threadIdx.x;
    const int lane = tid & 63, wave = tid >> 6;
    const int wr = wave >> 1, wc = wave & 1;
    const int llo = lane & 15, lhi = lane >> 4;
    const int m0 = blockIdx.x * 128;
    const int n0 = blockIdx.y * 128;
    const bool addp = ADD && ((int)blockIdx.y < add_nblk);
    const int gr = lane >> 3;           // row within 8-row group
    const int gc = (lane & 7) ^ gr;     // pre-swizzled source chunk
    f32x4 acc[4][4] = {};

    for (int k0 = 0; k0 < KTOT; k0 += 64) {
        #pragma unroll
        for (int p = 0; p < 4; ++p) {
            int r0 = wave * 32 + p * 8;
            gll16(W + (size_t)(n0 + r0 + gr) * KTOT + k0 + gc * 8, &Ws[r0 * 64]);
        }
        if (!addp) {
            #pragma unroll
            for (int p = 0; p < 4; ++p) {
                int r0 = wave * 32 + p * 8;
                gll16(A + (size_t)(m0 + r0 + gr) * KTOT + k0 + gc * 8, &As[r0 * 64]);
            }
        } else {
            #pragma unroll
            for (int p = 0; p < 4; ++p) {
                int c = tid + p * 256;
                int r = c >> 3, c16 = c & 7;
                int m = m0 + r;
                short8v av = {};
                if (m < M) {
                    ushort8v fa = *reinterpret_cast<const ushort8v*>(A + (size_t)m * KTOT + k0 + c16 * 8);
                    ushort8v pa = *reinterpret_cast<const ushort8v*>(Aadd + (size_t)m * 128 + k0 + c16 * 8);
                    #pragma unroll
                    for (int q = 0; q < 8; ++q) av[q] = (short)f2bf(bf2f(fa[q]) + bf2f(pa[q]));
                }
                *reinterpret_cast<short8v*>((char*)As + r * 128 + ((c16 * 16) ^ ((r & 7) << 4))) = av;
            }
        }
        __syncthreads();
        #pragma unroll
        for (int kk = 0; kk < 2; ++kk) {
            int kb = kk * 64 + lhi * 16;
            short8v af[4], bf[4];
            #pragma unroll
            for (int i = 0; i < 4; ++i) {
                int r = wr * 64 + i * 16 + llo;
                af[i] = *reinterpret_cast<const short8v*>((const char*)As + r * 128 + (kb ^ ((r & 7) << 4)));
                int cc = wc * 64 + i * 16 + llo;
                bf[i] = *reinterpret_cast<const short8v*>((const char*)Ws + cc * 128 + (kb ^ ((cc & 7) << 4)));
            }
            #pragma unroll
            for (int i = 0; i < 4; ++i)
                #pragma unroll
                for (int j = 0; j < 4; ++j)
                    acc[i][j] = __builtin_amdgcn_mfma_f32_16x16x32_bf16(af[i], bf[j], acc[i][j], 0, 0, 0);
        }
        __syncthreads();
    }

    if (LNF) {
        // residual(bf16) + LN: pass 1 computes x = featb + acc + bias -> kept in acc
        float s1[4][4] = {}, s2[4][4] = {};
        #pragma unroll
        for (int i = 0; i < 4; ++i)
            #pragma unroll
            for (int rg = 0; rg < 4; ++rg) {
                int m = m0 + wr * 64 + i * 16 + lhi * 4 + rg;
                if (m < M) {
                    #pragma unroll
                    for (int j = 0; j < 4; ++j) {
                        int n = wc * 64 + j * 16 + llo;
                        float x = bf2f(featb[(size_t)m * 128 + n]) + acc[i][j][rg] + bias[n];
                        acc[i][j][rg] = x;
                        s1[i][rg] += x; s2[i][rg] += x * x;
                    }
                }
            }
        #pragma unroll
        for (int i = 0; i < 4; ++i)
            #pragma unroll
            for (int rg = 0; rg < 4; ++rg) {
                #pragma unroll
                for (int off = 1; off < 16; off <<= 1) {
                    s1[i][rg] += __shfl_xor(s1[i][rg], off);
                    s2[i][rg] += __shfl_xor(s2[i][rg], off);
                }
                if (llo == 0)
                    lnsum[wr * 64 + i * 16 + lhi * 4 + rg][wc] = make_float2(s1[i][rg], s2[i][rg]);
            }
        __syncthreads();
        #pragma unroll
        for (int i = 0; i < 4; ++i)
            #pragma unroll
            for (int rg = 0; rg < 4; ++rg) {
                int r = wr * 64 + i * 16 + lhi * 4 + rg;
                int m = m0 + r;
                if (m >= M) continue;
                float2 a0 = lnsum[r][0], a1 = lnsum[r][1];
                float mu = (a0.x + a1.x) * 0.0078125f;
                float var = fmaxf((a0.y + a1.y) * 0.0078125f - mu * mu, 0.f);
                float inv = rsqrtf(var + 1e-5f);
                #pragma unroll
                for (int j = 0; j < 4; ++j) {
                    int n = wc * 64 + j * 16 + llo;
                    float v = (acc[i][j][rg] - mu) * inv * lng[n] + lnb[n];
                    featb[(size_t)m * 128 + n] = f2bf(v);
                }
            }
    } else if (CBF16) {
        #pragma unroll
        for (int j = 0; j < 4; ++j) {
            int nl = wc * 64 + j * 16 + llo;
            float bn = bias[n0 + nl];
            #pragma unroll
            for (int i = 0; i < 4; ++i)
                #pragma unroll
                for (int rg = 0; rg < 4; ++rg) {
                    float v = acc[i][j][rg] + bn;
                    if (GELU) v = 0.5f * v * (1.0f + erff(v * 0.7071067811865475f));
                    smem[(wr * 64 + i * 16 + lhi * 4 + rg) * 128 + nl] = f2bf(v);
                }
        }
        __syncthreads();
        unsigned short* C = (unsigned short*)Cp;
        #pragma unroll
        for (int c = 0; c < 8; ++c) {
            int idx = tid + c * 256;
            int r = idx >> 4, ch = idx & 15;
            if (m0 + r < M)
                *reinterpret_cast<ushort8v*>(C + (size_t)(m0 + r) * ldc + n0 + ch * 8) =
                    *reinterpret_cast<const ushort8v*>(&smem[r * 128 + ch * 8]);
        }
    } else {
        float* C = (float*)Cp;
        #pragma unroll
        for (int j = 0; j < 4; ++j) {
            int n = n0 + wc * 64 + j * 16 + llo;
            float bn = bias[n];
            #pragma unroll
            for (int i = 0; i < 4; ++i)
                #pragma unroll
                for (int rg = 0; rg < 4; ++rg) {
                    int m = m0 + wr * 64 + i * 16 + lhi * 4 + rg;
                    if (m < M) {
                        float v = acc[i][j][rg] + bn;
                        if (GELU) v = 0.5f * v * (1.0f + erff(v * 0.7071067811865475f));
                        C[(size_t)m * ldc + n] = v;
                    }
                }
        }
    }
}

// ------------------- merged windowed attention: lvl0 (T=25,HG=8) + lvl1 (T=100,HG=2)
// blocks [0,960): lvl0 window w, all 8 heads.  blocks [960,2400): lvl1,
// idx-960 -> w = idx%360, head-pair hb = (idx/360)*2.  ITEMS=200 both.
__global__ __launch_bounds__(256) void attn_merged(
    const unsigned short* __restrict__ qkv, const int* __restrict__ vl0,
    const int* __restrict__ vl1, unsigned short* __restrict__ oout)
{
    __shared__ float Ks[3200];    // lvl0: [25][128] ; lvl1: [100][32]
    __shared__ float Vs[3200];
    __shared__ int vl[100];
    int T, HGsh, hb, w;
    const int* vlist;
    if ((int)blockIdx.x < 960) {
        T = 25; HGsh = 3; hb = 0; w = blockIdx.x; vlist = vl0;
    } else {
        int idx = blockIdx.x - 960;
        T = 100; HGsh = 1; hb = (idx / 360) * 2; w = idx % 360; vlist = vl1;
    }
    const int HG = 1 << HGsh;
    const int rs = HG * 16;            // row stride in floats
    const int tid = threadIdx.x;
    if (tid < T) vl[tid] = vlist[w * T + tid];
    const int r8sh = HGsh + 1;         // chunks per row = HG*2
    for (int idx = tid; idx < (T << r8sh); idx += 256) {
        int t = idx >> r8sh, c8 = (idx & ((1 << r8sh) - 1)) * 8;
        int vox = vlist[w * T + t];
        const unsigned short* base = qkv + (size_t)vox * 384 + hb * 16 + c8;
        ushort8v kv = *reinterpret_cast<const ushort8v*>(base + 128);
        ushort8v vv = *reinterpret_cast<const ushort8v*>(base + 256);
        #pragma unroll
        for (int q = 0; q < 8; ++q) { Ks[t * rs + c8 + q] = bf2f(kv[q]); Vs[t * rs + c8 + q] = bf2f(vv[q]); }
    }
    __syncthreads();
    const int ITEMS = T << HGsh;
    for (int item = tid; item < ITEMS; item += 256) {
        int h = item & (HG - 1);
        int q = item >> HGsh;
        int vq = vl[q];
        const unsigned short* qb = qkv + (size_t)vq * 384 + (hb + h) * 16;
        ushort8v qa = *reinterpret_cast<const ushort8v*>(qb);
        ushort8v qc = *reinterpret_cast<const ushort8v*>(qb + 8);
        float4 q0 = make_float4(bf2f(qa[0]), bf2f(qa[1]), bf2f(qa[2]), bf2f(qa[3]));
        float4 q1 = make_float4(bf2f(qa[4]), bf2f(qa[5]), bf2f(qa[6]), bf2f(qa[7]));
        float4 q2 = make_float4(bf2f(qc[0]), bf2f(qc[1]), bf2f(qc[2]), bf2f(qc[3]));
        float4 q3 = make_float4(bf2f(qc[4]), bf2f(qc[5]), bf2f(qc[6]), bf2f(qc[7]));
        float mx = -INFINITY, l = 0.f;
        float4 o0 = make_float4(0,0,0,0), o1 = o0, o2 = o0, o3 = o0;
        const float* kbase = Ks + h * 16;
        const float* vbase = Vs + h * 16;
        for (int t = 0; t < T; ++t) {
            const float4* kr = reinterpret_cast<const float4*>(kbase + t * rs);
            float4 k0 = kr[0], k1 = kr[1], k2 = kr[2], k3 = kr[3];
            float s = q0.x*k0.x + q0.y*k0.y + q0.z*k0.z + q0.w*k0.w
                    + q1.x*k1.x + q1.y*k1.y + q1.z*k1.z + q1.w*k1.w
                    + q2.x*k2.x + q2.y*k2.y + q2.z*k2.z + q2.w*k2.w
                    + q3.x*k3.x + q3.y*k3.y + q3.z*k3.z + q3.w*k3.w;
            s *= 0.25f;
            float mo = mx;
            mx = fmaxf(mx, s);
            float cc = __expf(mo - mx);
            float p  = __expf(s - mx);
            l = l * cc + p;
            const float4* vr = reinterpret_cast<const float4*>(vbase + t * rs);
            float4 v0 = vr[0], v1 = vr[1], v2 = vr[2], v3 = vr[3];
            o0.x = o0.x*cc + p*v0.x; o0.y = o0.y*cc + p*v0.y; o0.z = o0.z*cc + p*v0.z; o0.w = o0.w*cc + p*v0.w;
            o1.x = o1.x*cc + p*v1.x; o1.y = o1.y*cc + p*v1.y; o1.z = o1.z*cc + p*v1.z; o1.w = o1.w*cc + p*v1.w;
            o2.x = o2.x*cc + p*v2.x; o2.y = o2.y*cc + p*v2.y; o2.z = o2.z*cc + p*v2.z; o2.w = o2.w*cc + p*v2.w;
            o3.x = o3.x*cc + p*v3.x; o3.y = o3.y*cc + p*v3.y; o3.z = o3.z*cc + p*v3.z; o3.w = o3.w*cc + p*v3.w;
        }
        float rl = 1.0f / l;
        ushort8v r0, r1;
        r0[0]=f2bf(o0.x*rl); r0[1]=f2bf(o0.y*rl); r0[2]=f2bf(o0.z*rl); r0[3]=f2bf(o0.w*rl);
        r0[4]=f2bf(o1.x*rl); r0[5]=f2bf(o1.y*rl); r0[6]=f2bf(o1.z*rl); r0[7]=f2bf(o1.w*rl);
        r1[0]=f2bf(o2.x*rl); r1[1]=f2bf(o2.y*rl); r1[2]=f2bf(o2.z*rl); r1[3]=f2bf(o2.w*rl);
        r1[4]=f2bf(o3.x*rl); r1[5]=f2bf(o3.y*rl); r1[6]=f2bf(o3.z*rl); r1[7]=f2bf(o3.w*rl);
        unsigned short* op = oout + (size_t)vq * 128 + (hb + h) * 16;
        *reinterpret_cast<ushort8v*>(op) = r0;
        *reinterpret_cast<ushort8v*>(op + 8) = r1;
    }
}

// ------------------- BEV scatter into padded canvas (bf16 copy, stride 420)
__global__ __launch_bounds__(256) void scatter_kernel(const unsigned short* __restrict__ featb,
    const int* __restrict__ coors, unsigned short* __restrict__ canvas)
{
    int idx = blockIdx.x * 256 + threadIdx.x;
    if (idx >= NVOX * 16) return;
    int n = idx >> 4, c8 = (idx & 15) << 3;
    int b = coors[n * 4], y = coors[n * 4 + 2], x = coors[n * 4 + 3];
    size_t p = (((size_t)b * 404 + y + 2) * 420 + x + 2) * 128 + c8;
    *reinterpret_cast<ushort8v*>(canvas + p) =
        *reinterpret_cast<const ushort8v*>(featb + (size_t)n * 128 + c8);
}

// --------- zero the halo of a stride-420 padded canvas
__global__ __launch_bounds__(256) void halo_zero(unsigned short* __restrict__ c) {
    int idx = blockIdx.x * 256 + threadIdx.x;
    if (idx >= 2 * 9680 * 16) return;
    int b = idx / (9680 * 16);
    int rem = idx % (9680 * 16);
    int p = rem >> 4, ch = (rem & 15) * 8;
    int y, x;
    if (p < 1680) { int ry = p / 420; y = (ry < 2) ? ry : ry + 400; x = p % 420; }
    else { int q = p - 1680; y = 2 + q / 20; int cx = q % 20; x = (cx < 2) ? cx : cx + 400; }
    ushort8v z = {};
    *reinterpret_cast<ushort8v*>(c + (((size_t)b * 404 + y) * 420 + x) * 128 + ch) = z;
}

// ------------------- conv weight re-layout -> bf16 [i][ky*3+kx][cout][cin]
__global__ __launch_bounds__(256) void wtrans_kernel(const float* __restrict__ cw,
                                                     unsigned short* __restrict__ wbuf)
{
    int idx = blockIdx.x * 256 + threadIdx.x;
    if (idx >= 2 * 9 * 128 * 128) return;
    int ci = idx & 127;
    int co = (idx >> 7) & 127;
    int kk = (idx >> 14) % 9;
    int i  = idx / (9 * 16384);
    wbuf[idx] = f2bf(cw[(((size_t)i * 128 + co) * 128 + ci) * 9 + kk]);
}

// ---------------- 3x3 dilated(2) conv + BN + ReLU, LDS-A once + LDS-W double-buffered
template<bool NCHW_OUT>
__global__ __launch_bounds__(512, 1) void conv_mfma(
    const unsigned short* __restrict__ in, const unsigned short* __restrict__ wbuf,
    const float* __restrict__ g, const float* __restrict__ bsh,
    const float* __restrict__ bm, const float* __restrict__ bv,
    void* __restrict__ out)
{
    __shared__ unsigned short Ab[8 * 36 * 128];
    __shared__ unsigned short Wb[2 * 128 * 128];
    const int tid = threadIdx.x;
    const int lane = tid & 63, wave = tid >> 6;
    const int cog = wave & 1, yg = wave >> 1;
    const int llo = lane & 15, lhi = lane >> 4;
    const int x0 = blockIdx.x * 32, y0 = blockIdx.y * 4, b = blockIdx.z;
    const int c16s = lane & 15;

    #pragma unroll
    for (int it = 0; it < 9; ++it) {
        int gidx = it * 32 + wave * 4 + lhi;
        int row = gidx / 36, xi = gidx % 36;
        gll16(in + (((size_t)b * 404 + y0 + row) * 420 + x0 + xi) * 128 + ((c16s ^ (xi & 15)) * 8),
              Ab + (size_t)(it * 512 + wave * 64) * 8);
    }
    {
        const unsigned short* wt = wbuf;
        #pragma unroll
        for (int it = 0; it < 4; ++it) {
            int co = it * 32 + wave * 4 + lhi;
            gll16(wt + co * 128 + ((c16s ^ (co & 15)) * 8),
                  Wb + (size_t)(it * 512 + wave * 64) * 8);
        }
    }
    __syncthreads();

    f32x4 acc[2][4] = {};
    #pragma unroll
    for (int t = 0; t < 9; ++t) {
        if (t < 8) {
            const unsigned short* wt = wbuf + (size_t)(t + 1) * 16384;
            unsigned short* dst = Wb + ((t + 1) & 1) * 16384;
            #pragma unroll
            for (int it = 0; it < 4; ++it) {
                int co = it * 32 + wave * 4 + lhi;
                gll16(wt + co * 128 + ((c16s ^ (co & 15)) * 8),
                      dst + (size_t)(it * 512 + wave * 64) * 8);
            }
        }
        const unsigned short* Wp = Wb + (t & 1) * 16384;
        const int ky = t / 3, kx = t % 3;
        const int r = yg + 2 * ky;
        #pragma unroll
        for (int kk = 0; kk < 4; ++kk) {
            short8v a[2], w[4];
            #pragma unroll
            for (int i = 0; i < 2; ++i) {
                int xi = i * 16 + llo + 2 * kx;
                a[i] = *reinterpret_cast<const short8v*>(
                    (const char*)Ab + (r * 36 + xi) * 256 + ((kk * 64 + lhi * 16) ^ ((xi & 15) << 4)));
            }
            #pragma unroll
            for (int j = 0; j < 4; ++j) {
                int co = cog * 64 + j * 16 + llo;
                w[j] = *reinterpret_cast<const short8v*>(
                    (const char*)Wp + co * 256 + ((kk * 64 + lhi * 16) ^ ((co & 15) << 4)));
            }
            #pragma unroll
            for (int i = 0; i < 2; ++i)
                #pragma unroll
                for (int j = 0; j < 4; ++j)
                    acc[i][j] = __builtin_amdgcn_mfma_f32_16x16x32_bf16(a[i], w[j], acc[i][j], 0, 0, 0);
        }
        __syncthreads();
    }

    const int y = y0 + yg;
    if (NCHW_OUT) {
        #pragma unroll
        for (int j = 0; j < 4; ++j) {
            int co = cog * 64 + j * 16 + llo;
            float scale = rsqrtf(bv[co] + 1e-3f) * g[co];
            float shift = bsh[co] - bm[co] * scale;
            #pragma unroll
            for (int i = 0; i < 2; ++i) {
                int px = x0 + i * 16 + lhi * 4;
                if (px < 400) {
                    float4 v;
                    v.x = fmaxf(acc[i][j][0] * scale + shift, 0.f);
                    v.y = fmaxf(acc[i][j][1] * scale + shift, 0.f);
                    v.z = fmaxf(acc[i][j][2] * scale + shift, 0.f);
                    v.w = fmaxf(acc[i][j][3] * scale + shift, 0.f);
                    *reinterpret_cast<float4*>(
                        (float*)out + (((size_t)b * 128 + co) * 400 + y) * 400 + px) = v;
                }
            }
        }
    } else {
        unsigned short* Cw = Wb + wave * 2048;
        #pragma unroll
        for (int j = 0; j < 4; ++j) {
            int co = cog * 64 + j * 16 + llo;
            float scale = rsqrtf(bv[co] + 1e-3f) * g[co];
            float shift = bsh[co] - bm[co] * scale;
            #pragma unroll
            for (int i = 0; i < 2; ++i)
                #pragma unroll
                for (int rg = 0; rg < 4; ++rg)
                    Cw[(i * 16 + lhi * 4 + rg) * 64 + j * 16 + llo] =
                        f2bf(fmaxf(acc[i][j][rg] * scale + shift, 0.f));
        }
        #pragma unroll
        for (int s = 0; s < 4; ++s) {
            int pxl = s * 8 + (lane >> 3);
            int oct = lane & 7;
            int px = x0 + pxl;
            if (px < 400)
                *reinterpret_cast<ushort8v*>(
                    (unsigned short*)out + (((size_t)b * 404 + y + 2) * 420 + px + 2) * 128
                                         + cog * 64 + oct * 8) =
                    *reinterpret_cast<const ushort8v*>(&Cw[pxl * 64 + oct * 8]);
        }
    }
}

// ---------------------------------------------------------------- launcher
extern "C" void kernel_launch(void* const* d_in, const int* in_sizes, int n_in,
                              void* d_out, int out_size, void* d_ws, size_t ws_size,
                              hipStream_t stream) {
    const float* voxel_feat = (const float*)d_in[0];
    const int*   coors      = (const int*)d_in[1];
    const float* ciw0       = (const float*)d_in[2];
    const float* ciw1       = (const float*)d_in[3];
    const int* vx[2][2] = {{(const int*)d_in[4], (const int*)d_in[6]},
                           {(const int*)d_in[8], (const int*)d_in[10]}};
    const float* ipw = (const float*)d_in[12];
    const float* ipb = (const float*)d_in[13];
    const float* ow  = (const float*)d_in[14];
    const float* obp = (const float*)d_in[15];
    const float* l1w = (const float*)d_in[16];
    const float* l1b = (const float*)d_in[17];
    const float* l2w = (const float*)d_in[18];
    const float* l2b = (const float*)d_in[19];
    const float* g1  = (const float*)d_in[20];
    const float* b1  = (const float*)d_in[21];
    const float* g2  = (const float*)d_in[22];
    const float* b2  = (const float*)d_in[23];
    const float* cw  = (const float*)d_in[24];
    const float* bng = (const float*)d_in[25];
    const float* bnb = (const float*)d_in[26];
    const float* bnm = (const float*)d_in[27];
    const float* bnv = (const float*)d_in[28];

    float* F = (float*)d_ws;
    unsigned short* W0   = (unsigned short*)F;           // bf16 weights: 1,867,776 ushorts
    unsigned short* ipwb = W0;                           // 589824
    unsigned short* owb  = W0 + 589824;                  // 196608
    unsigned short* l1wb = W0 + 786432;                  // 393216
    unsigned short* l2wb = W0 + 1179648;                 // 393216
    unsigned short* cwb  = W0 + 1572864;                 // 294912 (ends 1,867,776 = F+933,888 f32)
    unsigned short* featb = (unsigned short*)(F + 940000);    // 7.68M ushorts, ends F+4,780,000
    unsigned short* pos0  = (unsigned short*)(F + 4780000);   // ends F+8,620,000
    unsigned short* pos1  = (unsigned short*)(F + 8620000);   // ends F+12,460,000
    unsigned short* obufb = (unsigned short*)(F + 12460000);  // ends F+16,300,000
    unsigned short* hbufb = (unsigned short*)(F + 16300000);  // 15.36M ushorts, ends F+23,980,000
    // conv phase (pos/obuf/hbuf dead; featb live for scatter):
    // padded canvases [2][404][420][128] bf16 = 43,438,080 ushorts each
    unsigned short* canvas1 = (unsigned short*)(F + 8620000);   // ends F+30,339,040
    unsigned short* canvas2 = (unsigned short*)(F + 30339040);  // ends F+52,058,080
    unsigned short* qkvb = (unsigned short*)d_out;       // 23.04M ushorts scratch

    cvt_bf16<<<30000, 256, 0, stream>>>(voxel_feat, featb, NVOX * 128);
    pos_kernel<<<30000, 256, 0, stream>>>(ciw0, pos0);
    pos_kernel<<<30000, 256, 0, stream>>>(ciw1, pos1);
    cvt_bf16<<<(589824 + 255) / 256, 256, 0, stream>>>(ipw, ipwb, 589824);
    cvt_bf16<<<(196608 + 255) / 256, 256, 0, stream>>>(ow,  owb,  196608);
    cvt_bf16<<<(393216 + 255) / 256, 256, 0, stream>>>(l1w, l1wb, 393216);
    cvt_bf16<<<(393216 + 255) / 256, 256, 0, stream>>>(l2w, l2wb, 393216);
    wtrans_kernel<<<(2 * 9 * 16384 + 255) / 256, 256, 0, stream>>>(cw, cwb);

    for (int li = 0; li < 12; ++li) {
        int s = li & 1;
        const unsigned short* pos = s ? pos1 : pos0;
        gemm_mfma<128, true, false, true, false><<<dim3(469, 3), 256, 0, stream>>>(
            featb, pos, 2, ipwb + (size_t)li * 49152, ipb + li * 384, qkvb, NVOX, 384,
            nullptr, nullptr, nullptr);
        attn_merged<<<2400, 256, 0, stream>>>(qkvb, vx[s][0], vx[s][1], obufb);
        gemm_mfma<128, false, false, false, true><<<dim3(469, 1), 256, 0, stream>>>(
            obufb, nullptr, 0, owb + (size_t)li * 16384, obp + li * 128, nullptr, NVOX, 128,
            featb, g1 + li * 128, b1 + li * 128);
        gemm_mfma<128, false, true, true, false><<<dim3(469, 2), 256, 0, stream>>>(
            featb, nullptr, 0, l1wb + (size_t)li * 32768, l1b + li * 256, hbufb, NVOX, 256,
            nullptr, nullptr, nullptr);
        gemm_mfma<256, false, false, false, true><<<dim3(469, 1), 256, 0, stream>>>(
            hbufb, nullptr, 0, l2wb + (size_t)li * 32768, l2b + li * 128, nullptr, NVOX, 128,
            featb, g2 + li * 128, b2 + li * 128);
    }

    // BEV: zero canvas1 fully + canvas2 halo only, scatter, conv1, conv2
    hipMemsetAsync(canvas1, 0, (size_t)43438080 * 2, stream);
    halo_zero<<<(2 * 9680 * 16 + 255) / 256, 256, 0, stream>>>(canvas2);
    scatter_kernel<<<(NVOX * 16 + 255) / 256, 256, 0, stream>>>(featb, coors, canvas1);
    conv_mfma<false><<<dim3(13, 100, 2), 512, 0, stream>>>(
        canvas1, cwb, bng, bnb, bnm, bnv, canvas2);
    conv_mfma<true><<<dim3(13, 100, 2), 512, 0, stream>>>(
        canvas2, cwb + 9 * 16384, bng + 128, bnb + 128, bnm + 128, bnv + 128, (float*)d_out);
}

// Round 15
// 2189.341 us; speedup vs baseline: 1.2467x; 1.0688x over previous
//
#include <hip/hip_runtime.h>
#include <math.h>

#define NVOX 60000

typedef __attribute__((ext_vector_type(8))) short short8v;            // 8 bf16 raw
typedef __attribute__((ext_vector_type(8))) unsigned short ushort8v;  // 8 bf16 raw
typedef __attribute__((ext_vector_type(4))) float f32x4;

static __device__ __forceinline__ unsigned short f2bf(float f) {
    unsigned u = __float_as_uint(f);
    unsigned r = (u + 0x7fffu + ((u >> 16) & 1u)) >> 16;
    return (unsigned short)r;
}
static __device__ __forceinline__ float bf2f(unsigned short h) {
    return __uint_as_float(((unsigned)h) << 16);
}
// async global->LDS 16B per lane: dest = lds_base + lane*16 (wave-uniform base)
static __device__ __forceinline__ void gll16(const unsigned short* g, unsigned short* l) {
    __builtin_amdgcn_global_load_lds(
        (const __attribute__((address_space(1))) unsigned*)g,
        (__attribute__((address_space(3))) unsigned*)l,
        16, 0, 0);
}

// ---------------------------------------------------------------- pos embed (bf16 out)
__global__ __launch_bounds__(256) void pos_kernel(const float* __restrict__ ciw,
                                                  unsigned short* __restrict__ pos) {
    int idx = blockIdx.x * 256 + threadIdx.x;
    if (idx >= NVOX * 128) return;
    int n = idx >> 7, d = idx & 127;
    int c = d >> 6, t = (d & 63) >> 1;
    float xy = ciw[n * 2 + c] - 6.0f;
    float inv = exp2f((float)t * (13.287712379549449f / 32.0f)); // 10000^(t/32)
    float e = xy / inv;
    pos[idx] = f2bf((d & 1) ? cosf(e) : sinf(e));
}

// ------------------------------------------------------- fp32 -> bf16 convert
__global__ __launch_bounds__(256) void cvt_bf16(const float* __restrict__ in,
                                                unsigned short* __restrict__ out, int n) {
    int idx = blockIdx.x * 256 + threadIdx.x;
    if (idx < n) out[idx] = f2bf(in[idx]);
}

// ----------------------------------------- MFMA GEMM: C = A*W^T + b (+variants)
// MT-row tile (64 or 128). A bf16 [M,KTOT]; W bf16 [N,KTOT]; optional A+=Aadd
// (bf16, K=128) for col-blocks < add_nblk; CBF16 out staged via LDS;
// LNF: fused residual+LN epilogue (N==128, gridDim.y==1), bf16 residual stream.
template<int MT, int KTOT, bool ADD, bool GELU, bool CBF16, bool LNF>
__global__ __launch_bounds__(256) void gemm_mfma(
    const unsigned short* __restrict__ A, const unsigned short* __restrict__ Aadd, int add_nblk,
    const unsigned short* __restrict__ W, const float* __restrict__ bias,
    void* __restrict__ Cp, int M, int ldc,
    unsigned short* __restrict__ featb,
    const float* __restrict__ lng, const float* __restrict__ lnb)
{
    constexpr int RF = MT / 32;                 // row frags per wave
    __shared__ unsigned short smem[(MT + 128) * 64];   // As(MT*64) + Ws(128*64); reused as Cs(MT*128)
    __shared__ float2 lnsum[MT][2];
    unsigned short* As = smem;
    unsigned short* Ws = smem + MT * 64;
    const int tid = threadIdx.x;
    const int lane = tid & 63, wave = tid >> 6;
    const int wr = wave >> 1, wc = wave & 1;
    const int llo = lane & 15, lhi = lane >> 4;
    const int m0 = blockIdx.x * MT;
    const int n0 = blockIdx.y * 128;
    const bool addp = ADD && ((int)blockIdx.y < add_nblk);
    const int gr = lane >> 3;           // row within 8-row group
    const int gc = (lane & 7) ^ gr;     // pre-swizzled source chunk
    f32x4 acc[RF][4] = {};

    for (int k0 = 0; k0 < KTOT; k0 += 64) {
        #pragma unroll
        for (int p = 0; p < 4; ++p) {
            int r0 = wave * 32 + p * 8;
            gll16(W + (size_t)(n0 + r0 + gr) * KTOT + k0 + gc * 8, &Ws[r0 * 64]);
        }
        if (!addp) {
            #pragma unroll
            for (int p = 0; p < RF; ++p) {
                int r0 = wave * (RF * 8) + p * 8;   // RF*8 rows per wave (4 waves cover MT)
                gll16(A + (size_t)(m0 + r0 + gr) * KTOT + k0 + gc * 8, &As[r0 * 64]);
            }
        } else {
            #pragma unroll
            for (int p = 0; p < RF; ++p) {
                int c = tid + p * 256;
                int r = c >> 3, c16 = c & 7;
                int m = m0 + r;
                short8v av = {};
                if (m < M) {
                    ushort8v fa = *reinterpret_cast<const ushort8v*>(A + (size_t)m * KTOT + k0 + c16 * 8);
                    ushort8v pa = *reinterpret_cast<const ushort8v*>(Aadd + (size_t)m * 128 + k0 + c16 * 8);
                    #pragma unroll
                    for (int q = 0; q < 8; ++q) av[q] = (short)f2bf(bf2f(fa[q]) + bf2f(pa[q]));
                }
                *reinterpret_cast<short8v*>((char*)As + r * 128 + ((c16 * 16) ^ ((r & 7) << 4))) = av;
            }
        }
        __syncthreads();
        #pragma unroll
        for (int kk = 0; kk < 2; ++kk) {
            int kb = kk * 64 + lhi * 16;
            short8v af[RF], bf[4];
            #pragma unroll
            for (int i = 0; i < RF; ++i) {
                int r = wr * (MT / 2) + i * 16 + llo;
                af[i] = *reinterpret_cast<const short8v*>((const char*)As + r * 128 + (kb ^ ((r & 7) << 4)));
            }
            #pragma unroll
            for (int j = 0; j < 4; ++j) {
                int cc = wc * 64 + j * 16 + llo;
                bf[j] = *reinterpret_cast<const short8v*>((const char*)Ws + cc * 128 + (kb ^ ((cc & 7) << 4)));
            }
            #pragma unroll
            for (int i = 0; i < RF; ++i)
                #pragma unroll
                for (int j = 0; j < 4; ++j)
                    acc[i][j] = __builtin_amdgcn_mfma_f32_16x16x32_bf16(af[i], bf[j], acc[i][j], 0, 0, 0);
        }
        __syncthreads();
    }

    if (LNF) {
        // residual(bf16) + LN: pass 1 computes x = featb + acc + bias -> kept in acc
        float s1[RF][4] = {}, s2[RF][4] = {};
        #pragma unroll
        for (int i = 0; i < RF; ++i)
            #pragma unroll
            for (int rg = 0; rg < 4; ++rg) {
                int m = m0 + wr * (MT / 2) + i * 16 + lhi * 4 + rg;
                if (m < M) {
                    #pragma unroll
                    for (int j = 0; j < 4; ++j) {
                        int n = wc * 64 + j * 16 + llo;
                        float x = bf2f(featb[(size_t)m * 128 + n]) + acc[i][j][rg] + bias[n];
                        acc[i][j][rg] = x;
                        s1[i][rg] += x; s2[i][rg] += x * x;
                    }
                }
            }
        #pragma unroll
        for (int i = 0; i < RF; ++i)
            #pragma unroll
            for (int rg = 0; rg < 4; ++rg) {
                #pragma unroll
                for (int off = 1; off < 16; off <<= 1) {
                    s1[i][rg] += __shfl_xor(s1[i][rg], off);
                    s2[i][rg] += __shfl_xor(s2[i][rg], off);
                }
                if (llo == 0)
                    lnsum[wr * (MT / 2) + i * 16 + lhi * 4 + rg][wc] = make_float2(s1[i][rg], s2[i][rg]);
            }
        __syncthreads();
        #pragma unroll
        for (int i = 0; i < RF; ++i)
            #pragma unroll
            for (int rg = 0; rg < 4; ++rg) {
                int r = wr * (MT / 2) + i * 16 + lhi * 4 + rg;
                int m = m0 + r;
                if (m >= M) continue;
                float2 a0 = lnsum[r][0], a1 = lnsum[r][1];
                float mu = (a0.x + a1.x) * 0.0078125f;
                float var = fmaxf((a0.y + a1.y) * 0.0078125f - mu * mu, 0.f);
                float inv = rsqrtf(var + 1e-5f);
                #pragma unroll
                for (int j = 0; j < 4; ++j) {
                    int n = wc * 64 + j * 16 + llo;
                    float v = (acc[i][j][rg] - mu) * inv * lng[n] + lnb[n];
                    featb[(size_t)m * 128 + n] = f2bf(v);
                }
            }
    } else if (CBF16) {
        #pragma unroll
        for (int j = 0; j < 4; ++j) {
            int nl = wc * 64 + j * 16 + llo;
            float bn = bias[n0 + nl];
            #pragma unroll
            for (int i = 0; i < RF; ++i)
                #pragma unroll
                for (int rg = 0; rg < 4; ++rg) {
                    float v = acc[i][j][rg] + bn;
                    if (GELU) v = 0.5f * v * (1.0f + erff(v * 0.7071067811865475f));
                    smem[(wr * (MT / 2) + i * 16 + lhi * 4 + rg) * 128 + nl] = f2bf(v);
                }
        }
        __syncthreads();
        unsigned short* C = (unsigned short*)Cp;
        #pragma unroll
        for (int c = 0; c < MT / 16; ++c) {
            int idx = tid + c * 256;
            int r = idx >> 4, ch = idx & 15;
            if (m0 + r < M)
                *reinterpret_cast<ushort8v*>(C + (size_t)(m0 + r) * ldc + n0 + ch * 8) =
                    *reinterpret_cast<const ushort8v*>(&smem[r * 128 + ch * 8]);
        }
    } else {
        float* C = (float*)Cp;
        #pragma unroll
        for (int j = 0; j < 4; ++j) {
            int n = n0 + wc * 64 + j * 16 + llo;
            float bn = bias[n];
            #pragma unroll
            for (int i = 0; i < RF; ++i)
                #pragma unroll
                for (int rg = 0; rg < 4; ++rg) {
                    int m = m0 + wr * (MT / 2) + i * 16 + lhi * 4 + rg;
                    if (m < M) {
                        float v = acc[i][j][rg] + bn;
                        if (GELU) v = 0.5f * v * (1.0f + erff(v * 0.7071067811865475f));
                        C[(size_t)m * ldc + n] = v;
                    }
                }
        }
    }
}

// ------------------- merged windowed attention: lvl0 (T=25,HG=8) + lvl1 (T=100,HG=2)
__global__ __launch_bounds__(256) void attn_merged(
    const unsigned short* __restrict__ qkv, const int* __restrict__ vl0,
    const int* __restrict__ vl1, unsigned short* __restrict__ oout)
{
    __shared__ float Ks[3200];    // lvl0: [25][128] ; lvl1: [100][32]
    __shared__ float Vs[3200];
    __shared__ int vl[100];
    int T, HGsh, hb, w;
    const int* vlist;
    if ((int)blockIdx.x < 960) {
        T = 25; HGsh = 3; hb = 0; w = blockIdx.x; vlist = vl0;
    } else {
        int idx = blockIdx.x - 960;
        T = 100; HGsh = 1; hb = (idx / 360) * 2; w = idx % 360; vlist = vl1;
    }
    const int HG = 1 << HGsh;
    const int rs = HG * 16;            // row stride in floats
    const int tid = threadIdx.x;
    if (tid < T) vl[tid] = vlist[w * T + tid];
    const int r8sh = HGsh + 1;         // chunks per row = HG*2
    for (int idx = tid; idx < (T << r8sh); idx += 256) {
        int t = idx >> r8sh, c8 = (idx & ((1 << r8sh) - 1)) * 8;
        int vox = vlist[w * T + t];
        const unsigned short* base = qkv + (size_t)vox * 384 + hb * 16 + c8;
        ushort8v kv = *reinterpret_cast<const ushort8v*>(base + 128);
        ushort8v vv = *reinterpret_cast<const ushort8v*>(base + 256);
        #pragma unroll
        for (int q = 0; q < 8; ++q) { Ks[t * rs + c8 + q] = bf2f(kv[q]); Vs[t * rs + c8 + q] = bf2f(vv[q]); }
    }
    __syncthreads();
    const int ITEMS = T << HGsh;
    for (int item = tid; item < ITEMS; item += 256) {
        int h = item & (HG - 1);
        int q = item >> HGsh;
        int vq = vl[q];
        const unsigned short* qb = qkv + (size_t)vq * 384 + (hb + h) * 16;
        ushort8v qa = *reinterpret_cast<const ushort8v*>(qb);
        ushort8v qc = *reinterpret_cast<const ushort8v*>(qb + 8);
        float4 q0 = make_float4(bf2f(qa[0]), bf2f(qa[1]), bf2f(qa[2]), bf2f(qa[3]));
        float4 q1 = make_float4(bf2f(qa[4]), bf2f(qa[5]), bf2f(qa[6]), bf2f(qa[7]));
        float4 q2 = make_float4(bf2f(qc[0]), bf2f(qc[1]), bf2f(qc[2]), bf2f(qc[3]));
        float4 q3 = make_float4(bf2f(qc[4]), bf2f(qc[5]), bf2f(qc[6]), bf2f(qc[7]));
        float mx = -INFINITY, l = 0.f;
        float4 o0 = make_float4(0,0,0,0), o1 = o0, o2 = o0, o3 = o0;
        const float* kbase = Ks + h * 16;
        const float* vbase = Vs + h * 16;
        for (int t = 0; t < T; ++t) {
            const float4* kr = reinterpret_cast<const float4*>(kbase + t * rs);
            float4 k0 = kr[0], k1 = kr[1], k2 = kr[2], k3 = kr[3];
            float s = q0.x*k0.x + q0.y*k0.y + q0.z*k0.z + q0.w*k0.w
                    + q1.x*k1.x + q1.y*k1.y + q1.z*k1.z + q1.w*k1.w
                    + q2.x*k2.x + q2.y*k2.y + q2.z*k2.z + q2.w*k2.w
                    + q3.x*k3.x + q3.y*k3.y + q3.z*k3.z + q3.w*k3.w;
            s *= 0.25f;
            float mo = mx;
            mx = fmaxf(mx, s);
            float cc = __expf(mo - mx);
            float p  = __expf(s - mx);
            l = l * cc + p;
            const float4* vr = reinterpret_cast<const float4*>(vbase + t * rs);
            float4 v0 = vr[0], v1 = vr[1], v2 = vr[2], v3 = vr[3];
            o0.x = o0.x*cc + p*v0.x; o0.y = o0.y*cc + p*v0.y; o0.z = o0.z*cc + p*v0.z; o0.w = o0.w*cc + p*v0.w;
            o1.x = o1.x*cc + p*v1.x; o1.y = o1.y*cc + p*v1.y; o1.z = o1.z*cc + p*v1.z; o1.w = o1.w*cc + p*v1.w;
            o2.x = o2.x*cc + p*v2.x; o2.y = o2.y*cc + p*v2.y; o2.z = o2.z*cc + p*v2.z; o2.w = o2.w*cc + p*v2.w;
            o3.x = o3.x*cc + p*v3.x; o3.y = o3.y*cc + p*v3.y; o3.z = o3.z*cc + p*v3.z; o3.w = o3.w*cc + p*v3.w;
        }
        float rl = 1.0f / l;
        ushort8v r0, r1;
        r0[0]=f2bf(o0.x*rl); r0[1]=f2bf(o0.y*rl); r0[2]=f2bf(o0.z*rl); r0[3]=f2bf(o0.w*rl);
        r0[4]=f2bf(o1.x*rl); r0[5]=f2bf(o1.y*rl); r0[6]=f2bf(o1.z*rl); r0[7]=f2bf(o1.w*rl);
        r1[0]=f2bf(o2.x*rl); r1[1]=f2bf(o2.y*rl); r1[2]=f2bf(o2.z*rl); r1[3]=f2bf(o2.w*rl);
        r1[4]=f2bf(o3.x*rl); r1[5]=f2bf(o3.y*rl); r1[6]=f2bf(o3.z*rl); r1[7]=f2bf(o3.w*rl);
        unsigned short* op = oout + (size_t)vq * 128 + (hb + h) * 16;
        *reinterpret_cast<ushort8v*>(op) = r0;
        *reinterpret_cast<ushort8v*>(op + 8) = r1;
    }
}

// ------------------- BEV scatter into padded canvas (bf16 copy, stride 420)
__global__ __launch_bounds__(256) void scatter_kernel(const unsigned short* __restrict__ featb,
    const int* __restrict__ coors, unsigned short* __restrict__ canvas)
{
    int idx = blockIdx.x * 256 + threadIdx.x;
    if (idx >= NVOX * 16) return;
    int n = idx >> 4, c8 = (idx & 15) << 3;
    int b = coors[n * 4], y = coors[n * 4 + 2], x = coors[n * 4 + 3];
    size_t p = (((size_t)b * 404 + y + 2) * 420 + x + 2) * 128 + c8;
    *reinterpret_cast<ushort8v*>(canvas + p) =
        *reinterpret_cast<const ushort8v*>(featb + (size_t)n * 128 + c8);
}

// --------- zero the halo of a stride-420 padded canvas
__global__ __launch_bounds__(256) void halo_zero(unsigned short* __restrict__ c) {
    int idx = blockIdx.x * 256 + threadIdx.x;
    if (idx >= 2 * 9680 * 16) return;
    int b = idx / (9680 * 16);
    int rem = idx % (9680 * 16);
    int p = rem >> 4, ch = (rem & 15) * 8;
    int y, x;
    if (p < 1680) { int ry = p / 420; y = (ry < 2) ? ry : ry + 400; x = p % 420; }
    else { int q = p - 1680; y = 2 + q / 20; int cx = q % 20; x = (cx < 2) ? cx : cx + 400; }
    ushort8v z = {};
    *reinterpret_cast<ushort8v*>(c + (((size_t)b * 404 + y) * 420 + x) * 128 + ch) = z;
}

// ------------------- conv weight re-layout -> bf16 [i][ky*3+kx][cout][cin]
__global__ __launch_bounds__(256) void wtrans_kernel(const float* __restrict__ cw,
                                                     unsigned short* __restrict__ wbuf)
{
    int idx = blockIdx.x * 256 + threadIdx.x;
    if (idx >= 2 * 9 * 128 * 128) return;
    int ci = idx & 127;
    int co = (idx >> 7) & 127;
    int kk = (idx >> 14) % 9;
    int i  = idx / (9 * 16384);
    wbuf[idx] = f2bf(cw[(((size_t)i * 128 + co) * 128 + ci) * 9 + kk]);
}

// ---------------- 3x3 dilated(2) conv + BN + ReLU, LDS-A once + LDS-W double-buffered
template<bool NCHW_OUT>
__global__ __launch_bounds__(512, 1) void conv_mfma(
    const unsigned short* __restrict__ in, const unsigned short* __restrict__ wbuf,
    const float* __restrict__ g, const float* __restrict__ bsh,
    const float* __restrict__ bm, const float* __restrict__ bv,
    void* __restrict__ out)
{
    __shared__ unsigned short Ab[8 * 36 * 128];
    __shared__ unsigned short Wb[2 * 128 * 128];
    const int tid = threadIdx.x;
    const int lane = tid & 63, wave = tid >> 6;
    const int cog = wave & 1, yg = wave >> 1;
    const int llo = lane & 15, lhi = lane >> 4;
    const int x0 = blockIdx.x * 32, y0 = blockIdx.y * 4, b = blockIdx.z;
    const int c16s = lane & 15;

    #pragma unroll
    for (int it = 0; it < 9; ++it) {
        int gidx = it * 32 + wave * 4 + lhi;
        int row = gidx / 36, xi = gidx % 36;
        gll16(in + (((size_t)b * 404 + y0 + row) * 420 + x0 + xi) * 128 + ((c16s ^ (xi & 15)) * 8),
              Ab + (size_t)(it * 512 + wave * 64) * 8);
    }
    {
        const unsigned short* wt = wbuf;
        #pragma unroll
        for (int it = 0; it < 4; ++it) {
            int co = it * 32 + wave * 4 + lhi;
            gll16(wt + co * 128 + ((c16s ^ (co & 15)) * 8),
                  Wb + (size_t)(it * 512 + wave * 64) * 8);
        }
    }
    __syncthreads();

    f32x4 acc[2][4] = {};
    #pragma unroll
    for (int t = 0; t < 9; ++t) {
        if (t < 8) {
            const unsigned short* wt = wbuf + (size_t)(t + 1) * 16384;
            unsigned short* dst = Wb + ((t + 1) & 1) * 16384;
            #pragma unroll
            for (int it = 0; it < 4; ++it) {
                int co = it * 32 + wave * 4 + lhi;
                gll16(wt + co * 128 + ((c16s ^ (co & 15)) * 8),
                      dst + (size_t)(it * 512 + wave * 64) * 8);
            }
        }
        const unsigned short* Wp = Wb + (t & 1) * 16384;
        const int ky = t / 3, kx = t % 3;
        const int r = yg + 2 * ky;
        #pragma unroll
        for (int kk = 0; kk < 4; ++kk) {
            short8v a[2], w[4];
            #pragma unroll
            for (int i = 0; i < 2; ++i) {
                int xi = i * 16 + llo + 2 * kx;
                a[i] = *reinterpret_cast<const short8v*>(
                    (const char*)Ab + (r * 36 + xi) * 256 + ((kk * 64 + lhi * 16) ^ ((xi & 15) << 4)));
            }
            #pragma unroll
            for (int j = 0; j < 4; ++j) {
                int co = cog * 64 + j * 16 + llo;
                w[j] = *reinterpret_cast<const short8v*>(
                    (const char*)Wp + co * 256 + ((kk * 64 + lhi * 16) ^ ((co & 15) << 4)));
            }
            #pragma unroll
            for (int i = 0; i < 2; ++i)
                #pragma unroll
                for (int j = 0; j < 4; ++j)
                    acc[i][j] = __builtin_amdgcn_mfma_f32_16x16x32_bf16(a[i], w[j], acc[i][j], 0, 0, 0);
        }
        __syncthreads();
    }

    const int y = y0 + yg;
    if (NCHW_OUT) {
        #pragma unroll
        for (int j = 0; j < 4; ++j) {
            int co = cog * 64 + j * 16 + llo;
            float scale = rsqrtf(bv[co] + 1e-3f) * g[co];
            float shift = bsh[co] - bm[co] * scale;
            #pragma unroll
            for (int i = 0; i < 2; ++i) {
                int px = x0 + i * 16 + lhi * 4;
                if (px < 400) {
                    float4 v;
                    v.x = fmaxf(acc[i][j][0] * scale + shift, 0.f);
                    v.y = fmaxf(acc[i][j][1] * scale + shift, 0.f);
                    v.z = fmaxf(acc[i][j][2] * scale + shift, 0.f);
                    v.w = fmaxf(acc[i][j][3] * scale + shift, 0.f);
                    *reinterpret_cast<float4*>(
                        (float*)out + (((size_t)b * 128 + co) * 400 + y) * 400 + px) = v;
                }
            }
        }
    } else {
        unsigned short* Cw = Wb + wave * 2048;
        #pragma unroll
        for (int j = 0; j < 4; ++j) {
            int co = cog * 64 + j * 16 + llo;
            float scale = rsqrtf(bv[co] + 1e-3f) * g[co];
            float shift = bsh[co] - bm[co] * scale;
            #pragma unroll
            for (int i = 0; i < 2; ++i)
                #pragma unroll
                for (int rg = 0; rg < 4; ++rg)
                    Cw[(i * 16 + lhi * 4 + rg) * 64 + j * 16 + llo] =
                        f2bf(fmaxf(acc[i][j][rg] * scale + shift, 0.f));
        }
        #pragma unroll
        for (int s = 0; s < 4; ++s) {
            int pxl = s * 8 + (lane >> 3);
            int oct = lane & 7;
            int px = x0 + pxl;
            if (px < 400)
                *reinterpret_cast<ushort8v*>(
                    (unsigned short*)out + (((size_t)b * 404 + y + 2) * 420 + px + 2) * 128
                                         + cog * 64 + oct * 8) =
                    *reinterpret_cast<const ushort8v*>(&Cw[pxl * 64 + oct * 8]);
        }
    }
}

// ---------------------------------------------------------------- launcher
extern "C" void kernel_launch(void* const* d_in, const int* in_sizes, int n_in,
                              void* d_out, int out_size, void* d_ws, size_t ws_size,
                              hipStream_t stream) {
    const float* voxel_feat = (const float*)d_in[0];
    const int*   coors      = (const int*)d_in[1];
    const float* ciw0       = (const float*)d_in[2];
    const float* ciw1       = (const float*)d_in[3];
    const int* vx[2][2] = {{(const int*)d_in[4], (const int*)d_in[6]},
                           {(const int*)d_in[8], (const int*)d_in[10]}};
    const float* ipw = (const float*)d_in[12];
    const float* ipb = (const float*)d_in[13];
    const float* ow  = (const float*)d_in[14];
    const float* obp = (const float*)d_in[15];
    const float* l1w = (const float*)d_in[16];
    const float* l1b = (const float*)d_in[17];
    const float* l2w = (const float*)d_in[18];
    const float* l2b = (const float*)d_in[19];
    const float* g1  = (const float*)d_in[20];
    const float* b1  = (const float*)d_in[21];
    const float* g2  = (const float*)d_in[22];
    const float* b2  = (const float*)d_in[23];
    const float* cw  = (const float*)d_in[24];
    const float* bng = (const float*)d_in[25];
    const float* bnb = (const float*)d_in[26];
    const float* bnm = (const float*)d_in[27];
    const float* bnv = (const float*)d_in[28];

    float* F = (float*)d_ws;
    unsigned short* W0   = (unsigned short*)F;           // bf16 weights: 1,867,776 ushorts
    unsigned short* ipwb = W0;                           // 589824
    unsigned short* owb  = W0 + 589824;                  // 196608
    unsigned short* l1wb = W0 + 786432;                  // 393216
    unsigned short* l2wb = W0 + 1179648;                 // 393216
    unsigned short* cwb  = W0 + 1572864;                 // 294912
    unsigned short* featb = (unsigned short*)(F + 940000);    // 7.68M ushorts
    unsigned short* pos0  = (unsigned short*)(F + 4780000);
    unsigned short* pos1  = (unsigned short*)(F + 8620000);
    unsigned short* obufb = (unsigned short*)(F + 12460000);
    unsigned short* hbufb = (unsigned short*)(F + 16300000);  // 15.36M ushorts
    // conv phase: padded canvases [2][404][420][128] bf16 = 43,438,080 ushorts each
    unsigned short* canvas1 = (unsigned short*)(F + 8620000);
    unsigned short* canvas2 = (unsigned short*)(F + 30339040);
    unsigned short* qkvb = (unsigned short*)d_out;       // 23.04M ushorts scratch

    cvt_bf16<<<30000, 256, 0, stream>>>(voxel_feat, featb, NVOX * 128);
    pos_kernel<<<30000, 256, 0, stream>>>(ciw0, pos0);
    pos_kernel<<<30000, 256, 0, stream>>>(ciw1, pos1);
    cvt_bf16<<<(589824 + 255) / 256, 256, 0, stream>>>(ipw, ipwb, 589824);
    cvt_bf16<<<(196608 + 255) / 256, 256, 0, stream>>>(ow,  owb,  196608);
    cvt_bf16<<<(393216 + 255) / 256, 256, 0, stream>>>(l1w, l1wb, 393216);
    cvt_bf16<<<(393216 + 255) / 256, 256, 0, stream>>>(l2w, l2wb, 393216);
    wtrans_kernel<<<(2 * 9 * 16384 + 255) / 256, 256, 0, stream>>>(cw, cwb);

    for (int li = 0; li < 12; ++li) {
        int s = li & 1;
        const unsigned short* pos = s ? pos1 : pos0;
        gemm_mfma<64, 128, true, false, true, false><<<dim3(938, 3), 256, 0, stream>>>(
            featb, pos, 2, ipwb + (size_t)li * 49152, ipb + li * 384, qkvb, NVOX, 384,
            nullptr, nullptr, nullptr);
        attn_merged<<<2400, 256, 0, stream>>>(qkvb, vx[s][0], vx[s][1], obufb);
        gemm_mfma<64, 128, false, false, false, true><<<dim3(938, 1), 256, 0, stream>>>(
            obufb, nullptr, 0, owb + (size_t)li * 16384, obp + li * 128, nullptr, NVOX, 128,
            featb, g1 + li * 128, b1 + li * 128);
        gemm_mfma<64, 128, false, true, true, false><<<dim3(938, 2), 256, 0, stream>>>(
            featb, nullptr, 0, l1wb + (size_t)li * 32768, l1b + li * 256, hbufb, NVOX, 256,
            nullptr, nullptr, nullptr);
        gemm_mfma<64, 256, false, false, false, true><<<dim3(938, 1), 256, 0, stream>>>(
            hbufb, nullptr, 0, l2wb + (size_t)li * 32768, l2b + li * 128, nullptr, NVOX, 128,
            featb, g2 + li * 128, b2 + li * 128);
    }

    // BEV: zero canvas1 fully + canvas2 halo only, scatter, conv1, conv2
    hipMemsetAsync(canvas1, 0, (size_t)43438080 * 2, stream);
    halo_zero<<<(2 * 9680 * 16 + 255) / 256, 256, 0, stream>>>(canvas2);
    scatter_kernel<<<(NVOX * 16 + 255) / 256, 256, 0, stream>>>(featb, coors, canvas1);
    conv_mfma<false><<<dim3(13, 100, 2), 512, 0, stream>>>(
        canvas1, cwb, bng, bnb, bnm, bnv, canvas2);
    conv_mfma<true><<<dim3(13, 100, 2), 512, 0, stream>>>(
        canvas2, cwb + 9 * 16384, bng + 128, bnb + 128, bnm + 128, bnv + 128, (float*)d_out);
}

// Round 16
// 2178.341 us; speedup vs baseline: 1.2530x; 1.0050x over previous
//
#include <hip/hip_runtime.h>
#include <math.h>

#define NVOX 60000

typedef __attribute__((ext_vector_type(8))) short short8v;            // 8 bf16 raw
typedef __attribute__((ext_vector_type(8))) unsigned short ushort8v;  // 8 bf16 raw
typedef __attribute__((ext_vector_type(4))) float f32x4;

static __device__ __forceinline__ unsigned short f2bf(float f) {
    unsigned u = __float_as_uint(f);
    unsigned r = (u + 0x7fffu + ((u >> 16) & 1u)) >> 16;
    return (unsigned short)r;
}
static __device__ __forceinline__ float bf2f(unsigned short h) {
    return __uint_as_float(((unsigned)h) << 16);
}
// async global->LDS 16B per lane: dest = lds_base + lane*16 (wave-uniform base)
static __device__ __forceinline__ void gll16(const unsigned short* g, unsigned short* l) {
    __builtin_amdgcn_global_load_lds(
        (const __attribute__((address_space(1))) unsigned*)g,
        (__attribute__((address_space(3))) unsigned*)l,
        16, 0, 0);
}

// ---------------------------------------------------------------- pos embed (bf16 out)
__global__ __launch_bounds__(256) void pos_kernel(const float* __restrict__ ciw,
                                                  unsigned short* __restrict__ pos) {
    int idx = blockIdx.x * 256 + threadIdx.x;
    if (idx >= NVOX * 128) return;
    int n = idx >> 7, d = idx & 127;
    int c = d >> 6, t = (d & 63) >> 1;
    float xy = ciw[n * 2 + c] - 6.0f;
    float inv = exp2f((float)t * (13.287712379549449f / 32.0f)); // 10000^(t/32)
    float e = xy / inv;
    pos[idx] = f2bf((d & 1) ? cosf(e) : sinf(e));
}

// ------------------------------------------------------- fp32 -> bf16 convert
__global__ __launch_bounds__(256) void cvt_bf16(const float* __restrict__ in,
                                                unsigned short* __restrict__ out, int n) {
    int idx = blockIdx.x * 256 + threadIdx.x;
    if (idx < n) out[idx] = f2bf(in[idx]);
}

// ----------------------------------------- MFMA GEMM: C = A*W^T + b (+variants)
// MT-row tile (32/64/128). A bf16 [M,KTOT]; W bf16 [N,KTOT]; optional A+=Aadd
// (bf16, K=128) for col-blocks < add_nblk; CBF16 out staged via LDS;
// LNF: fused residual+LN epilogue (N==128, gridDim.y==1), bf16 residual stream.
template<int MT, int KTOT, bool ADD, bool GELU, bool CBF16, bool LNF>
__global__ __launch_bounds__(256) void gemm_mfma(
    const unsigned short* __restrict__ A, const unsigned short* __restrict__ Aadd, int add_nblk,
    const unsigned short* __restrict__ W, const float* __restrict__ bias,
    void* __restrict__ Cp, int M, int ldc,
    unsigned short* __restrict__ featb,
    const float* __restrict__ lng, const float* __restrict__ lnb)
{
    constexpr int RF = (MT + 31) / 32;          // row frags per wave (>=1)
    __shared__ unsigned short smem[(MT + 128) * 64];   // As(MT*64) + Ws(128*64); reused as Cs(MT*128)
    __shared__ float2 lnsum[MT][2];
    unsigned short* As = smem;
    unsigned short* Ws = smem + MT * 64;
    const int tid = threadIdx.x;
    const int lane = tid & 63, wave = tid >> 6;
    const int wr = wave >> 1, wc = wave & 1;
    const int llo = lane & 15, lhi = lane >> 4;
    const int m0 = blockIdx.x * MT;
    const int n0 = blockIdx.y * 128;
    const bool addp = ADD && ((int)blockIdx.y < add_nblk);
    const int gr = lane >> 3;           // row within 8-row group
    const int gc = (lane & 7) ^ gr;     // pre-swizzled source chunk
    f32x4 acc[RF][4] = {};

    for (int k0 = 0; k0 < KTOT; k0 += 64) {
        #pragma unroll
        for (int p = 0; p < 4; ++p) {
            int r0 = wave * 32 + p * 8;
            gll16(W + (size_t)(n0 + r0 + gr) * KTOT + k0 + gc * 8, &Ws[r0 * 64]);
        }
        if (!addp) {
            #pragma unroll
            for (int p = 0; p < RF; ++p) {
                int r0 = wave * (RF * 8) + p * 8;   // RF*8 rows per wave (4 waves cover MT)
                gll16(A + (size_t)(m0 + r0 + gr) * KTOT + k0 + gc * 8, &As[r0 * 64]);
            }
        } else {
            #pragma unroll
            for (int p = 0; p < RF; ++p) {
                int c = tid + p * 256;
                int r = c >> 3, c16 = c & 7;
                int m = m0 + r;
                short8v av = {};
                if (m < M && r < MT) {
                    ushort8v fa = *reinterpret_cast<const ushort8v*>(A + (size_t)m * KTOT + k0 + c16 * 8);
                    ushort8v pa = *reinterpret_cast<const ushort8v*>(Aadd + (size_t)m * 128 + k0 + c16 * 8);
                    #pragma unroll
                    for (int q = 0; q < 8; ++q) av[q] = (short)f2bf(bf2f(fa[q]) + bf2f(pa[q]));
                }
                if (r < MT)
                    *reinterpret_cast<short8v*>((char*)As + r * 128 + ((c16 * 16) ^ ((r & 7) << 4))) = av;
            }
        }
        __syncthreads();
        #pragma unroll
        for (int kk = 0; kk < 2; ++kk) {
            int kb = kk * 64 + lhi * 16;
            short8v af[RF], bf[4];
            #pragma unroll
            for (int i = 0; i < RF; ++i) {
                int r = wr * (MT / 2) + i * 16 + llo;
                af[i] = *reinterpret_cast<const short8v*>((const char*)As + r * 128 + (kb ^ ((r & 7) << 4)));
            }
            #pragma unroll
            for (int j = 0; j < 4; ++j) {
                int cc = wc * 64 + j * 16 + llo;
                bf[j] = *reinterpret_cast<const short8v*>((const char*)Ws + cc * 128 + (kb ^ ((cc & 7) << 4)));
            }
            #pragma unroll
            for (int i = 0; i < RF; ++i)
                #pragma unroll
                for (int j = 0; j < 4; ++j)
                    acc[i][j] = __builtin_amdgcn_mfma_f32_16x16x32_bf16(af[i], bf[j], acc[i][j], 0, 0, 0);
        }
        __syncthreads();
    }

    if (LNF) {
        // residual(bf16) + LN: pass 1 computes x = featb + acc + bias -> kept in acc
        float s1[RF][4] = {}, s2[RF][4] = {};
        #pragma unroll
        for (int i = 0; i < RF; ++i)
            #pragma unroll
            for (int rg = 0; rg < 4; ++rg) {
                int m = m0 + wr * (MT / 2) + i * 16 + lhi * 4 + rg;
                if (m < M) {
                    #pragma unroll
                    for (int j = 0; j < 4; ++j) {
                        int n = wc * 64 + j * 16 + llo;
                        float x = bf2f(featb[(size_t)m * 128 + n]) + acc[i][j][rg] + bias[n];
                        acc[i][j][rg] = x;
                        s1[i][rg] += x; s2[i][rg] += x * x;
                    }
                }
            }
        #pragma unroll
        for (int i = 0; i < RF; ++i)
            #pragma unroll
            for (int rg = 0; rg < 4; ++rg) {
                #pragma unroll
                for (int off = 1; off < 16; off <<= 1) {
                    s1[i][rg] += __shfl_xor(s1[i][rg], off);
                    s2[i][rg] += __shfl_xor(s2[i][rg], off);
                }
                if (llo == 0)
                    lnsum[wr * (MT / 2) + i * 16 + lhi * 4 + rg][wc] = make_float2(s1[i][rg], s2[i][rg]);
            }
        __syncthreads();
        #pragma unroll
        for (int i = 0; i < RF; ++i)
            #pragma unroll
            for (int rg = 0; rg < 4; ++rg) {
                int r = wr * (MT / 2) + i * 16 + lhi * 4 + rg;
                int m = m0 + r;
                if (m >= M) continue;
                float2 a0 = lnsum[r][0], a1 = lnsum[r][1];
                float mu = (a0.x + a1.x) * 0.0078125f;
                float var = fmaxf((a0.y + a1.y) * 0.0078125f - mu * mu, 0.f);
                float inv = rsqrtf(var + 1e-5f);
                #pragma unroll
                for (int j = 0; j < 4; ++j) {
                    int n = wc * 64 + j * 16 + llo;
                    float v = (acc[i][j][rg] - mu) * inv * lng[n] + lnb[n];
                    featb[(size_t)m * 128 + n] = f2bf(v);
                }
            }
    } else if (CBF16) {
        #pragma unroll
        for (int j = 0; j < 4; ++j) {
            int nl = wc * 64 + j * 16 + llo;
            float bn = bias[n0 + nl];
            #pragma unroll
            for (int i = 0; i < RF; ++i)
                #pragma unroll
                for (int rg = 0; rg < 4; ++rg) {
                    float v = acc[i][j][rg] + bn;
                    if (GELU) v = 0.5f * v * (1.0f + erff(v * 0.7071067811865475f));
                    smem[(wr * (MT / 2) + i * 16 + lhi * 4 + rg) * 128 + nl] = f2bf(v);
                }
        }
        __syncthreads();
        unsigned short* C = (unsigned short*)Cp;
        #pragma unroll
        for (int c = 0; c < MT / 16; ++c) {
            int idx = tid + c * 256;
            int r = idx >> 4, ch = idx & 15;
            if (m0 + r < M)
                *reinterpret_cast<ushort8v*>(C + (size_t)(m0 + r) * ldc + n0 + ch * 8) =
                    *reinterpret_cast<const ushort8v*>(&smem[r * 128 + ch * 8]);
        }
    } else {
        float* C = (float*)Cp;
        #pragma unroll
        for (int j = 0; j < 4; ++j) {
            int n = n0 + wc * 64 + j * 16 + llo;
            float bn = bias[n];
            #pragma unroll
            for (int i = 0; i < RF; ++i)
                #pragma unroll
                for (int rg = 0; rg < 4; ++rg) {
                    int m = m0 + wr * (MT / 2) + i * 16 + lhi * 4 + rg;
                    if (m < M) {
                        float v = acc[i][j][rg] + bn;
                        if (GELU) v = 0.5f * v * (1.0f + erff(v * 0.7071067811865475f));
                        C[(size_t)m * ldc + n] = v;
                    }
                }
        }
    }
}

// ------------------- merged windowed attention: lvl0 (T=25,HG=8) + lvl1 (T=100,HG=2)
__global__ __launch_bounds__(256) void attn_merged(
    const unsigned short* __restrict__ qkv, const int* __restrict__ vl0,
    const int* __restrict__ vl1, unsigned short* __restrict__ oout)
{
    __shared__ float Ks[3200];    // lvl0: [25][128] ; lvl1: [100][32]
    __shared__ float Vs[3200];
    __shared__ int vl[100];
    int T, HGsh, hb, w;
    const int* vlist;
    if ((int)blockIdx.x < 960) {
        T = 25; HGsh = 3; hb = 0; w = blockIdx.x; vlist = vl0;
    } else {
        int idx = blockIdx.x - 960;
        T = 100; HGsh = 1; hb = (idx / 360) * 2; w = idx % 360; vlist = vl1;
    }
    const int HG = 1 << HGsh;
    const int rs = HG * 16;            // row stride in floats
    const int tid = threadIdx.x;
    if (tid < T) vl[tid] = vlist[w * T + tid];
    const int r8sh = HGsh + 1;         // chunks per row = HG*2
    for (int idx = tid; idx < (T << r8sh); idx += 256) {
        int t = idx >> r8sh, c8 = (idx & ((1 << r8sh) - 1)) * 8;
        int vox = vlist[w * T + t];
        const unsigned short* base = qkv + (size_t)vox * 384 + hb * 16 + c8;
        ushort8v kv = *reinterpret_cast<const ushort8v*>(base + 128);
        ushort8v vv = *reinterpret_cast<const ushort8v*>(base + 256);
        #pragma unroll
        for (int q = 0; q < 8; ++q) { Ks[t * rs + c8 + q] = bf2f(kv[q]); Vs[t * rs + c8 + q] = bf2f(vv[q]); }
    }
    __syncthreads();
    const int ITEMS = T << HGsh;
    for (int item = tid; item < ITEMS; item += 256) {
        int h = item & (HG - 1);
        int q = item >> HGsh;
        int vq = vl[q];
        const unsigned short* qb = qkv + (size_t)vq * 384 + (hb + h) * 16;
        ushort8v qa = *reinterpret_cast<const ushort8v*>(qb);
        ushort8v qc = *reinterpret_cast<const ushort8v*>(qb + 8);
        float4 q0 = make_float4(bf2f(qa[0]), bf2f(qa[1]), bf2f(qa[2]), bf2f(qa[3]));
        float4 q1 = make_float4(bf2f(qa[4]), bf2f(qa[5]), bf2f(qa[6]), bf2f(qa[7]));
        float4 q2 = make_float4(bf2f(qc[0]), bf2f(qc[1]), bf2f(qc[2]), bf2f(qc[3]));
        float4 q3 = make_float4(bf2f(qc[4]), bf2f(qc[5]), bf2f(qc[6]), bf2f(qc[7]));
        float mx = -INFINITY, l = 0.f;
        float4 o0 = make_float4(0,0,0,0), o1 = o0, o2 = o0, o3 = o0;
        const float* kbase = Ks + h * 16;
        const float* vbase = Vs + h * 16;
        for (int t = 0; t < T; ++t) {
            const float4* kr = reinterpret_cast<const float4*>(kbase + t * rs);
            float4 k0 = kr[0], k1 = kr[1], k2 = kr[2], k3 = kr[3];
            float s = q0.x*k0.x + q0.y*k0.y + q0.z*k0.z + q0.w*k0.w
                    + q1.x*k1.x + q1.y*k1.y + q1.z*k1.z + q1.w*k1.w
                    + q2.x*k2.x + q2.y*k2.y + q2.z*k2.z + q2.w*k2.w
                    + q3.x*k3.x + q3.y*k3.y + q3.z*k3.z + q3.w*k3.w;
            s *= 0.25f;
            float mo = mx;
            mx = fmaxf(mx, s);
            float cc = __expf(mo - mx);
            float p  = __expf(s - mx);
            l = l * cc + p;
            const float4* vr = reinterpret_cast<const float4*>(vbase + t * rs);
            float4 v0 = vr[0], v1 = vr[1], v2 = vr[2], v3 = vr[3];
            o0.x = o0.x*cc + p*v0.x; o0.y = o0.y*cc + p*v0.y; o0.z = o0.z*cc + p*v0.z; o0.w = o0.w*cc + p*v0.w;
            o1.x = o1.x*cc + p*v1.x; o1.y = o1.y*cc + p*v1.y; o1.z = o1.z*cc + p*v1.z; o1.w = o1.w*cc + p*v1.w;
            o2.x = o2.x*cc + p*v2.x; o2.y = o2.y*cc + p*v2.y; o2.z = o2.z*cc + p*v2.z; o2.w = o2.w*cc + p*v2.w;
            o3.x = o3.x*cc + p*v3.x; o3.y = o3.y*cc + p*v3.y; o3.z = o3.z*cc + p*v3.z; o3.w = o3.w*cc + p*v3.w;
        }
        float rl = 1.0f / l;
        ushort8v r0, r1;
        r0[0]=f2bf(o0.x*rl); r0[1]=f2bf(o0.y*rl); r0[2]=f2bf(o0.z*rl); r0[3]=f2bf(o0.w*rl);
        r0[4]=f2bf(o1.x*rl); r0[5]=f2bf(o1.y*rl); r0[6]=f2bf(o1.z*rl); r0[7]=f2bf(o1.w*rl);
        r1[0]=f2bf(o2.x*rl); r1[1]=f2bf(o2.y*rl); r1[2]=f2bf(o2.z*rl); r1[3]=f2bf(o2.w*rl);
        r1[4]=f2bf(o3.x*rl); r1[5]=f2bf(o3.y*rl); r1[6]=f2bf(o3.z*rl); r1[7]=f2bf(o3.w*rl);
        unsigned short* op = oout + (size_t)vq * 128 + (hb + h) * 16;
        *reinterpret_cast<ushort8v*>(op) = r0;
        *reinterpret_cast<ushort8v*>(op + 8) = r1;
    }
}

// ------------------- BEV scatter into padded canvas (bf16 copy, stride 420)
__global__ __launch_bounds__(256) void scatter_kernel(const unsigned short* __restrict__ featb,
    const int* __restrict__ coors, unsigned short* __restrict__ canvas)
{
    int idx = blockIdx.x * 256 + threadIdx.x;
    if (idx >= NVOX * 16) return;
    int n = idx >> 4, c8 = (idx & 15) << 3;
    int b = coors[n * 4], y = coors[n * 4 + 2], x = coors[n * 4 + 3];
    size_t p = (((size_t)b * 404 + y + 2) * 420 + x + 2) * 128 + c8;
    *reinterpret_cast<ushort8v*>(canvas + p) =
        *reinterpret_cast<const ushort8v*>(featb + (size_t)n * 128 + c8);
}

// --------- zero the halo of a stride-420 padded canvas
__global__ __launch_bounds__(256) void halo_zero(unsigned short* __restrict__ c) {
    int idx = blockIdx.x * 256 + threadIdx.x;
    if (idx >= 2 * 9680 * 16) return;
    int b = idx / (9680 * 16);
    int rem = idx % (9680 * 16);
    int p = rem >> 4, ch = (rem & 15) * 8;
    int y, x;
    if (p < 1680) { int ry = p / 420; y = (ry < 2) ? ry : ry + 400; x = p % 420; }
    else { int q = p - 1680; y = 2 + q / 20; int cx = q % 20; x = (cx < 2) ? cx : cx + 400; }
    ushort8v z = {};
    *reinterpret_cast<ushort8v*>(c + (((size_t)b * 404 + y) * 420 + x) * 128 + ch) = z;
}

// ------------------- conv weight re-layout -> bf16 [i][ky*3+kx][cout][cin]
__global__ __launch_bounds__(256) void wtrans_kernel(const float* __restrict__ cw,
                                                     unsigned short* __restrict__ wbuf)
{
    int idx = blockIdx.x * 256 + threadIdx.x;
    if (idx >= 2 * 9 * 128 * 128) return;
    int ci = idx & 127;
    int co = (idx >> 7) & 127;
    int kk = (idx >> 14) % 9;
    int i  = idx / (9 * 16384);
    wbuf[idx] = f2bf(cw[(((size_t)i * 128 + co) * 128 + ci) * 9 + kk]);
}

// ---------------- 3x3 dilated(2) conv + BN + ReLU, LDS-A once + LDS-W double-buffered
template<bool NCHW_OUT>
__global__ __launch_bounds__(512, 1) void conv_mfma(
    const unsigned short* __restrict__ in, const unsigned short* __restrict__ wbuf,
    const float* __restrict__ g, const float* __restrict__ bsh,
    const float* __restrict__ bm, const float* __restrict__ bv,
    void* __restrict__ out)
{
    __shared__ unsigned short Ab[8 * 36 * 128];
    __shared__ unsigned short Wb[2 * 128 * 128];
    const int tid = threadIdx.x;
    const int lane = tid & 63, wave = tid >> 6;
    const int cog = wave & 1, yg = wave >> 1;
    const int llo = lane & 15, lhi = lane >> 4;
    const int x0 = blockIdx.x * 32, y0 = blockIdx.y * 4, b = blockIdx.z;
    const int c16s = lane & 15;

    #pragma unroll
    for (int it = 0; it < 9; ++it) {
        int gidx = it * 32 + wave * 4 + lhi;
        int row = gidx / 36, xi = gidx % 36;
        gll16(in + (((size_t)b * 404 + y0 + row) * 420 + x0 + xi) * 128 + ((c16s ^ (xi & 15)) * 8),
              Ab + (size_t)(it * 512 + wave * 64) * 8);
    }
    {
        const unsigned short* wt = wbuf;
        #pragma unroll
        for (int it = 0; it < 4; ++it) {
            int co = it * 32 + wave * 4 + lhi;
            gll16(wt + co * 128 + ((c16s ^ (co & 15)) * 8),
                  Wb + (size_t)(it * 512 + wave * 64) * 8);
        }
    }
    __syncthreads();

    f32x4 acc[2][4] = {};
    #pragma unroll
    for (int t = 0; t < 9; ++t) {
        if (t < 8) {
            const unsigned short* wt = wbuf + (size_t)(t + 1) * 16384;
            unsigned short* dst = Wb + ((t + 1) & 1) * 16384;
            #pragma unroll
            for (int it = 0; it < 4; ++it) {
                int co = it * 32 + wave * 4 + lhi;
                gll16(wt + co * 128 + ((c16s ^ (co & 15)) * 8),
                      dst + (size_t)(it * 512 + wave * 64) * 8);
            }
        }
        const unsigned short* Wp = Wb + (t & 1) * 16384;
        const int ky = t / 3, kx = t % 3;
        const int r = yg + 2 * ky;
        #pragma unroll
        for (int kk = 0; kk < 4; ++kk) {
            short8v a[2], w[4];
            #pragma unroll
            for (int i = 0; i < 2; ++i) {
                int xi = i * 16 + llo + 2 * kx;
                a[i] = *reinterpret_cast<const short8v*>(
                    (const char*)Ab + (r * 36 + xi) * 256 + ((kk * 64 + lhi * 16) ^ ((xi & 15) << 4)));
            }
            #pragma unroll
            for (int j = 0; j < 4; ++j) {
                int co = cog * 64 + j * 16 + llo;
                w[j] = *reinterpret_cast<const short8v*>(
                    (const char*)Wp + co * 256 + ((kk * 64 + lhi * 16) ^ ((co & 15) << 4)));
            }
            #pragma unroll
            for (int i = 0; i < 2; ++i)
                #pragma unroll
                for (int j = 0; j < 4; ++j)
                    acc[i][j] = __builtin_amdgcn_mfma_f32_16x16x32_bf16(a[i], w[j], acc[i][j], 0, 0, 0);
        }
        __syncthreads();
    }

    const int y = y0 + yg;
    if (NCHW_OUT) {
        #pragma unroll
        for (int j = 0; j < 4; ++j) {
            int co = cog * 64 + j * 16 + llo;
            float scale = rsqrtf(bv[co] + 1e-3f) * g[co];
            float shift = bsh[co] - bm[co] * scale;
            #pragma unroll
            for (int i = 0; i < 2; ++i) {
                int px = x0 + i * 16 + lhi * 4;
                if (px < 400) {
                    float4 v;
                    v.x = fmaxf(acc[i][j][0] * scale + shift, 0.f);
                    v.y = fmaxf(acc[i][j][1] * scale + shift, 0.f);
                    v.z = fmaxf(acc[i][j][2] * scale + shift, 0.f);
                    v.w = fmaxf(acc[i][j][3] * scale + shift, 0.f);
                    *reinterpret_cast<float4*>(
                        (float*)out + (((size_t)b * 128 + co) * 400 + y) * 400 + px) = v;
                }
            }
        }
    } else {
        unsigned short* Cw = Wb + wave * 2048;
        #pragma unroll
        for (int j = 0; j < 4; ++j) {
            int co = cog * 64 + j * 16 + llo;
            float scale = rsqrtf(bv[co] + 1e-3f) * g[co];
            float shift = bsh[co] - bm[co] * scale;
            #pragma unroll
            for (int i = 0; i < 2; ++i)
                #pragma unroll
                for (int rg = 0; rg < 4; ++rg)
                    Cw[(i * 16 + lhi * 4 + rg) * 64 + j * 16 + llo] =
                        f2bf(fmaxf(acc[i][j][rg] * scale + shift, 0.f));
        }
        #pragma unroll
        for (int s = 0; s < 4; ++s) {
            int pxl = s * 8 + (lane >> 3);
            int oct = lane & 7;
            int px = x0 + pxl;
            if (px < 400)
                *reinterpret_cast<ushort8v*>(
                    (unsigned short*)out + (((size_t)b * 404 + y + 2) * 420 + px + 2) * 128
                                         + cog * 64 + oct * 8) =
                    *reinterpret_cast<const ushort8v*>(&Cw[pxl * 64 + oct * 8]);
        }
    }
}

// ---------------------------------------------------------------- launcher
extern "C" void kernel_launch(void* const* d_in, const int* in_sizes, int n_in,
                              void* d_out, int out_size, void* d_ws, size_t ws_size,
                              hipStream_t stream) {
    const float* voxel_feat = (const float*)d_in[0];
    const int*   coors      = (const int*)d_in[1];
    const float* ciw0       = (const float*)d_in[2];
    const float* ciw1       = (const float*)d_in[3];
    const int* vx[2][2] = {{(const int*)d_in[4], (const int*)d_in[6]},
                           {(const int*)d_in[8], (const int*)d_in[10]}};
    const float* ipw = (const float*)d_in[12];
    const float* ipb = (const float*)d_in[13];
    const float* ow  = (const float*)d_in[14];
    const float* obp = (const float*)d_in[15];
    const float* l1w = (const float*)d_in[16];
    const float* l1b = (const float*)d_in[17];
    const float* l2w = (const float*)d_in[18];
    const float* l2b = (const float*)d_in[19];
    const float* g1  = (const float*)d_in[20];
    const float* b1  = (const float*)d_in[21];
    const float* g2  = (const float*)d_in[22];
    const float* b2  = (const float*)d_in[23];
    const float* cw  = (const float*)d_in[24];
    const float* bng = (const float*)d_in[25];
    const float* bnb = (const float*)d_in[26];
    const float* bnm = (const float*)d_in[27];
    const float* bnv = (const float*)d_in[28];

    float* F = (float*)d_ws;
    unsigned short* W0   = (unsigned short*)F;           // bf16 weights: 1,867,776 ushorts
    unsigned short* ipwb = W0;                           // 589824
    unsigned short* owb  = W0 + 589824;                  // 196608
    unsigned short* l1wb = W0 + 786432;                  // 393216
    unsigned short* l2wb = W0 + 1179648;                 // 393216
    unsigned short* cwb  = W0 + 1572864;                 // 294912
    unsigned short* featb = (unsigned short*)(F + 940000);    // 7.68M ushorts
    unsigned short* pos0  = (unsigned short*)(F + 4780000);
    unsigned short* pos1  = (unsigned short*)(F + 8620000);
    unsigned short* obufb = (unsigned short*)(F + 12460000);
    unsigned short* hbufb = (unsigned short*)(F + 16300000);  // 15.36M ushorts
    // conv phase: padded canvases [2][404][420][128] bf16 = 43,438,080 ushorts each
    unsigned short* canvas1 = (unsigned short*)(F + 8620000);
    unsigned short* canvas2 = (unsigned short*)(F + 30339040);
    unsigned short* qkvb = (unsigned short*)d_out;       // 23.04M ushorts scratch

    cvt_bf16<<<30000, 256, 0, stream>>>(voxel_feat, featb, NVOX * 128);
    pos_kernel<<<30000, 256, 0, stream>>>(ciw0, pos0);
    pos_kernel<<<30000, 256, 0, stream>>>(ciw1, pos1);
    cvt_bf16<<<(589824 + 255) / 256, 256, 0, stream>>>(ipw, ipwb, 589824);
    cvt_bf16<<<(196608 + 255) / 256, 256, 0, stream>>>(ow,  owb,  196608);
    cvt_bf16<<<(393216 + 255) / 256, 256, 0, stream>>>(l1w, l1wb, 393216);
    cvt_bf16<<<(393216 + 255) / 256, 256, 0, stream>>>(l2w, l2wb, 393216);
    wtrans_kernel<<<(2 * 9 * 16384 + 255) / 256, 256, 0, stream>>>(cw, cwb);

    for (int li = 0; li < 12; ++li) {
        int s = li & 1;
        const unsigned short* pos = s ? pos1 : pos0;
        gemm_mfma<64, 128, true, false, true, false><<<dim3(938, 3), 256, 0, stream>>>(
            featb, pos, 2, ipwb + (size_t)li * 49152, ipb + li * 384, qkvb, NVOX, 384,
            nullptr, nullptr, nullptr);
        attn_merged<<<2400, 256, 0, stream>>>(qkvb, vx[s][0], vx[s][1], obufb);
        gemm_mfma<32, 128, false, false, false, true><<<dim3(1875, 1), 256, 0, stream>>>(
            obufb, nullptr, 0, owb + (size_t)li * 16384, obp + li * 128, nullptr, NVOX, 128,
            featb, g1 + li * 128, b1 + li * 128);
        gemm_mfma<64, 128, false, true, true, false><<<dim3(938, 2), 256, 0, stream>>>(
            featb, nullptr, 0, l1wb + (size_t)li * 32768, l1b + li * 256, hbufb, NVOX, 256,
            nullptr, nullptr, nullptr);
        gemm_mfma<32, 256, false, false, false, true><<<dim3(1875, 1), 256, 0, stream>>>(
            hbufb, nullptr, 0, l2wb + (size_t)li * 32768, l2b + li * 128, nullptr, NVOX, 128,
            featb, g2 + li * 128, b2 + li * 128);
    }

    // BEV: zero canvas1 fully + canvas2 halo only, scatter, conv1, conv2
    hipMemsetAsync(canvas1, 0, (size_t)43438080 * 2, stream);
    halo_zero<<<(2 * 9680 * 16 + 255) / 256, 256, 0, stream>>>(canvas2);
    scatter_kernel<<<(NVOX * 16 + 255) / 256, 256, 0, stream>>>(featb, coors, canvas1);
    conv_mfma<false><<<dim3(13, 100, 2), 512, 0, stream>>>(
        canvas1, cwb, bng, bnb, bnm, bnv, canvas2);
    conv_mfma<true><<<dim3(13, 100, 2), 512, 0, stream>>>(
        canvas2, cwb + 9 * 16384, bng + 128, bnb + 128, bnm + 128, bnv + 128, (float*)d_out);
}

// Round 17
// 2107.416 us; speedup vs baseline: 1.2952x; 1.0337x over previous
//
#include <hip/hip_runtime.h>
#include <math.h>

#define NVOX 60000

typedef __attribute__((ext_vector_type(8))) short short8v;            // 8 bf16 raw
typedef __attribute__((ext_vector_type(8))) unsigned short ushort8v;  // 8 bf16 raw
typedef __attribute__((ext_vector_type(4))) float f32x4;

static __device__ __forceinline__ unsigned short f2bf(float f) {
    unsigned u = __float_as_uint(f);
    unsigned r = (u + 0x7fffu + ((u >> 16) & 1u)) >> 16;
    return (unsigned short)r;
}
static __device__ __forceinline__ float bf2f(unsigned short h) {
    return __uint_as_float(((unsigned)h) << 16);
}
// async global->LDS 16B per lane: dest = lds_base + lane*16 (wave-uniform base)
static __device__ __forceinline__ void gll16(const unsigned short* g, unsigned short* l) {
    __builtin_amdgcn_global_load_lds(
        (const __attribute__((address_space(1))) unsigned*)g,
        (__attribute__((address_space(3))) unsigned*)l,
        16, 0, 0);
}

// ---------------------------------------------------------------- pos embed (bf16 out)
__global__ __launch_bounds__(256) void pos_kernel(const float* __restrict__ ciw,
                                                  unsigned short* __restrict__ pos) {
    int idx = blockIdx.x * 256 + threadIdx.x;
    if (idx >= NVOX * 128) return;
    int n = idx >> 7, d = idx & 127;
    int c = d >> 6, t = (d & 63) >> 1;
    float xy = ciw[n * 2 + c] - 6.0f;
    float inv = exp2f((float)t * (13.287712379549449f / 32.0f)); // 10000^(t/32)
    float e = xy / inv;
    pos[idx] = f2bf((d & 1) ? cosf(e) : sinf(e));
}

// ------------------------------------------------------- fp32 -> bf16 convert
__global__ __launch_bounds__(256) void cvt_bf16(const float* __restrict__ in,
                                                unsigned short* __restrict__ out, int n) {
    int idx = blockIdx.x * 256 + threadIdx.x;
    if (idx < n) out[idx] = f2bf(in[idx]);
}

// ----------------- fused weight prep: ipw | ow | l1w | l2w -> bf16 (contiguous dst)
__global__ __launch_bounds__(256) void wprep_kernel(
    const float* __restrict__ ipw, const float* __restrict__ ow,
    const float* __restrict__ l1w, const float* __restrict__ l2w,
    unsigned short* __restrict__ dst) {
    int idx = blockIdx.x * 256 + threadIdx.x;
    if (idx >= 1572864) return;
    float v;
    if (idx < 589824) v = ipw[idx];
    else if (idx < 786432) v = ow[idx - 589824];
    else if (idx < 1179648) v = l1w[idx - 786432];
    else v = l2w[idx - 1179648];
    dst[idx] = f2bf(v);
}

// ----------------------------------------- MFMA GEMM: C = A*W^T + b (+variants)
// MT-row tile. Grid: x = n-tile (fast) so A-sharing blocks are dispatch-adjacent,
// y = m-tile. A bf16 [M,KTOT]; W bf16 [N,KTOT]; optional A+=Aadd (bf16, K=128)
// for n-blocks < add_nblk; CBF16 out staged via LDS; LNF: fused residual+LN
// epilogue (N==128, gridDim.x==1), bf16 residual stream.
template<int MT, int KTOT, bool ADD, bool GELU, bool CBF16, bool LNF>
__global__ __launch_bounds__(256) void gemm_mfma(
    const unsigned short* __restrict__ A, const unsigned short* __restrict__ Aadd, int add_nblk,
    const unsigned short* __restrict__ W, const float* __restrict__ bias,
    void* __restrict__ Cp, int M, int ldc,
    unsigned short* __restrict__ featb,
    const float* __restrict__ lng, const float* __restrict__ lnb)
{
    constexpr int RF = (MT + 31) / 32;          // row frags per wave (>=1)
    __shared__ unsigned short smem[(MT + 128) * 64];   // As(MT*64) + Ws(128*64); reused as Cs(MT*128)
    __shared__ float2 lnsum[MT][2];
    unsigned short* As = smem;
    unsigned short* Ws = smem + MT * 64;
    const int tid = threadIdx.x;
    const int lane = tid & 63, wave = tid >> 6;
    const int wr = wave >> 1, wc = wave & 1;
    const int llo = lane & 15, lhi = lane >> 4;
    const int m0 = blockIdx.y * MT;
    const int n0 = blockIdx.x * 128;
    const bool addp = ADD && ((int)blockIdx.x < add_nblk);
    const int gr = lane >> 3;           // row within 8-row group
    const int gc = (lane & 7) ^ gr;     // pre-swizzled source chunk
    f32x4 acc[RF][4] = {};

    for (int k0 = 0; k0 < KTOT; k0 += 64) {
        #pragma unroll
        for (int p = 0; p < 4; ++p) {
            int r0 = wave * 32 + p * 8;
            gll16(W + (size_t)(n0 + r0 + gr) * KTOT + k0 + gc * 8, &Ws[r0 * 64]);
        }
        if (!addp) {
            #pragma unroll
            for (int p = 0; p < RF; ++p) {
                int r0 = wave * (RF * 8) + p * 8;   // RF*8 rows per wave (4 waves cover MT)
                gll16(A + (size_t)(m0 + r0 + gr) * KTOT + k0 + gc * 8, &As[r0 * 64]);
            }
        } else {
            #pragma unroll
            for (int p = 0; p < RF; ++p) {
                int c = tid + p * 256;
                int r = c >> 3, c16 = c & 7;
                int m = m0 + r;
                short8v av = {};
                if (m < M && r < MT) {
                    ushort8v fa = *reinterpret_cast<const ushort8v*>(A + (size_t)m * KTOT + k0 + c16 * 8);
                    ushort8v pa = *reinterpret_cast<const ushort8v*>(Aadd + (size_t)m * 128 + k0 + c16 * 8);
                    #pragma unroll
                    for (int q = 0; q < 8; ++q) av[q] = (short)f2bf(bf2f(fa[q]) + bf2f(pa[q]));
                }
                if (r < MT)
                    *reinterpret_cast<short8v*>((char*)As + r * 128 + ((c16 * 16) ^ ((r & 7) << 4))) = av;
            }
        }
        __syncthreads();
        #pragma unroll
        for (int kk = 0; kk < 2; ++kk) {
            int kb = kk * 64 + lhi * 16;
            short8v af[RF], bf[4];
            #pragma unroll
            for (int i = 0; i < RF; ++i) {
                int r = wr * (MT / 2) + i * 16 + llo;
                af[i] = *reinterpret_cast<const short8v*>((const char*)As + r * 128 + (kb ^ ((r & 7) << 4)));
            }
            #pragma unroll
            for (int j = 0; j < 4; ++j) {
                int cc = wc * 64 + j * 16 + llo;
                bf[j] = *reinterpret_cast<const short8v*>((const char*)Ws + cc * 128 + (kb ^ ((cc & 7) << 4)));
            }
            #pragma unroll
            for (int i = 0; i < RF; ++i)
                #pragma unroll
                for (int j = 0; j < 4; ++j)
                    acc[i][j] = __builtin_amdgcn_mfma_f32_16x16x32_bf16(af[i], bf[j], acc[i][j], 0, 0, 0);
        }
        __syncthreads();
    }

    if (LNF) {
        // residual(bf16) + LN: pass 1 computes x = featb + acc + bias -> kept in acc
        float s1[RF][4] = {}, s2[RF][4] = {};
        #pragma unroll
        for (int i = 0; i < RF; ++i)
            #pragma unroll
            for (int rg = 0; rg < 4; ++rg) {
                int m = m0 + wr * (MT / 2) + i * 16 + lhi * 4 + rg;
                if (m < M) {
                    #pragma unroll
                    for (int j = 0; j < 4; ++j) {
                        int n = wc * 64 + j * 16 + llo;
                        float x = bf2f(featb[(size_t)m * 128 + n]) + acc[i][j][rg] + bias[n];
                        acc[i][j][rg] = x;
                        s1[i][rg] += x; s2[i][rg] += x * x;
                    }
                }
            }
        #pragma unroll
        for (int i = 0; i < RF; ++i)
            #pragma unroll
            for (int rg = 0; rg < 4; ++rg) {
                #pragma unroll
                for (int off = 1; off < 16; off <<= 1) {
                    s1[i][rg] += __shfl_xor(s1[i][rg], off);
                    s2[i][rg] += __shfl_xor(s2[i][rg], off);
                }
                if (llo == 0)
                    lnsum[wr * (MT / 2) + i * 16 + lhi * 4 + rg][wc] = make_float2(s1[i][rg], s2[i][rg]);
            }
        __syncthreads();
        #pragma unroll
        for (int i = 0; i < RF; ++i)
            #pragma unroll
            for (int rg = 0; rg < 4; ++rg) {
                int r = wr * (MT / 2) + i * 16 + lhi * 4 + rg;
                int m = m0 + r;
                if (m >= M) continue;
                float2 a0 = lnsum[r][0], a1 = lnsum[r][1];
                float mu = (a0.x + a1.x) * 0.0078125f;
                float var = fmaxf((a0.y + a1.y) * 0.0078125f - mu * mu, 0.f);
                float inv = rsqrtf(var + 1e-5f);
                #pragma unroll
                for (int j = 0; j < 4; ++j) {
                    int n = wc * 64 + j * 16 + llo;
                    float v = (acc[i][j][rg] - mu) * inv * lng[n] + lnb[n];
                    featb[(size_t)m * 128 + n] = f2bf(v);
                }
            }
    } else if (CBF16) {
        #pragma unroll
        for (int j = 0; j < 4; ++j) {
            int nl = wc * 64 + j * 16 + llo;
            float bn = bias[n0 + nl];
            #pragma unroll
            for (int i = 0; i < RF; ++i)
                #pragma unroll
                for (int rg = 0; rg < 4; ++rg) {
                    float v = acc[i][j][rg] + bn;
                    if (GELU) v = 0.5f * v * (1.0f + erff(v * 0.7071067811865475f));
                    smem[(wr * (MT / 2) + i * 16 + lhi * 4 + rg) * 128 + nl] = f2bf(v);
                }
        }
        __syncthreads();
        unsigned short* C = (unsigned short*)Cp;
        #pragma unroll
        for (int c = 0; c < MT / 16; ++c) {
            int idx = tid + c * 256;
            int r = idx >> 4, ch = idx & 15;
            if (m0 + r < M)
                *reinterpret_cast<ushort8v*>(C + (size_t)(m0 + r) * ldc + n0 + ch * 8) =
                    *reinterpret_cast<const ushort8v*>(&smem[r * 128 + ch * 8]);
        }
    } else {
        float* C = (float*)Cp;
        #pragma unroll
        for (int j = 0; j < 4; ++j) {
            int n = n0 + wc * 64 + j * 16 + llo;
            float bn = bias[n];
            #pragma unroll
            for (int i = 0; i < RF; ++i)
                #pragma unroll
                for (int rg = 0; rg < 4; ++rg) {
                    int m = m0 + wr * (MT / 2) + i * 16 + lhi * 4 + rg;
                    if (m < M) {
                        float v = acc[i][j][rg] + bn;
                        if (GELU) v = 0.5f * v * (1.0f + erff(v * 0.7071067811865475f));
                        C[(size_t)m * ldc + n] = v;
                    }
                }
        }
    }
}

// ------------------- merged windowed attention: lvl0 (T=25,HG=8) + lvl1 (T=100,HG=2)
__global__ __launch_bounds__(256) void attn_merged(
    const unsigned short* __restrict__ qkv, const int* __restrict__ vl0,
    const int* __restrict__ vl1, unsigned short* __restrict__ oout)
{
    __shared__ float Ks[3200];    // lvl0: [25][128] ; lvl1: [100][32]
    __shared__ float Vs[3200];
    __shared__ int vl[100];
    int T, HGsh, hb, w;
    const int* vlist;
    if ((int)blockIdx.x < 960) {
        T = 25; HGsh = 3; hb = 0; w = blockIdx.x; vlist = vl0;
    } else {
        int idx = blockIdx.x - 960;
        T = 100; HGsh = 1; hb = (idx / 360) * 2; w = idx % 360; vlist = vl1;
    }
    const int HG = 1 << HGsh;
    const int rs = HG * 16;            // row stride in floats
    const int tid = threadIdx.x;
    if (tid < T) vl[tid] = vlist[w * T + tid];
    const int r8sh = HGsh + 1;         // chunks per row = HG*2
    for (int idx = tid; idx < (T << r8sh); idx += 256) {
        int t = idx >> r8sh, c8 = (idx & ((1 << r8sh) - 1)) * 8;
        int vox = vlist[w * T + t];
        const unsigned short* base = qkv + (size_t)vox * 384 + hb * 16 + c8;
        ushort8v kv = *reinterpret_cast<const ushort8v*>(base + 128);
        ushort8v vv = *reinterpret_cast<const ushort8v*>(base + 256);
        #pragma unroll
        for (int q = 0; q < 8; ++q) { Ks[t * rs + c8 + q] = bf2f(kv[q]); Vs[t * rs + c8 + q] = bf2f(vv[q]); }
    }
    __syncthreads();
    const int ITEMS = T << HGsh;
    for (int item = tid; item < ITEMS; item += 256) {
        int h = item & (HG - 1);
        int q = item >> HGsh;
        int vq = vl[q];
        const unsigned short* qb = qkv + (size_t)vq * 384 + (hb + h) * 16;
        ushort8v qa = *reinterpret_cast<const ushort8v*>(qb);
        ushort8v qc = *reinterpret_cast<const ushort8v*>(qb + 8);
        float4 q0 = make_float4(bf2f(qa[0]), bf2f(qa[1]), bf2f(qa[2]), bf2f(qa[3]));
        float4 q1 = make_float4(bf2f(qa[4]), bf2f(qa[5]), bf2f(qa[6]), bf2f(qa[7]));
        float4 q2 = make_float4(bf2f(qc[0]), bf2f(qc[1]), bf2f(qc[2]), bf2f(qc[3]));
        float4 q3 = make_float4(bf2f(qc[4]), bf2f(qc[5]), bf2f(qc[6]), bf2f(qc[7]));
        float mx = -INFINITY, l = 0.f;
        float4 o0 = make_float4(0,0,0,0), o1 = o0, o2 = o0, o3 = o0;
        const float* kbase = Ks + h * 16;
        const float* vbase = Vs + h * 16;
        for (int t = 0; t < T; ++t) {
            const float4* kr = reinterpret_cast<const float4*>(kbase + t * rs);
            float4 k0 = kr[0], k1 = kr[1], k2 = kr[2], k3 = kr[3];
            float s = q0.x*k0.x + q0.y*k0.y + q0.z*k0.z + q0.w*k0.w
                    + q1.x*k1.x + q1.y*k1.y + q1.z*k1.z + q1.w*k1.w
                    + q2.x*k2.x + q2.y*k2.y + q2.z*k2.z + q2.w*k2.w
                    + q3.x*k3.x + q3.y*k3.y + q3.z*k3.z + q3.w*k3.w;
            s *= 0.25f;
            float mo = mx;
            mx = fmaxf(mx, s);
            float cc = __expf(mo - mx);
            float p  = __expf(s - mx);
            l = l * cc + p;
            const float4* vr = reinterpret_cast<const float4*>(vbase + t * rs);
            float4 v0 = vr[0], v1 = vr[1], v2 = vr[2], v3 = vr[3];
            o0.x = o0.x*cc + p*v0.x; o0.y = o0.y*cc + p*v0.y; o0.z = o0.z*cc + p*v0.z; o0.w = o0.w*cc + p*v0.w;
            o1.x = o1.x*cc + p*v1.x; o1.y = o1.y*cc + p*v1.y; o1.z = o1.z*cc + p*v1.z; o1.w = o1.w*cc + p*v1.w;
            o2.x = o2.x*cc + p*v2.x; o2.y = o2.y*cc + p*v2.y; o2.z = o2.z*cc + p*v2.z; o2.w = o2.w*cc + p*v2.w;
            o3.x = o3.x*cc + p*v3.x; o3.y = o3.y*cc + p*v3.y; o3.z = o3.z*cc + p*v3.z; o3.w = o3.w*cc + p*v3.w;
        }
        float rl = 1.0f / l;
        ushort8v r0, r1;
        r0[0]=f2bf(o0.x*rl); r0[1]=f2bf(o0.y*rl); r0[2]=f2bf(o0.z*rl); r0[3]=f2bf(o0.w*rl);
        r0[4]=f2bf(o1.x*rl); r0[5]=f2bf(o1.y*rl); r0[6]=f2bf(o1.z*rl); r0[7]=f2bf(o1.w*rl);
        r1[0]=f2bf(o2.x*rl); r1[1]=f2bf(o2.y*rl); r1[2]=f2bf(o2.z*rl); r1[3]=f2bf(o2.w*rl);
        r1[4]=f2bf(o3.x*rl); r1[5]=f2bf(o3.y*rl); r1[6]=f2bf(o3.z*rl); r1[7]=f2bf(o3.w*rl);
        unsigned short* op = oout + (size_t)vq * 128 + (hb + h) * 16;
        *reinterpret_cast<ushort8v*>(op) = r0;
        *reinterpret_cast<ushort8v*>(op + 8) = r1;
    }
}

// ------------------- BEV scatter into padded canvas (bf16 copy, stride 420)
__global__ __launch_bounds__(256) void scatter_kernel(const unsigned short* __restrict__ featb,
    const int* __restrict__ coors, unsigned short* __restrict__ canvas)
{
    int idx = blockIdx.x * 256 + threadIdx.x;
    if (idx >= NVOX * 16) return;
    int n = idx >> 4, c8 = (idx & 15) << 3;
    int b = coors[n * 4], y = coors[n * 4 + 2], x = coors[n * 4 + 3];
    size_t p = (((size_t)b * 404 + y + 2) * 420 + x + 2) * 128 + c8;
    *reinterpret_cast<ushort8v*>(canvas + p) =
        *reinterpret_cast<const ushort8v*>(featb + (size_t)n * 128 + c8);
}

// --------- zero the halo of a stride-420 padded canvas
__global__ __launch_bounds__(256) void halo_zero(unsigned short* __restrict__ c) {
    int idx = blockIdx.x * 256 + threadIdx.x;
    if (idx >= 2 * 9680 * 16) return;
    int b = idx / (9680 * 16);
    int rem = idx % (9680 * 16);
    int p = rem >> 4, ch = (rem & 15) * 8;
    int y, x;
    if (p < 1680) { int ry = p / 420; y = (ry < 2) ? ry : ry + 400; x = p % 420; }
    else { int q = p - 1680; y = 2 + q / 20; int cx = q % 20; x = (cx < 2) ? cx : cx + 400; }
    ushort8v z = {};
    *reinterpret_cast<ushort8v*>(c + (((size_t)b * 404 + y) * 420 + x) * 128 + ch) = z;
}

// ------------------- conv weight re-layout -> bf16 [i][ky*3+kx][cout][cin]
__global__ __launch_bounds__(256) void wtrans_kernel(const float* __restrict__ cw,
                                                     unsigned short* __restrict__ wbuf)
{
    int idx = blockIdx.x * 256 + threadIdx.x;
    if (idx >= 2 * 9 * 128 * 128) return;
    int ci = idx & 127;
    int co = (idx >> 7) & 127;
    int kk = (idx >> 14) % 9;
    int i  = idx / (9 * 16384);
    wbuf[idx] = f2bf(cw[(((size_t)i * 128 + co) * 128 + ci) * 9 + kk]);
}

// ---------------- 3x3 dilated(2) conv + BN + ReLU, LDS-A once + LDS-W double-buffered
template<bool NCHW_OUT>
__global__ __launch_bounds__(512, 1) void conv_mfma(
    const unsigned short* __restrict__ in, const unsigned short* __restrict__ wbuf,
    const float* __restrict__ g, const float* __restrict__ bsh,
    const float* __restrict__ bm, const float* __restrict__ bv,
    void* __restrict__ out)
{
    __shared__ unsigned short Ab[8 * 36 * 128];
    __shared__ unsigned short Wb[2 * 128 * 128];
    const int tid = threadIdx.x;
    const int lane = tid & 63, wave = tid >> 6;
    const int cog = wave & 1, yg = wave >> 1;
    const int llo = lane & 15, lhi = lane >> 4;
    const int x0 = blockIdx.x * 32, y0 = blockIdx.y * 4, b = blockIdx.z;
    const int c16s = lane & 15;

    #pragma unroll
    for (int it = 0; it < 9; ++it) {
        int gidx = it * 32 + wave * 4 + lhi;
        int row = gidx / 36, xi = gidx % 36;
        gll16(in + (((size_t)b * 404 + y0 + row) * 420 + x0 + xi) * 128 + ((c16s ^ (xi & 15)) * 8),
              Ab + (size_t)(it * 512 + wave * 64) * 8);
    }
    {
        const unsigned short* wt = wbuf;
        #pragma unroll
        for (int it = 0; it < 4; ++it) {
            int co = it * 32 + wave * 4 + lhi;
            gll16(wt + co * 128 + ((c16s ^ (co & 15)) * 8),
                  Wb + (size_t)(it * 512 + wave * 64) * 8);
        }
    }
    __syncthreads();

    f32x4 acc[2][4] = {};
    #pragma unroll
    for (int t = 0; t < 9; ++t) {
        if (t < 8) {
            const unsigned short* wt = wbuf + (size_t)(t + 1) * 16384;
            unsigned short* dst = Wb + ((t + 1) & 1) * 16384;
            #pragma unroll
            for (int it = 0; it < 4; ++it) {
                int co = it * 32 + wave * 4 + lhi;
                gll16(wt + co * 128 + ((c16s ^ (co & 15)) * 8),
                      dst + (size_t)(it * 512 + wave * 64) * 8);
            }
        }
        const unsigned short* Wp = Wb + (t & 1) * 16384;
        const int ky = t / 3, kx = t % 3;
        const int r = yg + 2 * ky;
        #pragma unroll
        for (int kk = 0; kk < 4; ++kk) {
            short8v a[2], w[4];
            #pragma unroll
            for (int i = 0; i < 2; ++i) {
                int xi = i * 16 + llo + 2 * kx;
                a[i] = *reinterpret_cast<const short8v*>(
                    (const char*)Ab + (r * 36 + xi) * 256 + ((kk * 64 + lhi * 16) ^ ((xi & 15) << 4)));
            }
            #pragma unroll
            for (int j = 0; j < 4; ++j) {
                int co = cog * 64 + j * 16 + llo;
                w[j] = *reinterpret_cast<const short8v*>(
                    (const char*)Wp + co * 256 + ((kk * 64 + lhi * 16) ^ ((co & 15) << 4)));
            }
            #pragma unroll
            for (int i = 0; i < 2; ++i)
                #pragma unroll
                for (int j = 0; j < 4; ++j)
                    acc[i][j] = __builtin_amdgcn_mfma_f32_16x16x32_bf16(a[i], w[j], acc[i][j], 0, 0, 0);
        }
        __syncthreads();
    }

    const int y = y0 + yg;
    if (NCHW_OUT) {
        #pragma unroll
        for (int j = 0; j < 4; ++j) {
            int co = cog * 64 + j * 16 + llo;
            float scale = rsqrtf(bv[co] + 1e-3f) * g[co];
            float shift = bsh[co] - bm[co] * scale;
            #pragma unroll
            for (int i = 0; i < 2; ++i) {
                int px = x0 + i * 16 + lhi * 4;
                if (px < 400) {
                    float4 v;
                    v.x = fmaxf(acc[i][j][0] * scale + shift, 0.f);
                    v.y = fmaxf(acc[i][j][1] * scale + shift, 0.f);
                    v.z = fmaxf(acc[i][j][2] * scale + shift, 0.f);
                    v.w = fmaxf(acc[i][j][3] * scale + shift, 0.f);
                    *reinterpret_cast<float4*>(
                        (float*)out + (((size_t)b * 128 + co) * 400 + y) * 400 + px) = v;
                }
            }
        }
    } else {
        unsigned short* Cw = Wb + wave * 2048;
        #pragma unroll
        for (int j = 0; j < 4; ++j) {
            int co = cog * 64 + j * 16 + llo;
            float scale = rsqrtf(bv[co] + 1e-3f) * g[co];
            float shift = bsh[co] - bm[co] * scale;
            #pragma unroll
            for (int i = 0; i < 2; ++i)
                #pragma unroll
                for (int rg = 0; rg < 4; ++rg)
                    Cw[(i * 16 + lhi * 4 + rg) * 64 + j * 16 + llo] =
                        f2bf(fmaxf(acc[i][j][rg] * scale + shift, 0.f));
        }
        #pragma unroll
        for (int s = 0; s < 4; ++s) {
            int pxl = s * 8 + (lane >> 3);
            int oct = lane & 7;
            int px = x0 + pxl;
            if (px < 400)
                *reinterpret_cast<ushort8v*>(
                    (unsigned short*)out + (((size_t)b * 404 + y + 2) * 420 + px + 2) * 128
                                         + cog * 64 + oct * 8) =
                    *reinterpret_cast<const ushort8v*>(&Cw[pxl * 64 + oct * 8]);
        }
    }
}

// ---------------------------------------------------------------- launcher
extern "C" void kernel_launch(void* const* d_in, const int* in_sizes, int n_in,
                              void* d_out, int out_size, void* d_ws, size_t ws_size,
                              hipStream_t stream) {
    const float* voxel_feat = (const float*)d_in[0];
    const int*   coors      = (const int*)d_in[1];
    const float* ciw0       = (const float*)d_in[2];
    const float* ciw1       = (const float*)d_in[3];
    const int* vx[2][2] = {{(const int*)d_in[4], (const int*)d_in[6]},
                           {(const int*)d_in[8], (const int*)d_in[10]}};
    const float* ipw = (const float*)d_in[12];
    const float* ipb = (const float*)d_in[13];
    const float* ow  = (const float*)d_in[14];
    const float* obp = (const float*)d_in[15];
    const float* l1w = (const float*)d_in[16];
    const float* l1b = (const float*)d_in[17];
    const float* l2w = (const float*)d_in[18];
    const float* l2b = (const float*)d_in[19];
    const float* g1  = (const float*)d_in[20];
    const float* b1  = (const float*)d_in[21];
    const float* g2  = (const float*)d_in[22];
    const float* b2  = (const float*)d_in[23];
    const float* cw  = (const float*)d_in[24];
    const float* bng = (const float*)d_in[25];
    const float* bnb = (const float*)d_in[26];
    const float* bnm = (const float*)d_in[27];
    const float* bnv = (const float*)d_in[28];

    float* F = (float*)d_ws;
    unsigned short* W0   = (unsigned short*)F;           // bf16 weights: 1,867,776 ushorts
    unsigned short* ipwb = W0;                           // 589824
    unsigned short* owb  = W0 + 589824;                  // 196608
    unsigned short* l1wb = W0 + 786432;                  // 393216
    unsigned short* l2wb = W0 + 1179648;                 // 393216
    unsigned short* cwb  = W0 + 1572864;                 // 294912
    unsigned short* featb = (unsigned short*)(F + 940000);    // 7.68M ushorts
    unsigned short* pos0  = (unsigned short*)(F + 4780000);
    unsigned short* pos1  = (unsigned short*)(F + 8620000);
    unsigned short* obufb = (unsigned short*)(F + 12460000);
    unsigned short* hbufb = (unsigned short*)(F + 16300000);  // 15.36M ushorts
    // conv phase: padded canvases [2][404][420][128] bf16 = 43,438,080 ushorts each
    unsigned short* canvas1 = (unsigned short*)(F + 8620000);
    unsigned short* canvas2 = (unsigned short*)(F + 30339040);
    unsigned short* qkvb = (unsigned short*)d_out;       // 23.04M ushorts scratch

    cvt_bf16<<<30000, 256, 0, stream>>>(voxel_feat, featb, NVOX * 128);
    pos_kernel<<<30000, 256, 0, stream>>>(ciw0, pos0);
    pos_kernel<<<30000, 256, 0, stream>>>(ciw1, pos1);
    wprep_kernel<<<6144, 256, 0, stream>>>(ipw, ow, l1w, l2w, W0);
    wtrans_kernel<<<(2 * 9 * 16384 + 255) / 256, 256, 0, stream>>>(cw, cwb);

    for (int li = 0; li < 12; ++li) {
        int s = li & 1;
        const unsigned short* pos = s ? pos1 : pos0;
        // QKV: grid x = n-tile (3, q/k get +pos), y = m-tile — A-sharers adjacent
        gemm_mfma<32, 128, true, false, true, false><<<dim3(3, 1875), 256, 0, stream>>>(
            featb, pos, 2, ipwb + (size_t)li * 49152, ipb + li * 384, qkvb, NVOX, 384,
            nullptr, nullptr, nullptr);
        attn_merged<<<2400, 256, 0, stream>>>(qkvb, vx[s][0], vx[s][1], obufb);
        gemm_mfma<32, 128, false, false, false, true><<<dim3(1, 1875), 256, 0, stream>>>(
            obufb, nullptr, 0, owb + (size_t)li * 16384, obp + li * 128, nullptr, NVOX, 128,
            featb, g1 + li * 128, b1 + li * 128);
        gemm_mfma<32, 128, false, true, true, false><<<dim3(2, 1875), 256, 0, stream>>>(
            featb, nullptr, 0, l1wb + (size_t)li * 32768, l1b + li * 256, hbufb, NVOX, 256,
            nullptr, nullptr, nullptr);
        gemm_mfma<32, 256, false, false, false, true><<<dim3(1, 1875), 256, 0, stream>>>(
            hbufb, nullptr, 0, l2wb + (size_t)li * 32768, l2b + li * 128, nullptr, NVOX, 128,
            featb, g2 + li * 128, b2 + li * 128);
    }

    // BEV: zero canvas1 fully + canvas2 halo only, scatter, conv1, conv2
    hipMemsetAsync(canvas1, 0, (size_t)43438080 * 2, stream);
    halo_zero<<<(2 * 9680 * 16 + 255) / 256, 256, 0, stream>>>(canvas2);
    scatter_kernel<<<(NVOX * 16 + 255) / 256, 256, 0, stream>>>(featb, coors, canvas1);
    conv_mfma<false><<<dim3(13, 100, 2), 512, 0, stream>>>(
        canvas1, cwb, bng, bnb, bnm, bnv, canvas2);
    conv_mfma<true><<<dim3(13, 100, 2), 512, 0, stream>>>(
        canvas2, cwb + 9 * 16384, bng + 128, bnb + 128, bnm + 128, bnv + 128, (float*)d_out);
}

// Round 18
// 2082.608 us; speedup vs baseline: 1.3106x; 1.0119x over previous
//
#include <hip/hip_runtime.h>
#include <math.h>

#define NVOX 60000

typedef __attribute__((ext_vector_type(8))) short short8v;            // 8 bf16 raw
typedef __attribute__((ext_vector_type(8))) unsigned short ushort8v;  // 8 bf16 raw
typedef __attribute__((ext_vector_type(4))) float f32x4;

static __device__ __forceinline__ unsigned short f2bf(float f) {
    unsigned u = __float_as_uint(f);
    unsigned r = (u + 0x7fffu + ((u >> 16) & 1u)) >> 16;
    return (unsigned short)r;
}
static __device__ __forceinline__ float bf2f(unsigned short h) {
    return __uint_as_float(((unsigned)h) << 16);
}
// async global->LDS 16B per lane: dest = lds_base + lane*16 (wave-uniform base)
static __device__ __forceinline__ void gll16(const unsigned short* g, unsigned short* l) {
    __builtin_amdgcn_global_load_lds(
        (const __attribute__((address_space(1))) unsigned*)g,
        (__attribute__((address_space(3))) unsigned*)l,
        16, 0, 0);
}

// ---------------------------------------------------------------- pos embed (bf16 out)
__global__ __launch_bounds__(256) void pos_kernel(const float* __restrict__ ciw,
                                                  unsigned short* __restrict__ pos) {
    int idx = blockIdx.x * 256 + threadIdx.x;
    if (idx >= NVOX * 128) return;
    int n = idx >> 7, d = idx & 127;
    int c = d >> 6, t = (d & 63) >> 1;
    float xy = ciw[n * 2 + c] - 6.0f;
    float inv = exp2f((float)t * (13.287712379549449f / 32.0f)); // 10000^(t/32)
    float e = xy / inv;
    pos[idx] = f2bf((d & 1) ? cosf(e) : sinf(e));
}

// ------------------------------------------------------- fp32 -> bf16 convert
__global__ __launch_bounds__(256) void cvt_bf16(const float* __restrict__ in,
                                                unsigned short* __restrict__ out, int n) {
    int idx = blockIdx.x * 256 + threadIdx.x;
    if (idx < n) out[idx] = f2bf(in[idx]);
}

// ----------------- fused weight prep: ipw | ow | l1w | l2w -> bf16 (contiguous dst)
__global__ __launch_bounds__(256) void wprep_kernel(
    const float* __restrict__ ipw, const float* __restrict__ ow,
    const float* __restrict__ l1w, const float* __restrict__ l2w,
    unsigned short* __restrict__ dst) {
    int idx = blockIdx.x * 256 + threadIdx.x;
    if (idx >= 1572864) return;
    float v;
    if (idx < 589824) v = ipw[idx];
    else if (idx < 786432) v = ow[idx - 589824];
    else if (idx < 1179648) v = l1w[idx - 786432];
    else v = l2w[idx - 1179648];
    dst[idx] = f2bf(v);
}

// ----------------------------------------- MFMA GEMM: C = A*W^T + b (+variants)
// MT-row tile. Grid: x = n-tile (fast), y = m-tile. LNF epilogue now stages
// through LDS for coalesced full-line featb stores.
template<int MT, int KTOT, bool ADD, bool GELU, bool CBF16, bool LNF>
__global__ __launch_bounds__(256) void gemm_mfma(
    const unsigned short* __restrict__ A, const unsigned short* __restrict__ Aadd, int add_nblk,
    const unsigned short* __restrict__ W, const float* __restrict__ bias,
    void* __restrict__ Cp, int M, int ldc,
    unsigned short* __restrict__ featb,
    const float* __restrict__ lng, const float* __restrict__ lnb)
{
    constexpr int RF = (MT + 31) / 32;          // row frags per wave (>=1)
    __shared__ unsigned short smem[(MT + 128) * 64];   // As(MT*64) + Ws(128*64); reused as Cs(MT*128)
    __shared__ float2 lnsum[MT][2];
    unsigned short* As = smem;
    unsigned short* Ws = smem + MT * 64;
    const int tid = threadIdx.x;
    const int lane = tid & 63, wave = tid >> 6;
    const int wr = wave >> 1, wc = wave & 1;
    const int llo = lane & 15, lhi = lane >> 4;
    const int m0 = blockIdx.y * MT;
    const int n0 = blockIdx.x * 128;
    const bool addp = ADD && ((int)blockIdx.x < add_nblk);
    const int gr = lane >> 3;           // row within 8-row group
    const int gc = (lane & 7) ^ gr;     // pre-swizzled source chunk
    f32x4 acc[RF][4] = {};

    for (int k0 = 0; k0 < KTOT; k0 += 64) {
        #pragma unroll
        for (int p = 0; p < 4; ++p) {
            int r0 = wave * 32 + p * 8;
            gll16(W + (size_t)(n0 + r0 + gr) * KTOT + k0 + gc * 8, &Ws[r0 * 64]);
        }
        if (!addp) {
            #pragma unroll
            for (int p = 0; p < RF; ++p) {
                int r0 = wave * (RF * 8) + p * 8;   // RF*8 rows per wave (4 waves cover MT)
                gll16(A + (size_t)(m0 + r0 + gr) * KTOT + k0 + gc * 8, &As[r0 * 64]);
            }
        } else {
            #pragma unroll
            for (int p = 0; p < RF; ++p) {
                int c = tid + p * 256;
                int r = c >> 3, c16 = c & 7;
                int m = m0 + r;
                short8v av = {};
                if (m < M && r < MT) {
                    ushort8v fa = *reinterpret_cast<const ushort8v*>(A + (size_t)m * KTOT + k0 + c16 * 8);
                    ushort8v pa = *reinterpret_cast<const ushort8v*>(Aadd + (size_t)m * 128 + k0 + c16 * 8);
                    #pragma unroll
                    for (int q = 0; q < 8; ++q) av[q] = (short)f2bf(bf2f(fa[q]) + bf2f(pa[q]));
                }
                if (r < MT)
                    *reinterpret_cast<short8v*>((char*)As + r * 128 + ((c16 * 16) ^ ((r & 7) << 4))) = av;
            }
        }
        __syncthreads();
        #pragma unroll
        for (int kk = 0; kk < 2; ++kk) {
            int kb = kk * 64 + lhi * 16;
            short8v af[RF], bf[4];
            #pragma unroll
            for (int i = 0; i < RF; ++i) {
                int r = wr * (MT / 2) + i * 16 + llo;
                af[i] = *reinterpret_cast<const short8v*>((const char*)As + r * 128 + (kb ^ ((r & 7) << 4)));
            }
            #pragma unroll
            for (int j = 0; j < 4; ++j) {
                int cc = wc * 64 + j * 16 + llo;
                bf[j] = *reinterpret_cast<const short8v*>((const char*)Ws + cc * 128 + (kb ^ ((cc & 7) << 4)));
            }
            #pragma unroll
            for (int i = 0; i < RF; ++i)
                #pragma unroll
                for (int j = 0; j < 4; ++j)
                    acc[i][j] = __builtin_amdgcn_mfma_f32_16x16x32_bf16(af[i], bf[j], acc[i][j], 0, 0, 0);
        }
        __syncthreads();
    }

    if (LNF) {
        // residual(bf16) + LN: pass 1 computes x = featb + acc + bias -> kept in acc
        float s1[RF][4] = {}, s2[RF][4] = {};
        #pragma unroll
        for (int i = 0; i < RF; ++i)
            #pragma unroll
            for (int rg = 0; rg < 4; ++rg) {
                int m = m0 + wr * (MT / 2) + i * 16 + lhi * 4 + rg;
                if (m < M) {
                    #pragma unroll
                    for (int j = 0; j < 4; ++j) {
                        int n = wc * 64 + j * 16 + llo;
                        float x = bf2f(featb[(size_t)m * 128 + n]) + acc[i][j][rg] + bias[n];
                        acc[i][j][rg] = x;
                        s1[i][rg] += x; s2[i][rg] += x * x;
                    }
                }
            }
        #pragma unroll
        for (int i = 0; i < RF; ++i)
            #pragma unroll
            for (int rg = 0; rg < 4; ++rg) {
                #pragma unroll
                for (int off = 1; off < 16; off <<= 1) {
                    s1[i][rg] += __shfl_xor(s1[i][rg], off);
                    s2[i][rg] += __shfl_xor(s2[i][rg], off);
                }
                if (llo == 0)
                    lnsum[wr * (MT / 2) + i * 16 + lhi * 4 + rg][wc] = make_float2(s1[i][rg], s2[i][rg]);
            }
        __syncthreads();
        // pass 2: LN -> stage bf16 tile in smem, then coalesced full-line stores
        #pragma unroll
        for (int i = 0; i < RF; ++i)
            #pragma unroll
            for (int rg = 0; rg < 4; ++rg) {
                int r = wr * (MT / 2) + i * 16 + lhi * 4 + rg;
                float2 a0 = lnsum[r][0], a1 = lnsum[r][1];
                float mu = (a0.x + a1.x) * 0.0078125f;
                float var = fmaxf((a0.y + a1.y) * 0.0078125f - mu * mu, 0.f);
                float inv = rsqrtf(var + 1e-5f);
                #pragma unroll
                for (int j = 0; j < 4; ++j) {
                    int n = wc * 64 + j * 16 + llo;
                    float v = (acc[i][j][rg] - mu) * inv * lng[n] + lnb[n];
                    smem[r * 128 + n] = f2bf(v);
                }
            }
        __syncthreads();
        #pragma unroll
        for (int c = 0; c < MT / 16; ++c) {
            int idx = tid + c * 256;
            int r = idx >> 4, ch = idx & 15;
            if (m0 + r < M)
                *reinterpret_cast<ushort8v*>(featb + (size_t)(m0 + r) * 128 + ch * 8) =
                    *reinterpret_cast<const ushort8v*>(&smem[r * 128 + ch * 8]);
        }
    } else if (CBF16) {
        #pragma unroll
        for (int j = 0; j < 4; ++j) {
            int nl = wc * 64 + j * 16 + llo;
            float bn = bias[n0 + nl];
            #pragma unroll
            for (int i = 0; i < RF; ++i)
                #pragma unroll
                for (int rg = 0; rg < 4; ++rg) {
                    float v = acc[i][j][rg] + bn;
                    if (GELU) v = 0.5f * v * (1.0f + erff(v * 0.7071067811865475f));
                    smem[(wr * (MT / 2) + i * 16 + lhi * 4 + rg) * 128 + nl] = f2bf(v);
                }
        }
        __syncthreads();
        unsigned short* C = (unsigned short*)Cp;
        #pragma unroll
        for (int c = 0; c < MT / 16; ++c) {
            int idx = tid + c * 256;
            int r = idx >> 4, ch = idx & 15;
            if (m0 + r < M)
                *reinterpret_cast<ushort8v*>(C + (size_t)(m0 + r) * ldc + n0 + ch * 8) =
                    *reinterpret_cast<const ushort8v*>(&smem[r * 128 + ch * 8]);
        }
    } else {
        float* C = (float*)Cp;
        #pragma unroll
        for (int j = 0; j < 4; ++j) {
            int n = n0 + wc * 64 + j * 16 + llo;
            float bn = bias[n];
            #pragma unroll
            for (int i = 0; i < RF; ++i)
                #pragma unroll
                for (int rg = 0; rg < 4; ++rg) {
                    int m = m0 + wr * (MT / 2) + i * 16 + lhi * 4 + rg;
                    if (m < M) {
                        float v = acc[i][j][rg] + bn;
                        if (GELU) v = 0.5f * v * (1.0f + erff(v * 0.7071067811865475f));
                        C[(size_t)m * ldc + n] = v;
                    }
                }
        }
    }
}

// ------------------- merged windowed attention: lvl0 (T=25,HG=8) + lvl1 (T=100,HG=2)
__global__ __launch_bounds__(256) void attn_merged(
    const unsigned short* __restrict__ qkv, const int* __restrict__ vl0,
    const int* __restrict__ vl1, unsigned short* __restrict__ oout)
{
    __shared__ float Ks[3200];    // lvl0: [25][128] ; lvl1: [100][32]
    __shared__ float Vs[3200];
    __shared__ int vl[100];
    int T, HGsh, hb, w;
    const int* vlist;
    if ((int)blockIdx.x < 960) {
        T = 25; HGsh = 3; hb = 0; w = blockIdx.x; vlist = vl0;
    } else {
        int idx = blockIdx.x - 960;
        T = 100; HGsh = 1; hb = (idx / 360) * 2; w = idx % 360; vlist = vl1;
    }
    const int HG = 1 << HGsh;
    const int rs = HG * 16;            // row stride in floats
    const int tid = threadIdx.x;
    if (tid < T) vl[tid] = vlist[w * T + tid];
    const int r8sh = HGsh + 1;         // chunks per row = HG*2
    for (int idx = tid; idx < (T << r8sh); idx += 256) {
        int t = idx >> r8sh, c8 = (idx & ((1 << r8sh) - 1)) * 8;
        int vox = vlist[w * T + t];
        const unsigned short* base = qkv + (size_t)vox * 384 + hb * 16 + c8;
        ushort8v kv = *reinterpret_cast<const ushort8v*>(base + 128);
        ushort8v vv = *reinterpret_cast<const ushort8v*>(base + 256);
        #pragma unroll
        for (int q = 0; q < 8; ++q) { Ks[t * rs + c8 + q] = bf2f(kv[q]); Vs[t * rs + c8 + q] = bf2f(vv[q]); }
    }
    __syncthreads();
    const int ITEMS = T << HGsh;
    for (int item = tid; item < ITEMS; item += 256) {
        int h = item & (HG - 1);
        int q = item >> HGsh;
        int vq = vl[q];
        const unsigned short* qb = qkv + (size_t)vq * 384 + (hb + h) * 16;
        ushort8v qa = *reinterpret_cast<const ushort8v*>(qb);
        ushort8v qc = *reinterpret_cast<const ushort8v*>(qb + 8);
        float4 q0 = make_float4(bf2f(qa[0]), bf2f(qa[1]), bf2f(qa[2]), bf2f(qa[3]));
        float4 q1 = make_float4(bf2f(qa[4]), bf2f(qa[5]), bf2f(qa[6]), bf2f(qa[7]));
        float4 q2 = make_float4(bf2f(qc[0]), bf2f(qc[1]), bf2f(qc[2]), bf2f(qc[3]));
        float4 q3 = make_float4(bf2f(qc[4]), bf2f(qc[5]), bf2f(qc[6]), bf2f(qc[7]));
        float mx = -INFINITY, l = 0.f;
        float4 o0 = make_float4(0,0,0,0), o1 = o0, o2 = o0, o3 = o0;
        const float* kbase = Ks + h * 16;
        const float* vbase = Vs + h * 16;
        for (int t = 0; t < T; ++t) {
            const float4* kr = reinterpret_cast<const float4*>(kbase + t * rs);
            float4 k0 = kr[0], k1 = kr[1], k2 = kr[2], k3 = kr[3];
            float s = q0.x*k0.x + q0.y*k0.y + q0.z*k0.z + q0.w*k0.w
                    + q1.x*k1.x + q1.y*k1.y + q1.z*k1.z + q1.w*k1.w
                    + q2.x*k2.x + q2.y*k2.y + q2.z*k2.z + q2.w*k2.w
                    + q3.x*k3.x + q3.y*k3.y + q3.z*k3.z + q3.w*k3.w;
            s *= 0.25f;
            float mo = mx;
            mx = fmaxf(mx, s);
            float cc = __expf(mo - mx);
            float p  = __expf(s - mx);
            l = l * cc + p;
            const float4* vr = reinterpret_cast<const float4*>(vbase + t * rs);
            float4 v0 = vr[0], v1 = vr[1], v2 = vr[2], v3 = vr[3];
            o0.x = o0.x*cc + p*v0.x; o0.y = o0.y*cc + p*v0.y; o0.z = o0.z*cc + p*v0.z; o0.w = o0.w*cc + p*v0.w;
            o1.x = o1.x*cc + p*v1.x; o1.y = o1.y*cc + p*v1.y; o1.z = o1.z*cc + p*v1.z; o1.w = o1.w*cc + p*v1.w;
            o2.x = o2.x*cc + p*v2.x; o2.y = o2.y*cc + p*v2.y; o2.z = o2.z*cc + p*v2.z; o2.w = o2.w*cc + p*v2.w;
            o3.x = o3.x*cc + p*v3.x; o3.y = o3.y*cc + p*v3.y; o3.z = o3.z*cc + p*v3.z; o3.w = o3.w*cc + p*v3.w;
        }
        float rl = 1.0f / l;
        ushort8v r0, r1;
        r0[0]=f2bf(o0.x*rl); r0[1]=f2bf(o0.y*rl); r0[2]=f2bf(o0.z*rl); r0[3]=f2bf(o0.w*rl);
        r0[4]=f2bf(o1.x*rl); r0[5]=f2bf(o1.y*rl); r0[6]=f2bf(o1.z*rl); r0[7]=f2bf(o1.w*rl);
        r1[0]=f2bf(o2.x*rl); r1[1]=f2bf(o2.y*rl); r1[2]=f2bf(o2.z*rl); r1[3]=f2bf(o2.w*rl);
        r1[4]=f2bf(o3.x*rl); r1[5]=f2bf(o3.y*rl); r1[6]=f2bf(o3.z*rl); r1[7]=f2bf(o3.w*rl);
        unsigned short* op = oout + (size_t)vq * 128 + (hb + h) * 16;
        *reinterpret_cast<ushort8v*>(op) = r0;
        *reinterpret_cast<ushort8v*>(op + 8) = r1;
    }
}

// ------------------- BEV scatter into padded canvas (bf16 copy, stride 420)
__global__ __launch_bounds__(256) void scatter_kernel(const unsigned short* __restrict__ featb,
    const int* __restrict__ coors, unsigned short* __restrict__ canvas)
{
    int idx = blockIdx.x * 256 + threadIdx.x;
    if (idx >= NVOX * 16) return;
    int n = idx >> 4, c8 = (idx & 15) << 3;
    int b = coors[n * 4], y = coors[n * 4 + 2], x = coors[n * 4 + 3];
    size_t p = (((size_t)b * 404 + y + 2) * 420 + x + 2) * 128 + c8;
    *reinterpret_cast<ushort8v*>(canvas + p) =
        *reinterpret_cast<const ushort8v*>(featb + (size_t)n * 128 + c8);
}

// --------- zero the halo of a stride-420 padded canvas
__global__ __launch_bounds__(256) void halo_zero(unsigned short* __restrict__ c) {
    int idx = blockIdx.x * 256 + threadIdx.x;
    if (idx >= 2 * 9680 * 16) return;
    int b = idx / (9680 * 16);
    int rem = idx % (9680 * 16);
    int p = rem >> 4, ch = (rem & 15) * 8;
    int y, x;
    if (p < 1680) { int ry = p / 420; y = (ry < 2) ? ry : ry + 400; x = p % 420; }
    else { int q = p - 1680; y = 2 + q / 20; int cx = q % 20; x = (cx < 2) ? cx : cx + 400; }
    ushort8v z = {};
    *reinterpret_cast<ushort8v*>(c + (((size_t)b * 404 + y) * 420 + x) * 128 + ch) = z;
}

// ------------------- conv weight re-layout -> bf16 [i][ky*3+kx][cout][cin]
__global__ __launch_bounds__(256) void wtrans_kernel(const float* __restrict__ cw,
                                                     unsigned short* __restrict__ wbuf)
{
    int idx = blockIdx.x * 256 + threadIdx.x;
    if (idx >= 2 * 9 * 128 * 128) return;
    int ci = idx & 127;
    int co = (idx >> 7) & 127;
    int kk = (idx >> 14) % 9;
    int i  = idx / (9 * 16384);
    wbuf[idx] = f2bf(cw[(((size_t)i * 128 + co) * 128 + ci) * 9 + kk]);
}

// ---------------- 3x3 dilated(2) conv + BN + ReLU, LDS-A once + LDS-W double-buffered
template<bool NCHW_OUT>
__global__ __launch_bounds__(512, 1) void conv_mfma(
    const unsigned short* __restrict__ in, const unsigned short* __restrict__ wbuf,
    const float* __restrict__ g, const float* __restrict__ bsh,
    const float* __restrict__ bm, const float* __restrict__ bv,
    void* __restrict__ out)
{
    __shared__ unsigned short Ab[8 * 36 * 128];
    __shared__ unsigned short Wb[2 * 128 * 128];
    const int tid = threadIdx.x;
    const int lane = tid & 63, wave = tid >> 6;
    const int cog = wave & 1, yg = wave >> 1;
    const int llo = lane & 15, lhi = lane >> 4;
    const int x0 = blockIdx.x * 32, y0 = blockIdx.y * 4, b = blockIdx.z;
    const int c16s = lane & 15;

    #pragma unroll
    for (int it = 0; it < 9; ++it) {
        int gidx = it * 32 + wave * 4 + lhi;
        int row = gidx / 36, xi = gidx % 36;
        gll16(in + (((size_t)b * 404 + y0 + row) * 420 + x0 + xi) * 128 + ((c16s ^ (xi & 15)) * 8),
              Ab + (size_t)(it * 512 + wave * 64) * 8);
    }
    {
        const unsigned short* wt = wbuf;
        #pragma unroll
        for (int it = 0; it < 4; ++it) {
            int co = it * 32 + wave * 4 + lhi;
            gll16(wt + co * 128 + ((c16s ^ (co & 15)) * 8),
                  Wb + (size_t)(it * 512 + wave * 64) * 8);
        }
    }
    __syncthreads();

    f32x4 acc[2][4] = {};
    #pragma unroll
    for (int t = 0; t < 9; ++t) {
        if (t < 8) {
            const unsigned short* wt = wbuf + (size_t)(t + 1) * 16384;
            unsigned short* dst = Wb + ((t + 1) & 1) * 16384;
            #pragma unroll
            for (int it = 0; it < 4; ++it) {
                int co = it * 32 + wave * 4 + lhi;
                gll16(wt + co * 128 + ((c16s ^ (co & 15)) * 8),
                      dst + (size_t)(it * 512 + wave * 64) * 8);
            }
        }
        const unsigned short* Wp = Wb + (t & 1) * 16384;
        const int ky = t / 3, kx = t % 3;
        const int r = yg + 2 * ky;
        #pragma unroll
        for (int kk = 0; kk < 4; ++kk) {
            short8v a[2], w[4];
            #pragma unroll
            for (int i = 0; i < 2; ++i) {
                int xi = i * 16 + llo + 2 * kx;
                a[i] = *reinterpret_cast<const short8v*>(
                    (const char*)Ab + (r * 36 + xi) * 256 + ((kk * 64 + lhi * 16) ^ ((xi & 15) << 4)));
            }
            #pragma unroll
            for (int j = 0; j < 4; ++j) {
                int co = cog * 64 + j * 16 + llo;
                w[j] = *reinterpret_cast<const short8v*>(
                    (const char*)Wp + co * 256 + ((kk * 64 + lhi * 16) ^ ((co & 15) << 4)));
            }
            #pragma unroll
            for (int i = 0; i < 2; ++i)
                #pragma unroll
                for (int j = 0; j < 4; ++j)
                    acc[i][j] = __builtin_amdgcn_mfma_f32_16x16x32_bf16(a[i], w[j], acc[i][j], 0, 0, 0);
        }
        __syncthreads();
    }

    const int y = y0 + yg;
    if (NCHW_OUT) {
        #pragma unroll
        for (int j = 0; j < 4; ++j) {
            int co = cog * 64 + j * 16 + llo;
            float scale = rsqrtf(bv[co] + 1e-3f) * g[co];
            float shift = bsh[co] - bm[co] * scale;
            #pragma unroll
            for (int i = 0; i < 2; ++i) {
                int px = x0 + i * 16 + lhi * 4;
                if (px < 400) {
                    float4 v;
                    v.x = fmaxf(acc[i][j][0] * scale + shift, 0.f);
                    v.y = fmaxf(acc[i][j][1] * scale + shift, 0.f);
                    v.z = fmaxf(acc[i][j][2] * scale + shift, 0.f);
                    v.w = fmaxf(acc[i][j][3] * scale + shift, 0.f);
                    *reinterpret_cast<float4*>(
                        (float*)out + (((size_t)b * 128 + co) * 400 + y) * 400 + px) = v;
                }
            }
        }
    } else {
        // stage per-wave [32px][64co] tile at Wb + wave*2048, then block-merged
        // full-line stores (each wave writes 4px x 256B contiguous)
        unsigned short* Cw = Wb + wave * 2048;
        #pragma unroll
        for (int j = 0; j < 4; ++j) {
            int co = cog * 64 + j * 16 + llo;
            float scale = rsqrtf(bv[co] + 1e-3f) * g[co];
            float shift = bsh[co] - bm[co] * scale;
            #pragma unroll
            for (int i = 0; i < 2; ++i)
                #pragma unroll
                for (int rg = 0; rg < 4; ++rg)
                    Cw[(i * 16 + lhi * 4 + rg) * 64 + j * 16 + llo] =
                        f2bf(fmaxf(acc[i][j][rg] * scale + shift, 0.f));
        }
        __syncthreads();
        unsigned short* outp = (unsigned short*)out;
        #pragma unroll
        for (int it = 0; it < 4; ++it) {
            int idx = tid + it * 512;          // 2048 chunks: [y(4)][px(32)][oct(16)]
            int oct = idx & 15;
            int pxl = (idx >> 4) & 31;
            int yy  = idx >> 9;
            int px = x0 + pxl;
            int cog2 = oct >> 3;               // channel half
            const unsigned short* src = Wb + (yy * 2 + cog2) * 2048 + pxl * 64 + (oct & 7) * 8;
            if (px < 400)
                *reinterpret_cast<ushort8v*>(
                    outp + (((size_t)b * 404 + y0 + yy + 2) * 420 + px + 2) * 128 + oct * 8) =
                    *reinterpret_cast<const ushort8v*>(src);
        }
    }
}

// ---------------------------------------------------------------- launcher
extern "C" void kernel_launch(void* const* d_in, const int* in_sizes, int n_in,
                              void* d_out, int out_size, void* d_ws, size_t ws_size,
                              hipStream_t stream) {
    const float* voxel_feat = (const float*)d_in[0];
    const int*   coors      = (const int*)d_in[1];
    const float* ciw0       = (const float*)d_in[2];
    const float* ciw1       = (const float*)d_in[3];
    const int* vx[2][2] = {{(const int*)d_in[4], (const int*)d_in[6]},
                           {(const int*)d_in[8], (const int*)d_in[10]}};
    const float* ipw = (const float*)d_in[12];
    const float* ipb = (const float*)d_in[13];
    const float* ow  = (const float*)d_in[14];
    const float* obp = (const float*)d_in[15];
    const float* l1w = (const float*)d_in[16];
    const float* l1b = (const float*)d_in[17];
    const float* l2w = (const float*)d_in[18];
    const float* l2b = (const float*)d_in[19];
    const float* g1  = (const float*)d_in[20];
    const float* b1  = (const float*)d_in[21];
    const float* g2  = (const float*)d_in[22];
    const float* b2  = (const float*)d_in[23];
    const float* cw  = (const float*)d_in[24];
    const float* bng = (const float*)d_in[25];
    const float* bnb = (const float*)d_in[26];
    const float* bnm = (const float*)d_in[27];
    const float* bnv = (const float*)d_in[28];

    float* F = (float*)d_ws;
    unsigned short* W0   = (unsigned short*)F;           // bf16 weights: 1,867,776 ushorts
    unsigned short* ipwb = W0;                           // 589824
    unsigned short* owb  = W0 + 589824;                  // 196608
    unsigned short* l1wb = W0 + 786432;                  // 393216
    unsigned short* l2wb = W0 + 1179648;                 // 393216
    unsigned short* cwb  = W0 + 1572864;                 // 294912
    unsigned short* featb = (unsigned short*)(F + 940000);    // 7.68M ushorts
    unsigned short* pos0  = (unsigned short*)(F + 4780000);
    unsigned short* pos1  = (unsigned short*)(F + 8620000);
    unsigned short* obufb = (unsigned short*)(F + 12460000);
    unsigned short* hbufb = (unsigned short*)(F + 16300000);  // 15.36M ushorts
    // conv phase: padded canvases [2][404][420][128] bf16 = 43,438,080 ushorts each
    unsigned short* canvas1 = (unsigned short*)(F + 8620000);
    unsigned short* canvas2 = (unsigned short*)(F + 30339040);
    unsigned short* qkvb = (unsigned short*)d_out;       // 23.04M ushorts scratch

    cvt_bf16<<<30000, 256, 0, stream>>>(voxel_feat, featb, NVOX * 128);
    pos_kernel<<<30000, 256, 0, stream>>>(ciw0, pos0);
    pos_kernel<<<30000, 256, 0, stream>>>(ciw1, pos1);
    wprep_kernel<<<6144, 256, 0, stream>>>(ipw, ow, l1w, l2w, W0);
    wtrans_kernel<<<(2 * 9 * 16384 + 255) / 256, 256, 0, stream>>>(cw, cwb);

    for (int li = 0; li < 12; ++li) {
        int s = li & 1;
        const unsigned short* pos = s ? pos1 : pos0;
        gemm_mfma<32, 128, true, false, true, false><<<dim3(3, 1875), 256, 0, stream>>>(
            featb, pos, 2, ipwb + (size_t)li * 49152, ipb + li * 384, qkvb, NVOX, 384,
            nullptr, nullptr, nullptr);
        attn_merged<<<2400, 256, 0, stream>>>(qkvb, vx[s][0], vx[s][1], obufb);
        gemm_mfma<32, 128, false, false, false, true><<<dim3(1, 1875), 256, 0, stream>>>(
            obufb, nullptr, 0, owb + (size_t)li * 16384, obp + li * 128, nullptr, NVOX, 128,
            featb, g1 + li * 128, b1 + li * 128);
        gemm_mfma<32, 128, false, true, true, false><<<dim3(2, 1875), 256, 0, stream>>>(
            featb, nullptr, 0, l1wb + (size_t)li * 32768, l1b + li * 256, hbufb, NVOX, 256,
            nullptr, nullptr, nullptr);
        gemm_mfma<32, 256, false, false, false, true><<<dim3(1, 1875), 256, 0, stream>>>(
            hbufb, nullptr, 0, l2wb + (size_t)li * 32768, l2b + li * 128, nullptr, NVOX, 128,
            featb, g2 + li * 128, b2 + li * 128);
    }

    // BEV: zero canvas1 fully + canvas2 halo only, scatter, conv1, conv2
    hipMemsetAsync(canvas1, 0, (size_t)43438080 * 2, stream);
    halo_zero<<<(2 * 9680 * 16 + 255) / 256, 256, 0, stream>>>(canvas2);
    scatter_kernel<<<(NVOX * 16 + 255) / 256, 256, 0, stream>>>(featb, coors, canvas1);
    conv_mfma<false><<<dim3(13, 100, 2), 512, 0, stream>>>(
        canvas1, cwb, bng, bnb, bnm, bnv, canvas2);
    conv_mfma<true><<<dim3(13, 100, 2), 512, 0, stream>>>(
        canvas2, cwb + 9 * 16384, bng + 128, bnb + 128, bnm + 128, bnv + 128, (float*)d_out);
}